// Round 17
// baseline (322.868 us; speedup 1.0000x reference)
//
#include <hip/hip_runtime.h>
#include <hip/hip_bf16.h>
#include <math.h>

#define D 2048
#define NROWS 2048      // b*n
#define NQKV 6144       // fused QKV width
#define H 16
#define DH 128
#define CHK 64
#define NC 16
#define EPSC 1e-6f
#define RSQDH 0.08838834764831845f   // 128^-0.5

typedef unsigned short ushort_t;
typedef __attribute__((ext_vector_type(4))) float f4_t;
typedef __attribute__((ext_vector_type(8))) short s8_t;
typedef __attribute__((ext_vector_type(8))) _Float16 h8_t;
typedef __attribute__((ext_vector_type(4))) _Float16 h4_t;
typedef __attribute__((ext_vector_type(4))) unsigned short us4_t;

#define MFMA16(a, b, c) __builtin_amdgcn_mfma_f32_16x16x32_bf16((a), (b), (c), 0, 0, 0)
#define MFMAH(a, b, c)  __builtin_amdgcn_mfma_f32_16x16x32_f16((a), (b), (c), 0, 0, 0)
#define GLOAD16(g, l) __builtin_amdgcn_global_load_lds((const __attribute__((address_space(1))) unsigned int*)(g), (__attribute__((address_space(3))) unsigned int*)(l), 16, 0, 0)

__device__ __forceinline__ ushort_t f2bf(float f) {
  union { float f; unsigned u; } v; v.f = f;
  unsigned r = (v.u + 0x7fffu + ((v.u >> 16) & 1u)) >> 16;
  return (ushort_t)r;
}
__device__ __forceinline__ float bf2f(ushort_t h) {
  union { unsigned u; float f; } v; v.u = ((unsigned)h) << 16;
  return v.f;
}

// ---------------- fp32 -> fp16 (1-term, for QKV GEMM A) --------------------
__global__ __launch_bounds__(256) void split_h(const float* __restrict__ in,
                                               _Float16* __restrict__ hi) {
  int i = (blockIdx.x * 256 + threadIdx.x) * 4;
  float4 v = *(const float4*)(in + i);
  float vv[4] = {v.x, v.y, v.z, v.w};
  h4_t h;
#pragma unroll
  for (int j = 0; j < 4; j++) h[j] = (_Float16)vv[j];
  *(h4_t*)(hi + i) = h;
}

// ------------- all 4 weights: transpose + fp16 round, one launch -----------
__global__ __launch_bounds__(256) void wsplit4(const float* __restrict__ Wq,
                                               const float* __restrict__ Wk,
                                               const float* __restrict__ Wv,
                                               const float* __restrict__ Wo,
                                               _Float16* __restrict__ Tqkv,
                                               _Float16* __restrict__ To) {
  __shared__ float t[32][33];
  const int tid = threadIdx.x;
  const int k0 = blockIdx.y * 32, n0 = blockIdx.x * 32;
  const int z = blockIdx.z;
  const float* W = (z == 0) ? Wq : (z == 1) ? Wk : (z == 2) ? Wv : Wo;
  _Float16* T = (z < 3) ? (Tqkv + (size_t)z * D * D) : To;
  const int c = tid & 31, rr = tid >> 5;
#pragma unroll
  for (int p = 0; p < 4; p++) {
    int r = p * 8 + rr;
    t[r][c] = W[(size_t)(k0 + r) * D + n0 + c];
  }
  __syncthreads();
#pragma unroll
  for (int p = 0; p < 4; p++) {
    int r = p * 8 + rr;
    T[(size_t)(n0 + r) * D + k0 + c] = (_Float16)t[c][r];
  }
}

// ------ fp16 1-term MFMA GEMM (fp32 out, final Wo GEMM; proven R13) --------
__global__ __launch_bounds__(256) void gemm1(const _Float16* __restrict__ Ah,
                                             const _Float16* __restrict__ Bt,
                                             float* __restrict__ C,
                                             int M, int N, int K) {
  __shared__ __align__(16) ushort_t A_s[2][4096];    // [128][32]
  __shared__ __align__(16) ushort_t B_s[2][4096];    // [128 cols][32 k]
  const int tid = threadIdx.x, lane = tid & 63, wid = tid >> 6;
  const int nwg = gridDim.x;
  int bid = blockIdx.x;
  int swz = (bid & 7) * (nwg >> 3) + (bid >> 3);     // XCD swizzle (nwg%8==0)
  const int nbn = N >> 7;
  const int bm = swz / nbn, bn = swz % nbn;
  const int row0 = bm << 7, col0 = bn << 7;
  const int lm = lane & 15, lg = lane >> 4;
  const int wrow = (wid >> 1) * 64, wcol = (wid & 1) * 64;
  const int NT = K >> 5;

  f4_t acc[4][4];
#pragma unroll
  for (int m = 0; m < 4; m++)
#pragma unroll
    for (int n = 0; n < 4; n++) acc[m][n] = (f4_t){0.f, 0.f, 0.f, 0.f};

  auto stage = [&](int buf, int ks) {
    int k0 = ks << 5;
#pragma unroll
    for (int p = 0; p < 2; p++) {
      int c = p * 256 + wid * 64 + lane;             // 16B chunk 0..511
      int r = c >> 2, q = (c & 3) * 8;
      char* la = (char*)&A_s[buf][0] + p * 4096 + wid * 1024;
      GLOAD16(Ah + (size_t)(row0 + r) * K + k0 + q, la);
      char* lb = (char*)&B_s[buf][0] + p * 4096 + wid * 1024;
      GLOAD16(Bt + (size_t)(col0 + r) * K + k0 + q, lb);
    }
  };

  stage(0, 0);
  __syncthreads();
  for (int t = 0; t < NT; t++) {
    int cur = t & 1;
    if (t + 1 < NT) stage(cur ^ 1, t + 1);
    h8_t af[4], bfr[4];
#pragma unroll
    for (int m = 0; m < 4; m++)
      af[m] = *(const h8_t*)&A_s[cur][(wrow + m * 16 + lm) * 32 + lg * 8];
#pragma unroll
    for (int n = 0; n < 4; n++)
      bfr[n] = *(const h8_t*)&B_s[cur][(wcol + n * 16 + lm) * 32 + lg * 8];
#pragma unroll
    for (int m = 0; m < 4; m++)
#pragma unroll
      for (int n = 0; n < 4; n++)
        acc[m][n] = MFMAH(af[m], bfr[n], acc[m][n]);
    __syncthreads();
  }
#pragma unroll
  for (int m = 0; m < 4; m++)
#pragma unroll
    for (int n = 0; n < 4; n++)
#pragma unroll
      for (int r = 0; r < 4; r++)
        C[(size_t)(row0 + wrow + m * 16 + lg * 4 + r) * N + col0 + wcol + n * 16 + lm] = acc[m][n][r];
}

// ------ fp16 8-phase-style 256^2 MFMA GEMM (fp16 out, QKV projection) ------
// T3+T4: per-phase {stage-issue || ds_read frags -> raw barrier -> setprio ->
// 16 MFMA -> setprio -> raw barrier}; counted vmcnt (never 0 in steady state).
// XOR-8 swizzled LDS (write: linear dest + pre-swizzled global source).
__global__ __launch_bounds__(512, 2) void gemm8(const _Float16* __restrict__ Ah,
                                                const _Float16* __restrict__ Bt,
                                                _Float16* __restrict__ C,
                                                int M, int N, int K) {
  __shared__ __align__(16) ushort_t A_s[2][16384];   // [256 rows][64 k] swz
  __shared__ __align__(16) ushort_t B_s[2][16384];
  const int tid = threadIdx.x, lane = tid & 63, wid = tid >> 6;
  const int nwg = gridDim.x;
  int bid = blockIdx.x;
  int swz = (bid & 7) * (nwg >> 3) + (bid >> 3);     // XCD chunked (nwg%8==0)
  const int nbn = N >> 8;
  const int bm = swz / nbn, bn = swz % nbn;
  const int row0 = bm << 8, col0 = bn << 8;
  const int lm = lane & 15, lg = lane >> 4;
  const int wr = wid >> 2, wc = wid & 3;             // 2 x 4 wave grid
  const int NT = K >> 6;

  f4_t acc[8][4];
#pragma unroll
  for (int m = 0; m < 8; m++)
#pragma unroll
    for (int n = 0; n < 4; n++) acc[m][n] = (f4_t){0.f, 0.f, 0.f, 0.f};

  auto stageA = [&](int buf, int t) {
    int k0 = t << 6;
#pragma unroll
    for (int p = 0; p < 4; p++) {
      int c = p * 512 + tid;            // 0..2047 (16B chunks, linear dest)
      int r = c >> 3, q = c & 7;
      int qx = q ^ (r & 7);             // pre-swizzled global source
      GLOAD16(Ah + (size_t)(row0 + r) * K + k0 + qx * 8, (char*)&A_s[buf][0] + c * 16);
    }
  };
  auto stageB = [&](int buf, int t) {
    int k0 = t << 6;
#pragma unroll
    for (int p = 0; p < 4; p++) {
      int c = p * 512 + tid;
      int r = c >> 3, q = c & 7;
      int qx = q ^ (r & 7);
      GLOAD16(Bt + (size_t)(col0 + r) * K + k0 + qx * 8, (char*)&B_s[buf][0] + c * 16);
    }
  };

  stageA(0, 0);
  stageB(0, 0);
  asm volatile("s_waitcnt vmcnt(0)" ::: "memory");
  __builtin_amdgcn_s_barrier();
  __builtin_amdgcn_sched_barrier(0);

  for (int t = 0; t < NT; t++) {
    const int cur = t & 1;
    const char* As = (const char*)&A_s[cur][0];
    const char* Bs = (const char*)&B_s[cur][0];
    h8_t bfr[4][2];
    // ================= phase 0 =================
    if (t + 1 < NT) {
      stageA(cur ^ 1, t + 1);
      asm volatile("s_waitcnt vmcnt(4)" ::: "memory");
    } else {
      asm volatile("s_waitcnt vmcnt(0)" ::: "memory");
    }
    __builtin_amdgcn_s_barrier();        // publish buf cur
    __builtin_amdgcn_sched_barrier(0);
#pragma unroll
    for (int n = 0; n < 4; n++)
#pragma unroll
      for (int ks = 0; ks < 2; ks++) {
        int row = wc * 64 + n * 16 + lm;
        bfr[n][ks] = *(const h8_t*)(Bs + row * 128 + (((ks * 4 + lg) ^ (row & 7)) << 4));
      }
    {
      h8_t af[2][2];
#pragma unroll
      for (int mm = 0; mm < 2; mm++)
#pragma unroll
        for (int ks = 0; ks < 2; ks++) {
          int row = wr * 128 + (0 + mm) * 16 + lm;
          af[mm][ks] = *(const h8_t*)(As + row * 128 + (((ks * 4 + lg) ^ (row & 7)) << 4));
        }
      __builtin_amdgcn_s_setprio(1);
#pragma unroll
      for (int mm = 0; mm < 2; mm++)
#pragma unroll
        for (int n = 0; n < 4; n++)
#pragma unroll
          for (int ks = 0; ks < 2; ks++)
            acc[0 + mm][n] = MFMAH(af[mm][ks], bfr[n][ks], acc[0 + mm][n]);
      __builtin_amdgcn_s_setprio(0);
    }
    __builtin_amdgcn_s_barrier();
    __builtin_amdgcn_sched_barrier(0);
    // ================= phase 1 =================
    if (t + 1 < NT) stageB(cur ^ 1, t + 1);
    {
      h8_t af[2][2];
#pragma unroll
      for (int mm = 0; mm < 2; mm++)
#pragma unroll
        for (int ks = 0; ks < 2; ks++) {
          int row = wr * 128 + (2 + mm) * 16 + lm;
          af[mm][ks] = *(const h8_t*)(As + row * 128 + (((ks * 4 + lg) ^ (row & 7)) << 4));
        }
      __builtin_amdgcn_s_setprio(1);
#pragma unroll
      for (int mm = 0; mm < 2; mm++)
#pragma unroll
        for (int n = 0; n < 4; n++)
#pragma unroll
          for (int ks = 0; ks < 2; ks++)
            acc[2 + mm][n] = MFMAH(af[mm][ks], bfr[n][ks], acc[2 + mm][n]);
      __builtin_amdgcn_s_setprio(0);
    }
    __builtin_amdgcn_s_barrier();
    __builtin_amdgcn_sched_barrier(0);
    // ================= phase 2 =================
    {
      h8_t af[2][2];
#pragma unroll
      for (int mm = 0; mm < 2; mm++)
#pragma unroll
        for (int ks = 0; ks < 2; ks++) {
          int row = wr * 128 + (4 + mm) * 16 + lm;
          af[mm][ks] = *(const h8_t*)(As + row * 128 + (((ks * 4 + lg) ^ (row & 7)) << 4));
        }
      __builtin_amdgcn_s_setprio(1);
#pragma unroll
      for (int mm = 0; mm < 2; mm++)
#pragma unroll
        for (int n = 0; n < 4; n++)
#pragma unroll
          for (int ks = 0; ks < 2; ks++)
            acc[4 + mm][n] = MFMAH(af[mm][ks], bfr[n][ks], acc[4 + mm][n]);
      __builtin_amdgcn_s_setprio(0);
    }
    __builtin_amdgcn_s_barrier();
    __builtin_amdgcn_sched_barrier(0);
    // ================= phase 3 =================
    {
      h8_t af[2][2];
#pragma unroll
      for (int mm = 0; mm < 2; mm++)
#pragma unroll
        for (int ks = 0; ks < 2; ks++) {
          int row = wr * 128 + (6 + mm) * 16 + lm;
          af[mm][ks] = *(const h8_t*)(As + row * 128 + (((ks * 4 + lg) ^ (row & 7)) << 4));
        }
      __builtin_amdgcn_s_setprio(1);
#pragma unroll
      for (int mm = 0; mm < 2; mm++)
#pragma unroll
        for (int n = 0; n < 4; n++)
#pragma unroll
          for (int ks = 0; ks < 2; ks++)
            acc[6 + mm][n] = MFMAH(af[mm][ks], bfr[n][ks], acc[6 + mm][n]);
      __builtin_amdgcn_s_setprio(0);
    }
    __builtin_amdgcn_s_barrier();        // all reads of buf cur done
    __builtin_amdgcn_sched_barrier(0);
  }
#pragma unroll
  for (int m = 0; m < 8; m++)
#pragma unroll
    for (int n = 0; n < 4; n++)
#pragma unroll
      for (int r = 0; r < 4; r++)
        C[(size_t)(row0 + wr * 128 + m * 16 + lg * 4 + r) * N + col0 + wc * 64 + n * 16 + lm] = (_Float16)acc[m][n][r];
}

// ---- activations + fused qk->bf16: softmax/clip q,k ; gate ; kb,vb --------
__device__ __forceinline__ float gate_fn(float z) {
  float t = -z;
  float sp = (t > 20.f) ? t : log1pf(expf(t));   // softplus(-z)
  float g = -sp * (1.f / 16.f);                  // log_sigmoid(z)/16
  return fminf(fmaxf(g, -16.f), 16.f);
}

__global__ __launch_bounds__(256) void act_kernel(const _Float16* __restrict__ qkv,
                                                  float* __restrict__ qs,
                                                  float* __restrict__ ksm,
                                                  float* __restrict__ kb,
                                                  float* __restrict__ vb,
                                                  ushort_t* __restrict__ qb16,
                                                  ushort_t* __restrict__ kb16) {
  int wave = blockIdx.x * 4 + (threadIdx.x >> 6);  // (row*16 + h)
  int lane = threadIdx.x & 63;
  int row = wave >> 4, h = wave & 15;
  size_t inb = (size_t)row * NQKV + h * 128;
  size_t base = (size_t)wave * 128;
  float q0 = (float)qkv[inb + lane],        q1 = (float)qkv[inb + 64 + lane];
  float k0 = (float)qkv[inb + 2048 + lane], k1 = (float)qkv[inb + 2048 + 64 + lane];
  float v0 = (float)qkv[inb + 4096 + lane], v1 = (float)qkv[inb + 4096 + 64 + lane];

  qb16[base + lane] = f2bf(q0 * RSQDH);
  qb16[base + 64 + lane] = f2bf(q1 * RSQDH);
  kb16[base + lane] = f2bf(k0);
  kb16[base + 64 + lane] = f2bf(k1);

  float m = fmaxf(q0, q1);
  for (int o = 1; o < 64; o <<= 1) m = fmaxf(m, __shfl_xor(m, o));
  float e0 = expf(q0 - m), e1 = expf(q1 - m);
  float s = e0 + e1;
  for (int o = 1; o < 64; o <<= 1) s += __shfl_xor(s, o);
  float inv = 1.f / s;
  float qs0 = fminf(fmaxf(e0 * inv, EPSC), 1.f - EPSC) * RSQDH;
  float qs1 = fminf(fmaxf(e1 * inv, EPSC), 1.f - EPSC) * RSQDH;

  float mk = fmaxf(k0, k1);
  for (int o = 1; o < 64; o <<= 1) mk = fmaxf(mk, __shfl_xor(mk, o));
  float f0 = expf(k0 - mk), f1 = expf(k1 - mk);
  float sk = f0 + f1;
  for (int o = 1; o < 64; o <<= 1) sk += __shfl_xor(sk, o);
  float invk = 1.f / sk;
  float ks0 = fminf(fmaxf(f0 * invk, EPSC), 1.f - EPSC);
  float ks1 = fminf(fmaxf(f1 * invk, EPSC), 1.f - EPSC);

  float g0 = gate_fn(k0), g1 = gate_fn(k1);

  qs[base + lane] = qs0;        qs[base + 64 + lane] = qs1;
  ksm[base + lane] = ks0;       ksm[base + 64 + lane] = ks1;
  kb[base + lane] = ks0 * g0;   kb[base + 64 + lane] = ks1 * g1;
  vb[base + lane] = v0 * g0;    vb[base + 64 + lane] = v1 * g1;
}

// -------- ksm -> transposed bf16 hi/lo kT[bh][d][n] ------------------------
__global__ __launch_bounds__(256) void k_transpose(const float* __restrict__ ksm,
                                                   ushort_t* __restrict__ kTh,
                                                   ushort_t* __restrict__ kTl) {
  __shared__ float t[32][33];
  const int tid = threadIdx.x;
  const int n0 = blockIdx.x * 32;
  const int d0 = blockIdx.y * 32;
  const int bh = blockIdx.z;
  const int b = bh >> 4, h = bh & 15;
  const int c = tid & 31, rr = tid >> 5;
#pragma unroll
  for (int p = 0; p < 4; p++) {
    int r = p * 8 + rr;
    t[r][c] = ksm[(size_t)(b * 1024 + n0 + r) * D + h * 128 + d0 + c];
  }
  __syncthreads();
#pragma unroll
  for (int p = 0; p < 4; p++) {
    int r = p * 8 + rr;
    float v = t[c][r];
    ushort_t hb = f2bf(v);
    kTh[(size_t)(bh * 128 + d0 + r) * 1024 + n0 + c] = hb;
    kTl[(size_t)(bh * 128 + d0 + r) * 1024 + n0 + c] = f2bf(v - bf2f(hb));
  }
}

// ------- per-chunk (MFMA): L = kb@k^T, attn = q@k^T, fwd-subst -> u, w -----
__global__ __launch_bounds__(256) void chunk_uw_kernel(const float* __restrict__ qs,
                                                       const float* __restrict__ ksm,
                                                       const float* __restrict__ kb,
                                                       const float* __restrict__ vb,
                                                       float* __restrict__ u,
                                                       float* __restrict__ w,
                                                       ushort_t* __restrict__ attn_h,
                                                       ushort_t* __restrict__ attn_l) {
  __shared__ __align__(16) ushort_t kh_s[8192];   // k hi  [64][128] swizzled
  __shared__ __align__(16) ushort_t kl_s[8192];   // k lo
  __shared__ __align__(16) ushort_t xh_s[8192];   // kb hi, then q hi
  __shared__ __align__(16) ushort_t xl_s[8192];   // kb lo, then q lo
  __shared__ float L_s[4096];                     // [64][64]
  const int tid = threadIdx.x, lane = tid & 63, wid = tid >> 6;
  const int lm = lane & 15, lg = lane >> 4;
  const int bh = blockIdx.x >> 4, ci = blockIdx.x & 15;
  const int rowbase = (bh >> 4) * 1024 + ci * 64;
  const int colbase = (bh & 15) * 128;
  const size_t gbase = (size_t)rowbase * D + colbase;
  const int wr = (wid >> 1) * 32, wc = (wid & 1) * 32;

  auto stageM = [&](const float* __restrict__ src, ushort_t* dh, ushort_t* dl) {
#pragma unroll
    for (int it = 0; it < 4; it++) {
      int idx = tid + it * 256;
      int r = idx >> 4, c8 = idx & 15;
      const float* g = src + gbase + (size_t)r * D + c8 * 8;
      float4 v0 = *(const float4*)g;
      float4 v1 = *(const float4*)(g + 4);
      float vv[8] = {v0.x, v0.y, v0.z, v0.w, v1.x, v1.y, v1.z, v1.w};
      s8_t hv, lv;
#pragma unroll
      for (int j = 0; j < 8; j++) {
        ushort_t hb = f2bf(vv[j]);
        hv[j] = (short)hb;
        lv[j] = (short)f2bf(vv[j] - bf2f(hb));
      }
      int byo = r * 256 + ((c8 * 16) ^ ((r & 7) << 4));
      *(s8_t*)((char*)dh + byo) = hv;
      *(s8_t*)((char*)dl + byo) = lv;
    }
  };

  auto mm3 = [&](const ushort_t* Ah, const ushort_t* Al,
                 const ushort_t* Bh, const ushort_t* Bl, f4_t acc[2][2]) {
#pragma unroll
    for (int m = 0; m < 2; m++)
#pragma unroll
      for (int n = 0; n < 2; n++) acc[m][n] = (f4_t){0.f, 0.f, 0.f, 0.f};
#pragma unroll
    for (int term = 0; term < 3; term++) {
      const ushort_t* A = (term == 2) ? Al : Ah;
      const ushort_t* Bsrc = (term == 1) ? Bl : Bh;
#pragma unroll
      for (int ks = 0; ks < 4; ks++) {
        s8_t af[2], bf_[2];
#pragma unroll
        for (int m = 0; m < 2; m++) {
          int row = wr + m * 16 + lm;
          int byo = row * 256 + ((ks * 64 + lg * 16) ^ ((row & 7) << 4));
          af[m] = *(const s8_t*)((const char*)A + byo);
        }
#pragma unroll
        for (int n = 0; n < 2; n++) {
          int row = wc + n * 16 + lm;
          int byo = row * 256 + ((ks * 64 + lg * 16) ^ ((row & 7) << 4));
          bf_[n] = *(const s8_t*)((const char*)Bsrc + byo);
        }
#pragma unroll
        for (int m = 0; m < 2; m++)
#pragma unroll
          for (int n = 0; n < 2; n++)
            acc[m][n] = MFMA16(af[m], bf_[n], acc[m][n]);
      }
    }
  };

  stageM(ksm, kh_s, kl_s);
  stageM(kb, xh_s, xl_s);
  __syncthreads();

  f4_t accL[2][2];
  mm3(xh_s, xl_s, kh_s, kl_s, accL);
#pragma unroll
  for (int m = 0; m < 2; m++)
#pragma unroll
    for (int n = 0; n < 2; n++)
#pragma unroll
      for (int r = 0; r < 4; r++) {
        int i = wr + m * 16 + lg * 4 + r;
        int j = wc + n * 16 + lm;
        L_s[i * 64 + j] = (j < i) ? accL[m][n][r] : 0.f;
      }
  __syncthreads();

  stageM(qs, xh_s, xl_s);
  __syncthreads();

  f4_t accA[2][2];
  mm3(xh_s, xl_s, kh_s, kl_s, accA);
  ushort_t* abh = attn_h + (size_t)blockIdx.x * 4096;
  ushort_t* abl = attn_l + (size_t)blockIdx.x * 4096;
#pragma unroll
  for (int m = 0; m < 2; m++)
#pragma unroll
    for (int n = 0; n < 2; n++)
#pragma unroll
      for (int r = 0; r < 4; r++) {
        int i = wr + m * 16 + lg * 4 + r;
        int j = wc + n * 16 + lm;
        float val = (j <= i) ? accA[m][n][r] : 0.f;
        ushort_t hb = f2bf(val);
        abh[i * 64 + j] = hb;
        abl[i * 64 + j] = f2bf(val - bf2f(hb));
      }

  float x[64];
  const int c = tid & 127;
  const float* rhs = (tid < 128) ? (vb + gbase + c) : (kb + gbase + c);
#pragma unroll
  for (int j = 0; j < 64; j++) x[j] = rhs[(size_t)j * D];
#pragma unroll
  for (int i = 0; i < 64; i++) {
    float xi = x[i];
#pragma unroll
    for (int r2 = i + 1; r2 < 64; r2++) x[r2] -= L_s[r2 * 64 + i] * xi;
  }
  float* dst = (tid < 128) ? u : w;
#pragma unroll
  for (int j = 0; j < 64; j++) dst[gbase + (size_t)j * D + c] = x[j];
}

// ------- sequential scan: grid(32 bh, 8 vgroups), 512 thr ------------------
__global__ __launch_bounds__(512, 2) void scan_kernel(const float* __restrict__ qs,
                                                      const float* __restrict__ u,
                                                      const float* __restrict__ w,
                                                      const ushort_t* __restrict__ kTh_g,
                                                      const ushort_t* __restrict__ kTl_g,
                                                      const ushort_t* __restrict__ ath_g,
                                                      const ushort_t* __restrict__ atl_g,
                                                      float* __restrict__ o_lin) {
  __shared__ __align__(16) ushort_t kT_h[2][8192];   // [k][i] swizzled, dbuf
  __shared__ __align__(16) ushort_t kT_l[2][8192];
  __shared__ __align__(16) ushort_t at_h[2][4096];   // [i][j] swizzled, dbuf
  __shared__ __align__(16) ushort_t at_l[2][4096];
  __shared__ __align__(16) ushort_t Sh_s[16 * 128];  // S^T [c][k] swizzled
  __shared__ __align__(16) ushort_t Sl_s[16 * 128];
  __shared__ __align__(16) ushort_t uh_s[16 * 80];   // u'^T [c][i]
  __shared__ __align__(16) ushort_t ul_s[16 * 80];
  __shared__ __align__(16) float oT[16 * 68];        // q@S partial [c][i]
  const int tid = threadIdx.x;
  const int bh = blockIdx.x;
  const int b = bh >> 4, h = bh & 15;
  const int g = blockIdx.y;            // 0..7 (16 dv cols each)
  const int colbase = h * 128;
  const int vcol = h * 128 + g * 16;
  const int lane = tid & 63, wid = tid >> 6;
  const int lm = lane & 15, lg = lane >> 4;
  const int dsub = lane >> 3;          // 0..7
  const int i8x = (lane & 7) ^ dsub;   // pre-swizzled col group

  for (int i = tid; i < 16 * 128; i += 512) { Sh_s[i] = 0; Sl_s[i] = 0; }

  f4_t acc3[2];                        // persistent S tiles (waves 4-7)
  acc3[0] = (f4_t){0.f, 0.f, 0.f, 0.f};
  acc3[1] = (f4_t){0.f, 0.f, 0.f, 0.f};

  const ushort_t* kThb = kTh_g + (size_t)bh * 128 * 1024;
  const ushort_t* kTlb = kTl_g + (size_t)bh * 128 * 1024;

  auto issue_stage = [&](int buf, int chunk) {
#pragma unroll
    for (int it = 0; it < 2; it++) {
      int seg = it * 8 + wid;               // 0..15 (8 kT rows each)
      int d = seg * 8 + dsub;               // row 0..127
      size_t goff = (size_t)d * 1024 + chunk * 64 + i8x * 8;
      GLOAD16(kThb + goff, (char*)&kT_h[buf][0] + seg * 1024);
      GLOAD16(kTlb + goff, (char*)&kT_l[buf][0] + seg * 1024);
    }
    {
      int i = wid * 8 + dsub;               // attn row 0..63
      size_t asrc = (size_t)(bh * 16 + chunk) * 4096 + i * 64 + i8x * 8;
      GLOAD16(ath_g + asrc, (char*)&at_h[buf][0] + wid * 1024);
      GLOAD16(atl_g + asrc, (char*)&at_l[buf][0] + wid * 1024);
    }
  };

  const bool isU = (wid < 4);
  const int m0 = (isU ? wid : (wid - 4)) * 16;
  const float* Asrc = isU ? w : qs;

  float4 pA[4][2];                      // prefetched w/q fragments (static idx)
  float pu[4];
  auto prefetchA = [&](int chunk) {
    const size_t gb = (size_t)(b * 1024 + chunk * 64) * D;
#pragma unroll
    for (int ks = 0; ks < 4; ks++) {
      const float* ap = Asrc + gb + (size_t)(m0 + lm) * D + colbase + ks * 32 + lg * 8;
      pA[ks][0] = *(const float4*)ap;
      pA[ks][1] = *(const float4*)(ap + 4);
    }
    if (isU) {
#pragma unroll
      for (int r = 0; r < 4; r++)
        pu[r] = u[gb + (size_t)(m0 + lg * 4 + r) * D + vcol + lm];
    }
  };

  issue_stage(0, 0);
  prefetchA(0);
  __syncthreads();                      // S mirror init visible

  for (int chunk = 0; chunk < 16; chunk++) {
    const int cur = chunk & 1;
    const size_t gbase = (size_t)(b * 1024 + chunk * 64) * D;
    if (chunk + 1 < 16) issue_stage(cur ^ 1, chunk + 1);
    // ---- phase1 MFMA from prefetched regs: u' / q@S ----
    {
      f4_t acc = (f4_t){0.f, 0.f, 0.f, 0.f};
#pragma unroll
      for (int ks = 0; ks < 4; ks++) {
        float av[8] = {pA[ks][0].x, pA[ks][0].y, pA[ks][0].z, pA[ks][0].w,
                       pA[ks][1].x, pA[ks][1].y, pA[ks][1].z, pA[ks][1].w};
        s8_t ah, al;
#pragma unroll
        for (int j = 0; j < 8; j++) {
          ushort_t hb = f2bf(av[j]);
          ah[j] = (short)hb;
          al[j] = (short)f2bf(av[j] - bf2f(hb));
        }
        int byo = (lm * 256 + ks * 64 + lg * 16) ^ ((lm & 7) << 4);
        s8_t sh = *(const s8_t*)((const char*)Sh_s + byo);
        s8_t sl = *(const s8_t*)((const char*)Sl_s + byo);
        acc = MFMA16(ah, sh, acc);
        acc = MFMA16(ah, sl, acc);
        acc = MFMA16(al, sh, acc);
      }
      if (isU) {
        float res[4];
#pragma unroll
        for (int r = 0; r < 4; r++) res[r] = pu[r] - acc[r];
        us4_t rh, rl;
#pragma unroll
        for (int r = 0; r < 4; r++) {
          ushort_t hb = f2bf(res[r]);
          rh[r] = hb;
          rl[r] = f2bf(res[r] - bf2f(hb));
        }
        *(us4_t*)&uh_s[lm * 80 + m0 + lg * 4] = rh;
        *(us4_t*)&ul_s[lm * 80 + m0 + lg * 4] = rl;
      } else {
        float4 res = {acc[0], acc[1], acc[2], acc[3]};
        *(float4*)&oT[lm * 68 + m0 + lg * 4] = res;
      }
    }
    __syncthreads();                     // B: u', oT visible; staging drained
    if (chunk + 1 < 16) prefetchA(chunk + 1);
    if (isU) {
      // ---- phase2 MFMA: o = oT + attn @ u' ; store to global ----
      float4 o0 = *(const float4*)&oT[lm * 68 + m0 + lg * 4];
      f4_t acc2 = (f4_t){o0.x, o0.y, o0.z, o0.w};
#pragma unroll
      for (int ks = 0; ks < 2; ks++) {
        int arow = m0 + lm;
        int abyo = arow * 128 + ((ks * 64 + lg * 16) ^ ((arow & 7) << 4));
        s8_t afh = *(const s8_t*)((const char*)&at_h[cur][0] + abyo);
        s8_t afl = *(const s8_t*)((const char*)&at_l[cur][0] + abyo);
        s8_t ufh = *(const s8_t*)&uh_s[lm * 80 + ks * 32 + lg * 8];
        s8_t ufl = *(const s8_t*)&ul_s[lm * 80 + ks * 32 + lg * 8];
        acc2 = MFMA16(afh, ufh, acc2);
        acc2 = MFMA16(afh, ufl, acc2);
        acc2 = MFMA16(afl, ufh, acc2);
      }
#pragma unroll
      for (int r = 0; r < 4; r++)
        o_lin[gbase + (size_t)(m0 + lg * 4 + r) * D + vcol + lm] = acc2[r];
    } else {
      // ---- phase3 MFMA: S += u'^T @ kT (persistent acc) + mirror refresh --
      const int w3 = wid - 4;
      s8_t ufh0 = *(const s8_t*)&uh_s[lm * 80 + 0 * 32 + lg * 8];
      s8_t ufl0 = *(const s8_t*)&ul_s[lm * 80 + 0 * 32 + lg * 8];
      s8_t ufh1 = *(const s8_t*)&uh_s[lm * 80 + 1 * 32 + lg * 8];
      s8_t ufl1 = *(const s8_t*)&ul_s[lm * 80 + 1 * 32 + lg * 8];
#pragma unroll
      for (int t = 0; t < 2; t++) {
        const int krow = (w3 * 2 + t) * 16 + lm;
        int b0 = krow * 128 + ((0 * 64 + lg * 16) ^ ((krow & 7) << 4));
        int b1 = krow * 128 + ((1 * 64 + lg * 16) ^ ((krow & 7) << 4));
        s8_t kh0 = *(const s8_t*)((const char*)&kT_h[cur][0] + b0);
        s8_t kl0 = *(const s8_t*)((const char*)&kT_l[cur][0] + b0);
        s8_t kh1 = *(const s8_t*)((const char*)&kT_h[cur][0] + b1);
        s8_t kl1 = *(const s8_t*)((const char*)&kT_l[cur][0] + b1);
        acc3[t] = MFMA16(ufh0, kh0, acc3[t]);
        acc3[t] = MFMA16(ufh0, kl0, acc3[t]);
        acc3[t] = MFMA16(ufl0, kh0, acc3[t]);
        acc3[t] = MFMA16(ufh1, kh1, acc3[t]);
        acc3[t] = MFMA16(ufh1, kl1, acc3[t]);
        acc3[t] = MFMA16(ufl1, kh1, acc3[t]);
      }
#pragma unroll
      for (int t = 0; t < 2; t++)
#pragma unroll
        for (int r = 0; r < 4; r++) {
          int c = lg * 4 + r;
          int k = (w3 * 2 + t) * 16 + lm;
          float sval = acc3[t][r];
          ushort_t hb = f2bf(sval);
          int sbyo = (c * 256 + k * 2) ^ ((c & 7) << 4);
          *(ushort_t*)((char*)Sh_s + sbyo) = hb;
          *(ushort_t*)((char*)Sl_s + sbyo) = f2bf(sval - bf2f(hb));
        }
    }
    __syncthreads();                     // C: reads done; mirror ordered
  }
}

// -------- v (from fp16 qkv) -> transposed bf16 vt[b][h][d][n] -------------
__global__ __launch_bounds__(256) void v_transpose(const _Float16* __restrict__ qkv,
                                                   ushort_t* __restrict__ vt) {
  __shared__ float t[32][33];
  const int tid = threadIdx.x;
  const int n0 = blockIdx.x * 32;
  const int d0 = blockIdx.y * 32;
  const int bh = blockIdx.z;
  const int b = bh >> 4, h = bh & 15;
  const int c = tid & 31, rr = tid >> 5;
#pragma unroll
  for (int p = 0; p < 4; p++) {
    int r = p * 8 + rr;
    t[r][c] = (float)qkv[(size_t)(b * 1024 + n0 + r) * NQKV + 4096 + h * 128 + d0 + c];
  }
  __syncthreads();
#pragma unroll
  for (int p = 0; p < 4; p++) {
    int r = p * 8 + rr;
    vt[(size_t)(bh * 128 + d0 + r) * 1024 + n0 + c] = f2bf(t[c][r]);
  }
}

// -------- MFMA bf16 flash attention + 0.5/0.5 mix + fp16 out --------------
__global__ __launch_bounds__(256) void attn_mfma(const ushort_t* __restrict__ qb,
                                                 const ushort_t* __restrict__ kb,
                                                 const ushort_t* __restrict__ vt,
                                                 const float* __restrict__ o_lin,
                                                 _Float16* __restrict__ mixh) {
  __shared__ __align__(16) ushort_t K_s[8192];
  __shared__ __align__(16) ushort_t V_s[8192];
  __shared__ __align__(16) ushort_t P_s[4][1152];
  const int tid = threadIdx.x;
  const int lane = tid & 63, wid = tid >> 6;
  const int bh = blockIdx.x;
  const int b = bh >> 4, h = bh & 15;
  const int qt = blockIdx.y;
  const int lm = lane & 15, lg = lane >> 4;

  s8_t qf[4];
  const size_t qrowG = (size_t)(b * 1024 + qt * 64 + wid * 16 + lm);
#pragma unroll
  for (int kb4 = 0; kb4 < 4; kb4++)
    qf[kb4] = *(const s8_t*)(qb + qrowG * D + h * 128 + kb4 * 32 + lg * 8);

  f4_t o[8];
#pragma unroll
  for (int n = 0; n < 8; n++) o[n] = (f4_t){0.f, 0.f, 0.f, 0.f};
  float mrow[4] = {-INFINITY, -INFINITY, -INFINITY, -INFINITY};
  float lrow[4] = {0.f, 0.f, 0.f, 0.f};
  const int myq = qt * 64 + wid * 16 + lg * 4;

  for (int kt = 0; kt <= qt; kt++) {
    __syncthreads();
#pragma unroll
    for (int p = 0; p < 4; p++) {
      int c = tid + p * 256;
      int key = c >> 4, dc = c & 15;
      s8_t v = *(const s8_t*)(kb + (size_t)(b * 1024 + kt * 64 + key) * D + h * 128 + dc * 8);
      int byo = key * 256 + ((dc * 16) ^ ((key & 7) << 4));
      *(s8_t*)((char*)K_s + byo) = v;
    }
#pragma unroll
    for (int p = 0; p < 4; p++) {
      int c = tid + p * 256;
      int d = c >> 3, nc = c & 7;
      s8_t v = *(const s8_t*)(vt + (size_t)(bh * 128 + d) * 1024 + kt * 64 + nc * 8);
      int byo = d * 128 + ((nc * 16) ^ ((d & 7) << 4));
      *(s8_t*)((char*)V_s + byo) = v;
    }
    __syncthreads();

    f4_t s[4];
#pragma unroll
    for (int ks = 0; ks < 4; ks++) {
      f4_t a = (f4_t){0.f, 0.f, 0.f, 0.f};
      int key = ks * 16 + lm;
#pragma unroll
      for (int kb4 = 0; kb4 < 4; kb4++) {
        int byo = key * 256 + ((kb4 * 64 + lg * 16) ^ ((key & 7) << 4));
        s8_t kf = *(const s8_t*)((char*)K_s + byo);
        a = MFMA16(qf[kb4], kf, a);
      }
      s[ks] = a;
    }
    if (kt == qt) {
#pragma unroll
      for (int ks = 0; ks < 4; ks++) {
        int key = kt * 64 + ks * 16 + lm;
#pragma unroll
        for (int r = 0; r < 4; r++)
          if (key > myq + r) s[ks][r] = -INFINITY;
      }
    }
    float mloc[4];
#pragma unroll
    for (int r = 0; r < 4; r++) {
      mloc[r] = fmaxf(fmaxf(s[0][r], s[1][r]), fmaxf(s[2][r], s[3][r]));
      mloc[r] = fmaxf(mloc[r], __shfl_xor(mloc[r], 1));
      mloc[r] = fmaxf(mloc[r], __shfl_xor(mloc[r], 2));
      mloc[r] = fmaxf(mloc[r], __shfl_xor(mloc[r], 4));
      mloc[r] = fmaxf(mloc[r], __shfl_xor(mloc[r], 8));
    }
    float scale[4];
#pragma unroll
    for (int r = 0; r < 4; r++) {
      float mn = fmaxf(mrow[r], mloc[r]);
      scale[r] = __expf(mrow[r] - mn);
      mrow[r] = mn;
    }
    float lad[4] = {0.f, 0.f, 0.f, 0.f};
#pragma unroll
    for (int ks = 0; ks < 4; ks++)
#pragma unroll
      for (int r = 0; r < 4; r++) {
        float p = __expf(s[ks][r] - mrow[r]);
        lad[r] += p;
        P_s[wid][(lg * 4 + r) * 72 + ks * 16 + lm] = f2bf(p);
      }
#pragma unroll
    for (int r = 0; r < 4; r++) {
      lad[r] += __shfl_xor(lad[r], 1);
      lad[r] += __shfl_xor(lad[r], 2);
      lad[r] += __shfl_xor(lad[r], 4);
      lad[r] += __shfl_xor(lad[r], 8);
      lrow[r] = lrow[r] * scale[r] + lad[r];
    }
#pragma unroll
    for (int n = 0; n < 8; n++)
#pragma unroll
      for (int r = 0; r < 4; r++) o[n][r] *= scale[r];

    s8_t pf[2];
#pragma unroll
    for (int ksl = 0; ksl < 2; ksl++)
      pf[ksl] = *(const s8_t*)&P_s[wid][lm * 72 + ksl * 32 + lg * 8];
#pragma unroll
    for (int n = 0; n < 8; n++) {
      int d = n * 16 + lm;
#pragma unroll
      for (int ksl = 0; ksl < 2; ksl++) {
        int byo = d * 128 + ((ksl * 64 + lg * 16) ^ ((d & 7) << 4));
        s8_t vf = *(const s8_t*)((char*)V_s + byo);
        o[n] = MFMA16(pf[ksl], vf, o[n]);
      }
    }
  }

  float invl[4];
#pragma unroll
  for (int r = 0; r < 4; r++) invl[r] = 1.f / lrow[r];
#pragma unroll
  for (int n = 0; n < 8; n++)
#pragma unroll
    for (int r = 0; r < 4; r++) {
      size_t G = (size_t)(b * 1024 + qt * 64 + wid * 16 + lg * 4 + r);
      int dcol = h * 128 + n * 16 + lm;
      float mix = 0.5f * (o[n][r] * invl[r]) + 0.5f * o_lin[G * D + dcol];
      mixh[G * D + dcol] = (_Float16)mix;
    }
}

// ---------------------------------------------------------------------------
extern "C" void kernel_launch(void* const* d_in, const int* in_sizes, int n_in,
                              void* d_out, int out_size, void* d_ws, size_t ws_size,
                              hipStream_t stream) {
  const float* x  = (const float*)d_in[0];
  const float* Wq = (const float*)d_in[1];
  const float* Wk = (const float*)d_in[2];
  const float* Wv = (const float*)d_in[3];
  const float* Wo = (const float*)d_in[4];
  float* out = (float*)d_out;
  float* ws = (float*)d_ws;

  const size_t B = (size_t)NROWS * D;   // 4,194,304 floats per slot
  _Float16* qkv = (_Float16*)(ws + 0 * B);   // [2048][6144] fp16 (slots 0-1)
  float* q_s  = ws + 3 * B;
  float* k_sm = ws + 4 * B;
  float* kbuf = ws + 5 * B;
  float* vbuf = ws + 6 * B;
  float* u    = ws + 7 * B;
  float* w    = ws + 8 * B;
  float* o_lin = kbuf;

  _Float16* x_hi = (_Float16*)u;                    // dead before chunk_uw writes u
  _Float16* Wt   = (_Float16*)(ws + 9 * B);         // QKV weights, dead after gemm8
  ushort_t* attn_h = (ushort_t*)(ws + 9 * B);                 // after gemm8
  ushort_t* attn_l = attn_h + (size_t)2097152;
  ushort_t* kTh_g  = (ushort_t*)(ws + 9 * B + 2097152);       // 4M u16
  ushort_t* kTl_g  = (ushort_t*)(ws + 10 * B);                // 4M u16
  _Float16* Wo_t   = (_Float16*)(ws + 10 * B + 2097152);      // own region
  ushort_t* qb16 = (ushort_t*)(ws + 2 * B);
  ushort_t* kb16 = qb16 + B;
  ushort_t* vt16 = (ushort_t*)vbuf;
  _Float16* mixh = (_Float16*)qkv;

  split_h<<<4096, 256, 0, stream>>>(x, x_hi);
  wsplit4<<<dim3(64, 64, 4), 256, 0, stream>>>(Wq, Wk, Wv, Wo, Wt, Wo_t);
  gemm8<<<8 * 24, 512, 0, stream>>>(x_hi, Wt, qkv, NROWS, NQKV, D);

  act_kernel<<<8192, 256, 0, stream>>>(qkv, q_s, k_sm, kbuf, vbuf, qb16, kb16);
  k_transpose<<<dim3(32, 4, 32), 256, 0, stream>>>(k_sm, kTh_g, kTl_g);
  chunk_uw_kernel<<<512, 256, 0, stream>>>(q_s, k_sm, kbuf, vbuf, u, w, attn_h, attn_l);
  scan_kernel<<<dim3(32, 8), 512, 0, stream>>>(q_s, u, w, kTh_g, kTl_g, attn_h, attn_l, o_lin);

  v_transpose<<<dim3(32, 4, 32), 256, 0, stream>>>(qkv, vt16);
  attn_mfma<<<dim3(32, 16), 256, 0, stream>>>(qb16, kb16, vt16, o_lin, mixh);

  gemm1<<<16 * 16, 256, 0, stream>>>(mixh, Wo_t, out, NROWS, D, D);
}

// Round 18
// 304.734 us; speedup vs baseline: 1.0595x; 1.0595x over previous
//
#include <hip/hip_runtime.h>
#include <hip/hip_bf16.h>
#include <math.h>

#define D 2048
#define NROWS 2048      // b*n
#define NQKV 6144       // fused QKV width
#define H 16
#define DH 128
#define CHK 64
#define NC 16
#define EPSC 1e-6f
#define RSQDH 0.08838834764831845f   // 128^-0.5

typedef unsigned short ushort_t;
typedef __attribute__((ext_vector_type(4))) float f4_t;
typedef __attribute__((ext_vector_type(8))) short s8_t;
typedef __attribute__((ext_vector_type(8))) _Float16 h8_t;
typedef __attribute__((ext_vector_type(4))) _Float16 h4_t;
typedef __attribute__((ext_vector_type(2))) _Float16 h2_t;
typedef __attribute__((ext_vector_type(4))) unsigned short us4_t;
typedef __attribute__((ext_vector_type(2))) unsigned short us2_t;

#define MFMA16(a, b, c) __builtin_amdgcn_mfma_f32_16x16x32_bf16((a), (b), (c), 0, 0, 0)
#define MFMAH(a, b, c)  __builtin_amdgcn_mfma_f32_16x16x32_f16((a), (b), (c), 0, 0, 0)
#define GLOAD16(g, l) __builtin_amdgcn_global_load_lds((const __attribute__((address_space(1))) unsigned int*)(g), (__attribute__((address_space(3))) unsigned int*)(l), 16, 0, 0)

__device__ __forceinline__ ushort_t f2bf(float f) {
  union { float f; unsigned u; } v; v.f = f;
  unsigned r = (v.u + 0x7fffu + ((v.u >> 16) & 1u)) >> 16;
  return (ushort_t)r;
}
__device__ __forceinline__ float bf2f(ushort_t h) {
  union { unsigned u; float f; } v; v.u = ((unsigned)h) << 16;
  return v.f;
}

// ---------------- fp32 -> fp16 (1-term, for QKV GEMM A) --------------------
__global__ __launch_bounds__(256) void split_h(const float* __restrict__ in,
                                               _Float16* __restrict__ hi) {
  int i = (blockIdx.x * 256 + threadIdx.x) * 4;
  float4 v = *(const float4*)(in + i);
  float vv[4] = {v.x, v.y, v.z, v.w};
  h4_t h;
#pragma unroll
  for (int j = 0; j < 4; j++) h[j] = (_Float16)vv[j];
  *(h4_t*)(hi + i) = h;
}

// ------------- all 4 weights: transpose + fp16 round, one launch -----------
__global__ __launch_bounds__(256) void wsplit4(const float* __restrict__ Wq,
                                               const float* __restrict__ Wk,
                                               const float* __restrict__ Wv,
                                               const float* __restrict__ Wo,
                                               _Float16* __restrict__ Tqkv,
                                               _Float16* __restrict__ To) {
  __shared__ float t[32][33];
  const int tid = threadIdx.x;
  const int k0 = blockIdx.y * 32, n0 = blockIdx.x * 32;
  const int z = blockIdx.z;
  const float* W = (z == 0) ? Wq : (z == 1) ? Wk : (z == 2) ? Wv : Wo;
  _Float16* T = (z < 3) ? (Tqkv + (size_t)z * D * D) : To;
  const int c = tid & 31, rr = tid >> 5;
#pragma unroll
  for (int p = 0; p < 4; p++) {
    int r = p * 8 + rr;
    t[r][c] = W[(size_t)(k0 + r) * D + n0 + c];
  }
  __syncthreads();
#pragma unroll
  for (int p = 0; p < 4; p++) {
    int r = p * 8 + rr;
    T[(size_t)(n0 + r) * D + k0 + c] = (_Float16)t[c][r];
  }
}

// ------ fp16 1-term MFMA GEMM (fp32 out, final Wo GEMM) --------------------
__global__ __launch_bounds__(256) void gemm1(const _Float16* __restrict__ Ah,
                                             const _Float16* __restrict__ Bt,
                                             float* __restrict__ C,
                                             int M, int N, int K) {
  __shared__ __align__(16) ushort_t A_s[2][4096];    // [128][32]
  __shared__ __align__(16) ushort_t B_s[2][4096];    // [128 cols][32 k]
  const int tid = threadIdx.x, lane = tid & 63, wid = tid >> 6;
  const int nwg = gridDim.x;
  int bid = blockIdx.x;
  int swz = (bid & 7) * (nwg >> 3) + (bid >> 3);     // XCD swizzle (nwg%8==0)
  const int nbn = N >> 7;
  const int bm = swz / nbn, bn = swz % nbn;
  const int row0 = bm << 7, col0 = bn << 7;
  const int lm = lane & 15, lg = lane >> 4;
  const int wrow = (wid >> 1) * 64, wcol = (wid & 1) * 64;
  const int NT = K >> 5;

  f4_t acc[4][4];
#pragma unroll
  for (int m = 0; m < 4; m++)
#pragma unroll
    for (int n = 0; n < 4; n++) acc[m][n] = (f4_t){0.f, 0.f, 0.f, 0.f};

  auto stage = [&](int buf, int ks) {
    int k0 = ks << 5;
#pragma unroll
    for (int p = 0; p < 2; p++) {
      int c = p * 256 + wid * 64 + lane;             // 16B chunk 0..511
      int r = c >> 2, q = (c & 3) * 8;
      char* la = (char*)&A_s[buf][0] + p * 4096 + wid * 1024;
      GLOAD16(Ah + (size_t)(row0 + r) * K + k0 + q, la);
      char* lb = (char*)&B_s[buf][0] + p * 4096 + wid * 1024;
      GLOAD16(Bt + (size_t)(col0 + r) * K + k0 + q, lb);
    }
  };

  stage(0, 0);
  __syncthreads();
  for (int t = 0; t < NT; t++) {
    int cur = t & 1;
    if (t + 1 < NT) stage(cur ^ 1, t + 1);
    h8_t af[4], bfr[4];
#pragma unroll
    for (int m = 0; m < 4; m++)
      af[m] = *(const h8_t*)&A_s[cur][(wrow + m * 16 + lm) * 32 + lg * 8];
#pragma unroll
    for (int n = 0; n < 4; n++)
      bfr[n] = *(const h8_t*)&B_s[cur][(wcol + n * 16 + lm) * 32 + lg * 8];
#pragma unroll
    for (int m = 0; m < 4; m++)
#pragma unroll
      for (int n = 0; n < 4; n++)
        acc[m][n] = MFMAH(af[m], bfr[n], acc[m][n]);
    __syncthreads();
  }
#pragma unroll
  for (int m = 0; m < 4; m++)
#pragma unroll
    for (int n = 0; n < 4; n++)
#pragma unroll
      for (int r = 0; r < 4; r++)
        C[(size_t)(row0 + wrow + m * 16 + lg * 4 + r) * N + col0 + wcol + n * 16 + lm] = acc[m][n][r];
}

// ------ fp16 1-term MFMA GEMM (fp16 out, QKV projection; proven R16) -------
__global__ __launch_bounds__(256) void gemm1h(const _Float16* __restrict__ Ah,
                                              const _Float16* __restrict__ Bt,
                                              _Float16* __restrict__ C,
                                              int M, int N, int K) {
  __shared__ __align__(16) ushort_t A_s[2][4096];    // [128][32]
  __shared__ __align__(16) ushort_t B_s[2][4096];    // [128 cols][32 k]
  const int tid = threadIdx.x, lane = tid & 63, wid = tid >> 6;
  const int nwg = gridDim.x;
  int bid = blockIdx.x;
  int swz = (bid & 7) * (nwg >> 3) + (bid >> 3);     // XCD swizzle (nwg%8==0)
  const int nbn = N >> 7;
  const int bm = swz / nbn, bn = swz % nbn;
  const int lm = lane & 15, lg = lane >> 4;
  const int row0 = bm << 7, col0 = bn << 7;
  const int wrow = (wid >> 1) * 64, wcol = (wid & 1) * 64;
  const int NT = K >> 5;

  f4_t acc[4][4];
#pragma unroll
  for (int m = 0; m < 4; m++)
#pragma unroll
    for (int n = 0; n < 4; n++) acc[m][n] = (f4_t){0.f, 0.f, 0.f, 0.f};

  auto stage = [&](int buf, int ks) {
    int k0 = ks << 5;
#pragma unroll
    for (int p = 0; p < 2; p++) {
      int c = p * 256 + wid * 64 + lane;             // 16B chunk 0..511
      int r = c >> 2, q = (c & 3) * 8;
      char* la = (char*)&A_s[buf][0] + p * 4096 + wid * 1024;
      GLOAD16(Ah + (size_t)(row0 + r) * K + k0 + q, la);
      char* lb = (char*)&B_s[buf][0] + p * 4096 + wid * 1024;
      GLOAD16(Bt + (size_t)(col0 + r) * K + k0 + q, lb);
    }
  };

  stage(0, 0);
  __syncthreads();
  for (int t = 0; t < NT; t++) {
    int cur = t & 1;
    if (t + 1 < NT) stage(cur ^ 1, t + 1);
    h8_t af[4], bfr[4];
#pragma unroll
    for (int m = 0; m < 4; m++)
      af[m] = *(const h8_t*)&A_s[cur][(wrow + m * 16 + lm) * 32 + lg * 8];
#pragma unroll
    for (int n = 0; n < 4; n++)
      bfr[n] = *(const h8_t*)&B_s[cur][(wcol + n * 16 + lm) * 32 + lg * 8];
#pragma unroll
    for (int m = 0; m < 4; m++)
#pragma unroll
      for (int n = 0; n < 4; n++)
        acc[m][n] = MFMAH(af[m], bfr[n], acc[m][n]);
    __syncthreads();
  }
#pragma unroll
  for (int m = 0; m < 4; m++)
#pragma unroll
    for (int n = 0; n < 4; n++)
#pragma unroll
      for (int r = 0; r < 4; r++)
        C[(size_t)(row0 + wrow + m * 16 + lg * 4 + r) * N + col0 + wcol + n * 16 + lm] = (_Float16)acc[m][n][r];
}

// ---- activations + fused qk->bf16 (vectorized loads/stores) ---------------
__device__ __forceinline__ float gate_fn(float z) {
  float t = -z;
  float sp = (t > 20.f) ? t : log1pf(expf(t));   // softplus(-z)
  float g = -sp * (1.f / 16.f);                  // log_sigmoid(z)/16
  return fminf(fmaxf(g, -16.f), 16.f);
}

__global__ __launch_bounds__(256) void act_kernel(const _Float16* __restrict__ qkv,
                                                  float* __restrict__ qs,
                                                  float* __restrict__ ksm,
                                                  float* __restrict__ kb,
                                                  float* __restrict__ vb,
                                                  ushort_t* __restrict__ qb16,
                                                  ushort_t* __restrict__ kb16) {
  int wave = blockIdx.x * 4 + (threadIdx.x >> 6);  // (row*16 + h)
  int lane = threadIdx.x & 63;
  int row = wave >> 4, h = wave & 15;
  size_t inb = (size_t)row * NQKV + h * 128;
  size_t base = (size_t)wave * 128;
  const int e0 = 2 * lane;                         // lane owns elems e0, e0+1

  h2_t qv = *(const h2_t*)(qkv + inb + e0);
  h2_t kv = *(const h2_t*)(qkv + inb + 2048 + e0);
  h2_t vv = *(const h2_t*)(qkv + inb + 4096 + e0);
  float q0 = (float)qv[0], q1 = (float)qv[1];
  float k0 = (float)kv[0], k1 = (float)kv[1];
  float v0 = (float)vv[0], v1 = (float)vv[1];

  // fused raw-logit bf16 outputs for base attention
  us2_t qo = {f2bf(q0 * RSQDH), f2bf(q1 * RSQDH)};
  us2_t ko = {f2bf(k0), f2bf(k1)};
  *(us2_t*)(qb16 + base + e0) = qo;
  *(us2_t*)(kb16 + base + e0) = ko;

  float m = fmaxf(q0, q1);
  for (int o = 1; o < 64; o <<= 1) m = fmaxf(m, __shfl_xor(m, o));
  float e0f = expf(q0 - m), e1f = expf(q1 - m);
  float s = e0f + e1f;
  for (int o = 1; o < 64; o <<= 1) s += __shfl_xor(s, o);
  float inv = 1.f / s;
  float qs0 = fminf(fmaxf(e0f * inv, EPSC), 1.f - EPSC) * RSQDH;
  float qs1 = fminf(fmaxf(e1f * inv, EPSC), 1.f - EPSC) * RSQDH;

  float mk = fmaxf(k0, k1);
  for (int o = 1; o < 64; o <<= 1) mk = fmaxf(mk, __shfl_xor(mk, o));
  float f0 = expf(k0 - mk), f1 = expf(k1 - mk);
  float sk = f0 + f1;
  for (int o = 1; o < 64; o <<= 1) sk += __shfl_xor(sk, o);
  float invk = 1.f / sk;
  float ks0 = fminf(fmaxf(f0 * invk, EPSC), 1.f - EPSC);
  float ks1 = fminf(fmaxf(f1 * invk, EPSC), 1.f - EPSC);

  float g0 = gate_fn(k0), g1 = gate_fn(k1);

  *(float2*)(qs + base + e0) = make_float2(qs0, qs1);
  *(float2*)(ksm + base + e0) = make_float2(ks0, ks1);
  *(float2*)(kb + base + e0) = make_float2(ks0 * g0, ks1 * g1);
  *(float2*)(vb + base + e0) = make_float2(v0 * g0, v1 * g1);
}

// -------- ksm -> transposed bf16 hi/lo kT[bh][d][n] ------------------------
__global__ __launch_bounds__(256) void k_transpose(const float* __restrict__ ksm,
                                                   ushort_t* __restrict__ kTh,
                                                   ushort_t* __restrict__ kTl) {
  __shared__ float t[32][33];
  const int tid = threadIdx.x;
  const int n0 = blockIdx.x * 32;
  const int d0 = blockIdx.y * 32;
  const int bh = blockIdx.z;
  const int b = bh >> 4, h = bh & 15;
  const int c = tid & 31, rr = tid >> 5;
#pragma unroll
  for (int p = 0; p < 4; p++) {
    int r = p * 8 + rr;
    t[r][c] = ksm[(size_t)(b * 1024 + n0 + r) * D + h * 128 + d0 + c];
  }
  __syncthreads();
#pragma unroll
  for (int p = 0; p < 4; p++) {
    int r = p * 8 + rr;
    float v = t[c][r];
    ushort_t hb = f2bf(v);
    kTh[(size_t)(bh * 128 + d0 + r) * 1024 + n0 + c] = hb;
    kTl[(size_t)(bh * 128 + d0 + r) * 1024 + n0 + c] = f2bf(v - bf2f(hb));
  }
}

// ------- per-chunk (MFMA): L = kb@k^T, attn = q@k^T, fwd-subst -> u, w -----
__global__ __launch_bounds__(256) void chunk_uw_kernel(const float* __restrict__ qs,
                                                       const float* __restrict__ ksm,
                                                       const float* __restrict__ kb,
                                                       const float* __restrict__ vb,
                                                       float* __restrict__ u,
                                                       float* __restrict__ w,
                                                       ushort_t* __restrict__ attn_h,
                                                       ushort_t* __restrict__ attn_l) {
  __shared__ __align__(16) ushort_t kh_s[8192];   // k hi  [64][128] swizzled
  __shared__ __align__(16) ushort_t kl_s[8192];   // k lo
  __shared__ __align__(16) ushort_t xh_s[8192];   // kb hi, then q hi
  __shared__ __align__(16) ushort_t xl_s[8192];   // kb lo, then q lo
  __shared__ float L_s[4096];                     // [64][64]
  const int tid = threadIdx.x, lane = tid & 63, wid = tid >> 6;
  const int lm = lane & 15, lg = lane >> 4;
  const int bh = blockIdx.x >> 4, ci = blockIdx.x & 15;
  const int rowbase = (bh >> 4) * 1024 + ci * 64;
  const int colbase = (bh & 15) * 128;
  const size_t gbase = (size_t)rowbase * D + colbase;
  const int wr = (wid >> 1) * 32, wc = (wid & 1) * 32;

  auto stageM = [&](const float* __restrict__ src, ushort_t* dh, ushort_t* dl) {
#pragma unroll
    for (int it = 0; it < 4; it++) {
      int idx = tid + it * 256;
      int r = idx >> 4, c8 = idx & 15;
      const float* g = src + gbase + (size_t)r * D + c8 * 8;
      float4 v0 = *(const float4*)g;
      float4 v1 = *(const float4*)(g + 4);
      float vv[8] = {v0.x, v0.y, v0.z, v0.w, v1.x, v1.y, v1.z, v1.w};
      s8_t hv, lv;
#pragma unroll
      for (int j = 0; j < 8; j++) {
        ushort_t hb = f2bf(vv[j]);
        hv[j] = (short)hb;
        lv[j] = (short)f2bf(vv[j] - bf2f(hb));
      }
      int byo = r * 256 + ((c8 * 16) ^ ((r & 7) << 4));
      *(s8_t*)((char*)dh + byo) = hv;
      *(s8_t*)((char*)dl + byo) = lv;
    }
  };

  auto mm3 = [&](const ushort_t* Ah, const ushort_t* Al,
                 const ushort_t* Bh, const ushort_t* Bl, f4_t acc[2][2]) {
#pragma unroll
    for (int m = 0; m < 2; m++)
#pragma unroll
      for (int n = 0; n < 2; n++) acc[m][n] = (f4_t){0.f, 0.f, 0.f, 0.f};
#pragma unroll
    for (int term = 0; term < 3; term++) {
      const ushort_t* A = (term == 2) ? Al : Ah;
      const ushort_t* Bsrc = (term == 1) ? Bl : Bh;
#pragma unroll
      for (int ks = 0; ks < 4; ks++) {
        s8_t af[2], bf_[2];
#pragma unroll
        for (int m = 0; m < 2; m++) {
          int row = wr + m * 16 + lm;
          int byo = row * 256 + ((ks * 64 + lg * 16) ^ ((row & 7) << 4));
          af[m] = *(const s8_t*)((const char*)A + byo);
        }
#pragma unroll
        for (int n = 0; n < 2; n++) {
          int row = wc + n * 16 + lm;
          int byo = row * 256 + ((ks * 64 + lg * 16) ^ ((row & 7) << 4));
          bf_[n] = *(const s8_t*)((const char*)Bsrc + byo);
        }
#pragma unroll
        for (int m = 0; m < 2; m++)
#pragma unroll
          for (int n = 0; n < 2; n++)
            acc[m][n] = MFMA16(af[m], bf_[n], acc[m][n]);
      }
    }
  };

  stageM(ksm, kh_s, kl_s);
  stageM(kb, xh_s, xl_s);
  __syncthreads();

  f4_t accL[2][2];
  mm3(xh_s, xl_s, kh_s, kl_s, accL);
#pragma unroll
  for (int m = 0; m < 2; m++)
#pragma unroll
    for (int n = 0; n < 2; n++)
#pragma unroll
      for (int r = 0; r < 4; r++) {
        int i = wr + m * 16 + lg * 4 + r;
        int j = wc + n * 16 + lm;
        L_s[i * 64 + j] = (j < i) ? accL[m][n][r] : 0.f;
      }
  __syncthreads();

  stageM(qs, xh_s, xl_s);
  __syncthreads();

  f4_t accA[2][2];
  mm3(xh_s, xl_s, kh_s, kl_s, accA);
  ushort_t* abh = attn_h + (size_t)blockIdx.x * 4096;
  ushort_t* abl = attn_l + (size_t)blockIdx.x * 4096;
#pragma unroll
  for (int m = 0; m < 2; m++)
#pragma unroll
    for (int n = 0; n < 2; n++)
#pragma unroll
      for (int r = 0; r < 4; r++) {
        int i = wr + m * 16 + lg * 4 + r;
        int j = wc + n * 16 + lm;
        float val = (j <= i) ? accA[m][n][r] : 0.f;
        ushort_t hb = f2bf(val);
        abh[i * 64 + j] = hb;
        abl[i * 64 + j] = f2bf(val - bf2f(hb));
      }

  float x[64];
  const int c = tid & 127;
  const float* rhs = (tid < 128) ? (vb + gbase + c) : (kb + gbase + c);
#pragma unroll
  for (int j = 0; j < 64; j++) x[j] = rhs[(size_t)j * D];
#pragma unroll
  for (int i = 0; i < 64; i++) {
    float xi = x[i];
#pragma unroll
    for (int r2 = i + 1; r2 < 64; r2++) x[r2] -= L_s[r2 * 64 + i] * xi;
  }
  float* dst = (tid < 128) ? u : w;
#pragma unroll
  for (int j = 0; j < 64; j++) dst[gbase + (size_t)j * D + c] = x[j];
}

// ------- sequential scan: grid(32 bh, 8 vgroups), 512 thr ------------------
__global__ __launch_bounds__(512, 2) void scan_kernel(const float* __restrict__ qs,
                                                      const float* __restrict__ u,
                                                      const float* __restrict__ w,
                                                      const ushort_t* __restrict__ kTh_g,
                                                      const ushort_t* __restrict__ kTl_g,
                                                      const ushort_t* __restrict__ ath_g,
                                                      const ushort_t* __restrict__ atl_g,
                                                      float* __restrict__ o_lin) {
  __shared__ __align__(16) ushort_t kT_h[2][8192];   // [k][i] swizzled, dbuf
  __shared__ __align__(16) ushort_t kT_l[2][8192];
  __shared__ __align__(16) ushort_t at_h[2][4096];   // [i][j] swizzled, dbuf
  __shared__ __align__(16) ushort_t at_l[2][4096];
  __shared__ __align__(16) ushort_t Sh_s[16 * 128];  // S^T [c][k] swizzled
  __shared__ __align__(16) ushort_t Sl_s[16 * 128];
  __shared__ __align__(16) ushort_t uh_s[16 * 80];   // u'^T [c][i]
  __shared__ __align__(16) ushort_t ul_s[16 * 80];
  __shared__ __align__(16) float oT[16 * 68];        // q@S partial [c][i]
  const int tid = threadIdx.x;
  const int bh = blockIdx.x;
  const int b = bh >> 4, h = bh & 15;
  const int g = blockIdx.y;            // 0..7 (16 dv cols each)
  const int colbase = h * 128;
  const int vcol = h * 128 + g * 16;
  const int lane = tid & 63, wid = tid >> 6;
  const int lm = lane & 15, lg = lane >> 4;
  const int dsub = lane >> 3;          // 0..7
  const int i8x = (lane & 7) ^ dsub;   // pre-swizzled col group

  for (int i = tid; i < 16 * 128; i += 512) { Sh_s[i] = 0; Sl_s[i] = 0; }

  f4_t acc3[2];                        // persistent S tiles (waves 4-7)
  acc3[0] = (f4_t){0.f, 0.f, 0.f, 0.f};
  acc3[1] = (f4_t){0.f, 0.f, 0.f, 0.f};

  const ushort_t* kThb = kTh_g + (size_t)bh * 128 * 1024;
  const ushort_t* kTlb = kTl_g + (size_t)bh * 128 * 1024;

  auto issue_stage = [&](int buf, int chunk) {
#pragma unroll
    for (int it = 0; it < 2; it++) {
      int seg = it * 8 + wid;               // 0..15 (8 kT rows each)
      int d = seg * 8 + dsub;               // row 0..127
      size_t goff = (size_t)d * 1024 + chunk * 64 + i8x * 8;
      GLOAD16(kThb + goff, (char*)&kT_h[buf][0] + seg * 1024);
      GLOAD16(kTlb + goff, (char*)&kT_l[buf][0] + seg * 1024);
    }
    {
      int i = wid * 8 + dsub;               // attn row 0..63
      size_t asrc = (size_t)(bh * 16 + chunk) * 4096 + i * 64 + i8x * 8;
      GLOAD16(ath_g + asrc, (char*)&at_h[buf][0] + wid * 1024);
      GLOAD16(atl_g + asrc, (char*)&at_l[buf][0] + wid * 1024);
    }
  };

  const bool isU = (wid < 4);
  const int m0 = (isU ? wid : (wid - 4)) * 16;
  const float* Asrc = isU ? w : qs;

  float4 pA[4][2];                      // prefetched w/q fragments (static idx)
  float pu[4];
  auto prefetchA = [&](int chunk) {
    const size_t gb = (size_t)(b * 1024 + chunk * 64) * D;
#pragma unroll
    for (int ks = 0; ks < 4; ks++) {
      const float* ap = Asrc + gb + (size_t)(m0 + lm) * D + colbase + ks * 32 + lg * 8;
      pA[ks][0] = *(const float4*)ap;
      pA[ks][1] = *(const float4*)(ap + 4);
    }
    if (isU) {
#pragma unroll
      for (int r = 0; r < 4; r++)
        pu[r] = u[gb + (size_t)(m0 + lg * 4 + r) * D + vcol + lm];
    }
  };

  issue_stage(0, 0);
  prefetchA(0);
  __syncthreads();                      // S mirror init visible

  for (int chunk = 0; chunk < 16; chunk++) {
    const int cur = chunk & 1;
    const size_t gbase = (size_t)(b * 1024 + chunk * 64) * D;
    if (chunk + 1 < 16) issue_stage(cur ^ 1, chunk + 1);
    // ---- phase1 MFMA from prefetched regs: u' / q@S ----
    {
      f4_t acc = (f4_t){0.f, 0.f, 0.f, 0.f};
#pragma unroll
      for (int ks = 0; ks < 4; ks++) {
        float av[8] = {pA[ks][0].x, pA[ks][0].y, pA[ks][0].z, pA[ks][0].w,
                       pA[ks][1].x, pA[ks][1].y, pA[ks][1].z, pA[ks][1].w};
        s8_t ah, al;
#pragma unroll
        for (int j = 0; j < 8; j++) {
          ushort_t hb = f2bf(av[j]);
          ah[j] = (short)hb;
          al[j] = (short)f2bf(av[j] - bf2f(hb));
        }
        int byo = (lm * 256 + ks * 64 + lg * 16) ^ ((lm & 7) << 4);
        s8_t sh = *(const s8_t*)((const char*)Sh_s + byo);
        s8_t sl = *(const s8_t*)((const char*)Sl_s + byo);
        acc = MFMA16(ah, sh, acc);
        acc = MFMA16(ah, sl, acc);
        acc = MFMA16(al, sh, acc);
      }
      if (isU) {
        float res[4];
#pragma unroll
        for (int r = 0; r < 4; r++) res[r] = pu[r] - acc[r];
        us4_t rh, rl;
#pragma unroll
        for (int r = 0; r < 4; r++) {
          ushort_t hb = f2bf(res[r]);
          rh[r] = hb;
          rl[r] = f2bf(res[r] - bf2f(hb));
        }
        *(us4_t*)&uh_s[lm * 80 + m0 + lg * 4] = rh;
        *(us4_t*)&ul_s[lm * 80 + m0 + lg * 4] = rl;
      } else {
        float4 res = {acc[0], acc[1], acc[2], acc[3]};
        *(float4*)&oT[lm * 68 + m0 + lg * 4] = res;
      }
    }
    __syncthreads();                     // B: u', oT visible; staging drained
    if (chunk + 1 < 16) prefetchA(chunk + 1);
    if (isU) {
      // ---- phase2 MFMA: o = oT + attn @ u' ; store to global ----
      float4 o0 = *(const float4*)&oT[lm * 68 + m0 + lg * 4];
      f4_t acc2 = (f4_t){o0.x, o0.y, o0.z, o0.w};
#pragma unroll
      for (int ks = 0; ks < 2; ks++) {
        int arow = m0 + lm;
        int abyo = arow * 128 + ((ks * 64 + lg * 16) ^ ((arow & 7) << 4));
        s8_t afh = *(const s8_t*)((const char*)&at_h[cur][0] + abyo);
        s8_t afl = *(const s8_t*)((const char*)&at_l[cur][0] + abyo);
        s8_t ufh = *(const s8_t*)&uh_s[lm * 80 + ks * 32 + lg * 8];
        s8_t ufl = *(const s8_t*)&ul_s[lm * 80 + ks * 32 + lg * 8];
        acc2 = MFMA16(afh, ufh, acc2);
        acc2 = MFMA16(afh, ufl, acc2);
        acc2 = MFMA16(afl, ufh, acc2);
      }
#pragma unroll
      for (int r = 0; r < 4; r++)
        o_lin[gbase + (size_t)(m0 + lg * 4 + r) * D + vcol + lm] = acc2[r];
    } else {
      // ---- phase3 MFMA: S += u'^T @ kT (persistent acc) + mirror refresh --
      const int w3 = wid - 4;
      s8_t ufh0 = *(const s8_t*)&uh_s[lm * 80 + 0 * 32 + lg * 8];
      s8_t ufl0 = *(const s8_t*)&ul_s[lm * 80 + 0 * 32 + lg * 8];
      s8_t ufh1 = *(const s8_t*)&uh_s[lm * 80 + 1 * 32 + lg * 8];
      s8_t ufl1 = *(const s8_t*)&ul_s[lm * 80 + 1 * 32 + lg * 8];
#pragma unroll
      for (int t = 0; t < 2; t++) {
        const int krow = (w3 * 2 + t) * 16 + lm;
        int b0 = krow * 128 + ((0 * 64 + lg * 16) ^ ((krow & 7) << 4));
        int b1 = krow * 128 + ((1 * 64 + lg * 16) ^ ((krow & 7) << 4));
        s8_t kh0 = *(const s8_t*)((const char*)&kT_h[cur][0] + b0);
        s8_t kl0 = *(const s8_t*)((const char*)&kT_l[cur][0] + b0);
        s8_t kh1 = *(const s8_t*)((const char*)&kT_h[cur][0] + b1);
        s8_t kl1 = *(const s8_t*)((const char*)&kT_l[cur][0] + b1);
        acc3[t] = MFMA16(ufh0, kh0, acc3[t]);
        acc3[t] = MFMA16(ufh0, kl0, acc3[t]);
        acc3[t] = MFMA16(ufl0, kh0, acc3[t]);
        acc3[t] = MFMA16(ufh1, kh1, acc3[t]);
        acc3[t] = MFMA16(ufh1, kl1, acc3[t]);
        acc3[t] = MFMA16(ufl1, kh1, acc3[t]);
      }
#pragma unroll
      for (int t = 0; t < 2; t++)
#pragma unroll
        for (int r = 0; r < 4; r++) {
          int c = lg * 4 + r;
          int k = (w3 * 2 + t) * 16 + lm;
          float sval = acc3[t][r];
          ushort_t hb = f2bf(sval);
          int sbyo = (c * 256 + k * 2) ^ ((c & 7) << 4);
          *(ushort_t*)((char*)Sh_s + sbyo) = hb;
          *(ushort_t*)((char*)Sl_s + sbyo) = f2bf(sval - bf2f(hb));
        }
    }
    __syncthreads();                     // C: reads done; mirror ordered
  }
}

// -------- v (from fp16 qkv) -> transposed bf16 vt[b][h][d][n] -------------
__global__ __launch_bounds__(256) void v_transpose(const _Float16* __restrict__ qkv,
                                                   ushort_t* __restrict__ vt) {
  __shared__ float t[32][33];
  const int tid = threadIdx.x;
  const int n0 = blockIdx.x * 32;
  const int d0 = blockIdx.y * 32;
  const int bh = blockIdx.z;
  const int b = bh >> 4, h = bh & 15;
  const int c = tid & 31, rr = tid >> 5;
#pragma unroll
  for (int p = 0; p < 4; p++) {
    int r = p * 8 + rr;
    t[r][c] = (float)qkv[(size_t)(b * 1024 + n0 + r) * NQKV + 4096 + h * 128 + d0 + c];
  }
  __syncthreads();
#pragma unroll
  for (int p = 0; p < 4; p++) {
    int r = p * 8 + rr;
    vt[(size_t)(bh * 128 + d0 + r) * 1024 + n0 + c] = f2bf(t[c][r]);
  }
}

// -------- MFMA bf16 flash attention + 0.5/0.5 mix + fp16 out --------------
__global__ __launch_bounds__(256) void attn_mfma(const ushort_t* __restrict__ qb,
                                                 const ushort_t* __restrict__ kb,
                                                 const ushort_t* __restrict__ vt,
                                                 const float* __restrict__ o_lin,
                                                 _Float16* __restrict__ mixh) {
  __shared__ __align__(16) ushort_t K_s[8192];
  __shared__ __align__(16) ushort_t V_s[8192];
  __shared__ __align__(16) ushort_t P_s[4][1152];
  const int tid = threadIdx.x;
  const int lane = tid & 63, wid = tid >> 6;
  const int bh = blockIdx.x;
  const int b = bh >> 4, h = bh & 15;
  const int qt = blockIdx.y;
  const int lm = lane & 15, lg = lane >> 4;

  s8_t qf[4];
  const size_t qrowG = (size_t)(b * 1024 + qt * 64 + wid * 16 + lm);
#pragma unroll
  for (int kb4 = 0; kb4 < 4; kb4++)
    qf[kb4] = *(const s8_t*)(qb + qrowG * D + h * 128 + kb4 * 32 + lg * 8);

  f4_t o[8];
#pragma unroll
  for (int n = 0; n < 8; n++) o[n] = (f4_t){0.f, 0.f, 0.f, 0.f};
  float mrow[4] = {-INFINITY, -INFINITY, -INFINITY, -INFINITY};
  float lrow[4] = {0.f, 0.f, 0.f, 0.f};
  const int myq = qt * 64 + wid * 16 + lg * 4;

  for (int kt = 0; kt <= qt; kt++) {
    __syncthreads();
#pragma unroll
    for (int p = 0; p < 4; p++) {
      int c = tid + p * 256;
      int key = c >> 4, dc = c & 15;
      s8_t v = *(const s8_t*)(kb + (size_t)(b * 1024 + kt * 64 + key) * D + h * 128 + dc * 8);
      int byo = key * 256 + ((dc * 16) ^ ((key & 7) << 4));
      *(s8_t*)((char*)K_s + byo) = v;
    }
#pragma unroll
    for (int p = 0; p < 4; p++) {
      int c = tid + p * 256;
      int d = c >> 3, nc = c & 7;
      s8_t v = *(const s8_t*)(vt + (size_t)(bh * 128 + d) * 1024 + kt * 64 + nc * 8);
      int byo = d * 128 + ((nc * 16) ^ ((d & 7) << 4));
      *(s8_t*)((char*)V_s + byo) = v;
    }
    __syncthreads();

    f4_t s[4];
#pragma unroll
    for (int ks = 0; ks < 4; ks++) {
      f4_t a = (f4_t){0.f, 0.f, 0.f, 0.f};
      int key = ks * 16 + lm;
#pragma unroll
      for (int kb4 = 0; kb4 < 4; kb4++) {
        int byo = key * 256 + ((kb4 * 64 + lg * 16) ^ ((key & 7) << 4));
        s8_t kf = *(const s8_t*)((char*)K_s + byo);
        a = MFMA16(qf[kb4], kf, a);
      }
      s[ks] = a;
    }
    if (kt == qt) {
#pragma unroll
      for (int ks = 0; ks < 4; ks++) {
        int key = kt * 64 + ks * 16 + lm;
#pragma unroll
        for (int r = 0; r < 4; r++)
          if (key > myq + r) s[ks][r] = -INFINITY;
      }
    }
    float mloc[4];
#pragma unroll
    for (int r = 0; r < 4; r++) {
      mloc[r] = fmaxf(fmaxf(s[0][r], s[1][r]), fmaxf(s[2][r], s[3][r]));
      mloc[r] = fmaxf(mloc[r], __shfl_xor(mloc[r], 1));
      mloc[r] = fmaxf(mloc[r], __shfl_xor(mloc[r], 2));
      mloc[r] = fmaxf(mloc[r], __shfl_xor(mloc[r], 4));
      mloc[r] = fmaxf(mloc[r], __shfl_xor(mloc[r], 8));
    }
    float scale[4];
#pragma unroll
    for (int r = 0; r < 4; r++) {
      float mn = fmaxf(mrow[r], mloc[r]);
      scale[r] = __expf(mrow[r] - mn);
      mrow[r] = mn;
    }
    float lad[4] = {0.f, 0.f, 0.f, 0.f};
#pragma unroll
    for (int ks = 0; ks < 4; ks++)
#pragma unroll
      for (int r = 0; r < 4; r++) {
        float p = __expf(s[ks][r] - mrow[r]);
        lad[r] += p;
        P_s[wid][(lg * 4 + r) * 72 + ks * 16 + lm] = f2bf(p);
      }
#pragma unroll
    for (int r = 0; r < 4; r++) {
      lad[r] += __shfl_xor(lad[r], 1);
      lad[r] += __shfl_xor(lad[r], 2);
      lad[r] += __shfl_xor(lad[r], 4);
      lad[r] += __shfl_xor(lad[r], 8);
      lrow[r] = lrow[r] * scale[r] + lad[r];
    }
#pragma unroll
    for (int n = 0; n < 8; n++)
#pragma unroll
      for (int r = 0; r < 4; r++) o[n][r] *= scale[r];

    s8_t pf[2];
#pragma unroll
    for (int ksl = 0; ksl < 2; ksl++)
      pf[ksl] = *(const s8_t*)&P_s[wid][lm * 72 + ksl * 32 + lg * 8];
#pragma unroll
    for (int n = 0; n < 8; n++) {
      int d = n * 16 + lm;
#pragma unroll
      for (int ksl = 0; ksl < 2; ksl++) {
        int byo = d * 128 + ((ksl * 64 + lg * 16) ^ ((d & 7) << 4));
        s8_t vf = *(const s8_t*)((char*)V_s + byo);
        o[n] = MFMA16(pf[ksl], vf, o[n]);
      }
    }
  }

  float invl[4];
#pragma unroll
  for (int r = 0; r < 4; r++) invl[r] = 1.f / lrow[r];
#pragma unroll
  for (int n = 0; n < 8; n++)
#pragma unroll
    for (int r = 0; r < 4; r++) {
      size_t G = (size_t)(b * 1024 + qt * 64 + wid * 16 + lg * 4 + r);
      int dcol = h * 128 + n * 16 + lm;
      float mix = 0.5f * (o[n][r] * invl[r]) + 0.5f * o_lin[G * D + dcol];
      mixh[G * D + dcol] = (_Float16)mix;
    }
}

// ---------------------------------------------------------------------------
extern "C" void kernel_launch(void* const* d_in, const int* in_sizes, int n_in,
                              void* d_out, int out_size, void* d_ws, size_t ws_size,
                              hipStream_t stream) {
  const float* x  = (const float*)d_in[0];
  const float* Wq = (const float*)d_in[1];
  const float* Wk = (const float*)d_in[2];
  const float* Wv = (const float*)d_in[3];
  const float* Wo = (const float*)d_in[4];
  float* out = (float*)d_out;
  float* ws = (float*)d_ws;

  const size_t B = (size_t)NROWS * D;   // 4,194,304 floats per slot
  _Float16* qkv = (_Float16*)(ws + 0 * B);   // [2048][6144] fp16 (slots 0-1)
  float* q_s  = ws + 3 * B;
  float* k_sm = ws + 4 * B;
  float* kbuf = ws + 5 * B;
  float* vbuf = ws + 6 * B;
  float* u    = ws + 7 * B;
  float* w    = ws + 8 * B;
  float* o_lin = kbuf;

  _Float16* x_hi = (_Float16*)u;                    // dead before chunk_uw writes u
  _Float16* Wt   = (_Float16*)(ws + 9 * B);         // QKV weights, dead after gemm1h
  ushort_t* attn_h = (ushort_t*)(ws + 9 * B);                 // after gemm1h
  ushort_t* attn_l = attn_h + (size_t)2097152;
  ushort_t* kTh_g  = (ushort_t*)(ws + 9 * B + 2097152);       // 4M u16
  ushort_t* kTl_g  = (ushort_t*)(ws + 10 * B);                // 4M u16
  _Float16* Wo_t   = (_Float16*)(ws + 10 * B + 2097152);      // own region
  ushort_t* qb16 = (ushort_t*)(ws + 2 * B);
  ushort_t* kb16 = qb16 + B;
  ushort_t* vt16 = (ushort_t*)vbuf;
  _Float16* mixh = (_Float16*)qkv;

  split_h<<<4096, 256, 0, stream>>>(x, x_hi);
  wsplit4<<<dim3(64, 64, 4), 256, 0, stream>>>(Wq, Wk, Wv, Wo, Wt, Wo_t);
  gemm1h<<<16 * 48, 256, 0, stream>>>(x_hi, Wt, qkv, NROWS, NQKV, D);

  act_kernel<<<8192, 256, 0, stream>>>(qkv, q_s, k_sm, kbuf, vbuf, qb16, kb16);
  k_transpose<<<dim3(32, 4, 32), 256, 0, stream>>>(k_sm, kTh_g, kTl_g);
  chunk_uw_kernel<<<512, 256, 0, stream>>>(q_s, k_sm, kbuf, vbuf, u, w, attn_h, attn_l);
  scan_kernel<<<dim3(32, 8), 512, 0, stream>>>(q_s, u, w, kTh_g, kTl_g, attn_h, attn_l, o_lin);

  v_transpose<<<dim3(32, 4, 32), 256, 0, stream>>>(qkv, vt16);
  attn_mfma<<<dim3(32, 16), 256, 0, stream>>>(qb16, kb16, vt16, o_lin, mixh);

  gemm1<<<16 * 16, 256, 0, stream>>>(mixh, Wo_t, out, NROWS, D, D);
}

// Round 19
// 285.469 us; speedup vs baseline: 1.1310x; 1.0675x over previous
//
#include <hip/hip_runtime.h>
#include <hip/hip_bf16.h>
#include <math.h>

#define D 2048
#define NROWS 2048      // b*n
#define NQKV 6144       // fused QKV width
#define H 16
#define DH 128
#define CHK 64
#define NC 16
#define EPSC 1e-6f
#define RSQDH 0.08838834764831845f   // 128^-0.5

typedef unsigned short ushort_t;
typedef __attribute__((ext_vector_type(4))) float f4_t;
typedef __attribute__((ext_vector_type(8))) short s8_t;
typedef __attribute__((ext_vector_type(8))) _Float16 h8_t;
typedef __attribute__((ext_vector_type(4))) _Float16 h4_t;
typedef __attribute__((ext_vector_type(2))) _Float16 h2_t;
typedef __attribute__((ext_vector_type(4))) unsigned short us4_t;
typedef __attribute__((ext_vector_type(2))) unsigned short us2_t;

#define MFMA16(a, b, c) __builtin_amdgcn_mfma_f32_16x16x32_bf16((a), (b), (c), 0, 0, 0)
#define MFMAH(a, b, c)  __builtin_amdgcn_mfma_f32_16x16x32_f16((a), (b), (c), 0, 0, 0)
#define GLOAD16(g, l) __builtin_amdgcn_global_load_lds((const __attribute__((address_space(1))) unsigned int*)(g), (__attribute__((address_space(3))) unsigned int*)(l), 16, 0, 0)

__device__ __forceinline__ ushort_t f2bf(float f) {
  union { float f; unsigned u; } v; v.f = f;
  unsigned r = (v.u + 0x7fffu + ((v.u >> 16) & 1u)) >> 16;
  return (ushort_t)r;
}
__device__ __forceinline__ float bf2f(ushort_t h) {
  union { unsigned u; float f; } v; v.u = ((unsigned)h) << 16;
  return v.f;
}

// ---------------- fp32 -> fp16 (1-term, for QKV GEMM A) --------------------
__global__ __launch_bounds__(256) void split_h(const float* __restrict__ in,
                                               _Float16* __restrict__ hi) {
  int i = (blockIdx.x * 256 + threadIdx.x) * 4;
  float4 v = *(const float4*)(in + i);
  float vv[4] = {v.x, v.y, v.z, v.w};
  h4_t h;
#pragma unroll
  for (int j = 0; j < 4; j++) h[j] = (_Float16)vv[j];
  *(h4_t*)(hi + i) = h;
}

// ------------- all 4 weights: transpose + fp16 round, one launch -----------
__global__ __launch_bounds__(256) void wsplit4(const float* __restrict__ Wq,
                                               const float* __restrict__ Wk,
                                               const float* __restrict__ Wv,
                                               const float* __restrict__ Wo,
                                               _Float16* __restrict__ Tqkv,
                                               _Float16* __restrict__ To) {
  __shared__ float t[32][33];
  const int tid = threadIdx.x;
  const int k0 = blockIdx.y * 32, n0 = blockIdx.x * 32;
  const int z = blockIdx.z;
  const float* W = (z == 0) ? Wq : (z == 1) ? Wk : (z == 2) ? Wv : Wo;
  _Float16* T = (z < 3) ? (Tqkv + (size_t)z * D * D) : To;
  const int c = tid & 31, rr = tid >> 5;
#pragma unroll
  for (int p = 0; p < 4; p++) {
    int r = p * 8 + rr;
    t[r][c] = W[(size_t)(k0 + r) * D + n0 + c];
  }
  __syncthreads();
#pragma unroll
  for (int p = 0; p < 4; p++) {
    int r = p * 8 + rr;
    T[(size_t)(n0 + r) * D + k0 + c] = (_Float16)t[c][r];
  }
}

// ------ fp16 1-term MFMA GEMM (fp32 out, final Wo GEMM) --------------------
__global__ __launch_bounds__(256) void gemm1(const _Float16* __restrict__ Ah,
                                             const _Float16* __restrict__ Bt,
                                             float* __restrict__ C,
                                             int M, int N, int K) {
  __shared__ __align__(16) ushort_t A_s[2][4096];    // [128][32]
  __shared__ __align__(16) ushort_t B_s[2][4096];    // [128 cols][32 k]
  const int tid = threadIdx.x, lane = tid & 63, wid = tid >> 6;
  const int nwg = gridDim.x;
  int bid = blockIdx.x;
  int swz = (bid & 7) * (nwg >> 3) + (bid >> 3);     // XCD swizzle (nwg%8==0)
  const int nbn = N >> 7;
  const int bm = swz / nbn, bn = swz % nbn;
  const int row0 = bm << 7, col0 = bn << 7;
  const int lm = lane & 15, lg = lane >> 4;
  const int wrow = (wid >> 1) * 64, wcol = (wid & 1) * 64;
  const int NT = K >> 5;

  f4_t acc[4][4];
#pragma unroll
  for (int m = 0; m < 4; m++)
#pragma unroll
    for (int n = 0; n < 4; n++) acc[m][n] = (f4_t){0.f, 0.f, 0.f, 0.f};

  auto stage = [&](int buf, int ks) {
    int k0 = ks << 5;
#pragma unroll
    for (int p = 0; p < 2; p++) {
      int c = p * 256 + wid * 64 + lane;             // 16B chunk 0..511
      int r = c >> 2, q = (c & 3) * 8;
      char* la = (char*)&A_s[buf][0] + p * 4096 + wid * 1024;
      GLOAD16(Ah + (size_t)(row0 + r) * K + k0 + q, la);
      char* lb = (char*)&B_s[buf][0] + p * 4096 + wid * 1024;
      GLOAD16(Bt + (size_t)(col0 + r) * K + k0 + q, lb);
    }
  };

  stage(0, 0);
  __syncthreads();
  for (int t = 0; t < NT; t++) {
    int cur = t & 1;
    if (t + 1 < NT) stage(cur ^ 1, t + 1);
    h8_t af[4], bfr[4];
#pragma unroll
    for (int m = 0; m < 4; m++)
      af[m] = *(const h8_t*)&A_s[cur][(wrow + m * 16 + lm) * 32 + lg * 8];
#pragma unroll
    for (int n = 0; n < 4; n++)
      bfr[n] = *(const h8_t*)&B_s[cur][(wcol + n * 16 + lm) * 32 + lg * 8];
#pragma unroll
    for (int m = 0; m < 4; m++)
#pragma unroll
      for (int n = 0; n < 4; n++)
        acc[m][n] = MFMAH(af[m], bfr[n], acc[m][n]);
    __syncthreads();
  }
#pragma unroll
  for (int m = 0; m < 4; m++)
#pragma unroll
    for (int n = 0; n < 4; n++)
#pragma unroll
      for (int r = 0; r < 4; r++)
        C[(size_t)(row0 + wrow + m * 16 + lg * 4 + r) * N + col0 + wcol + n * 16 + lm] = acc[m][n][r];
}

// ------ fp16 1-term MFMA GEMM (fp16 out, QKV projection) -------------------
__global__ __launch_bounds__(256) void gemm1h(const _Float16* __restrict__ Ah,
                                              const _Float16* __restrict__ Bt,
                                              _Float16* __restrict__ C,
                                              int M, int N, int K) {
  __shared__ __align__(16) ushort_t A_s[2][4096];    // [128][32]
  __shared__ __align__(16) ushort_t B_s[2][4096];    // [128 cols][32 k]
  const int tid = threadIdx.x, lane = tid & 63, wid = tid >> 6;
  const int nwg = gridDim.x;
  int bid = blockIdx.x;
  int swz = (bid & 7) * (nwg >> 3) + (bid >> 3);     // XCD swizzle (nwg%8==0)
  const int nbn = N >> 7;
  const int bm = swz / nbn, bn = swz % nbn;
  const int lm = lane & 15, lg = lane >> 4;
  const int row0 = bm << 7, col0 = bn << 7;
  const int wrow = (wid >> 1) * 64, wcol = (wid & 1) * 64;
  const int NT = K >> 5;

  f4_t acc[4][4];
#pragma unroll
  for (int m = 0; m < 4; m++)
#pragma unroll
    for (int n = 0; n < 4; n++) acc[m][n] = (f4_t){0.f, 0.f, 0.f, 0.f};

  auto stage = [&](int buf, int ks) {
    int k0 = ks << 5;
#pragma unroll
    for (int p = 0; p < 2; p++) {
      int c = p * 256 + wid * 64 + lane;             // 16B chunk 0..511
      int r = c >> 2, q = (c & 3) * 8;
      char* la = (char*)&A_s[buf][0] + p * 4096 + wid * 1024;
      GLOAD16(Ah + (size_t)(row0 + r) * K + k0 + q, la);
      char* lb = (char*)&B_s[buf][0] + p * 4096 + wid * 1024;
      GLOAD16(Bt + (size_t)(col0 + r) * K + k0 + q, lb);
    }
  };

  stage(0, 0);
  __syncthreads();
  for (int t = 0; t < NT; t++) {
    int cur = t & 1;
    if (t + 1 < NT) stage(cur ^ 1, t + 1);
    h8_t af[4], bfr[4];
#pragma unroll
    for (int m = 0; m < 4; m++)
      af[m] = *(const h8_t*)&A_s[cur][(wrow + m * 16 + lm) * 32 + lg * 8];
#pragma unroll
    for (int n = 0; n < 4; n++)
      bfr[n] = *(const h8_t*)&B_s[cur][(wcol + n * 16 + lm) * 32 + lg * 8];
#pragma unroll
    for (int m = 0; m < 4; m++)
#pragma unroll
      for (int n = 0; n < 4; n++)
        acc[m][n] = MFMAH(af[m], bfr[n], acc[m][n]);
    __syncthreads();
  }
#pragma unroll
  for (int m = 0; m < 4; m++)
#pragma unroll
    for (int n = 0; n < 4; n++)
#pragma unroll
      for (int r = 0; r < 4; r++)
        C[(size_t)(row0 + wrow + m * 16 + lg * 4 + r) * N + col0 + wcol + n * 16 + lm] = (_Float16)acc[m][n][r];
}

// ---- activations: qs emitted as bf16 hi/lo; qk->bf16 fused ----------------
__device__ __forceinline__ float gate_fn(float z) {
  float t = -z;
  float sp = (t > 20.f) ? t : log1pf(expf(t));   // softplus(-z)
  float g = -sp * (1.f / 16.f);                  // log_sigmoid(z)/16
  return fminf(fmaxf(g, -16.f), 16.f);
}

__global__ __launch_bounds__(256) void act_kernel(const _Float16* __restrict__ qkv,
                                                  ushort_t* __restrict__ qs_h,
                                                  ushort_t* __restrict__ qs_l,
                                                  float* __restrict__ ksm,
                                                  float* __restrict__ kb,
                                                  float* __restrict__ vb,
                                                  ushort_t* __restrict__ qb16,
                                                  ushort_t* __restrict__ kb16) {
  int wave = blockIdx.x * 4 + (threadIdx.x >> 6);  // (row*16 + h)
  int lane = threadIdx.x & 63;
  int row = wave >> 4, h = wave & 15;
  size_t inb = (size_t)row * NQKV + h * 128;
  size_t base = (size_t)wave * 128;
  const int e0 = 2 * lane;                         // lane owns elems e0, e0+1

  h2_t qv = *(const h2_t*)(qkv + inb + e0);
  h2_t kv = *(const h2_t*)(qkv + inb + 2048 + e0);
  h2_t vv = *(const h2_t*)(qkv + inb + 4096 + e0);
  float q0 = (float)qv[0], q1 = (float)qv[1];
  float k0 = (float)kv[0], k1 = (float)kv[1];
  float v0 = (float)vv[0], v1 = (float)vv[1];

  // fused raw-logit bf16 outputs for base attention
  us2_t qo = {f2bf(q0 * RSQDH), f2bf(q1 * RSQDH)};
  us2_t ko = {f2bf(k0), f2bf(k1)};
  *(us2_t*)(qb16 + base + e0) = qo;
  *(us2_t*)(kb16 + base + e0) = ko;

  float m = fmaxf(q0, q1);
  for (int o = 1; o < 64; o <<= 1) m = fmaxf(m, __shfl_xor(m, o));
  float e0f = expf(q0 - m), e1f = expf(q1 - m);
  float s = e0f + e1f;
  for (int o = 1; o < 64; o <<= 1) s += __shfl_xor(s, o);
  float inv = 1.f / s;
  float qs0 = fminf(fmaxf(e0f * inv, EPSC), 1.f - EPSC) * RSQDH;
  float qs1 = fminf(fmaxf(e1f * inv, EPSC), 1.f - EPSC) * RSQDH;

  float mk = fmaxf(k0, k1);
  for (int o = 1; o < 64; o <<= 1) mk = fmaxf(mk, __shfl_xor(mk, o));
  float f0 = expf(k0 - mk), f1 = expf(k1 - mk);
  float sk = f0 + f1;
  for (int o = 1; o < 64; o <<= 1) sk += __shfl_xor(sk, o);
  float invk = 1.f / sk;
  float ks0 = fminf(fmaxf(f0 * invk, EPSC), 1.f - EPSC);
  float ks1 = fminf(fmaxf(f1 * invk, EPSC), 1.f - EPSC);

  float g0 = gate_fn(k0), g1 = gate_fn(k1);

  // qs as bf16 hi/lo (split once; consumers use directly)
  ushort_t qh0 = f2bf(qs0), qh1 = f2bf(qs1);
  us2_t qhv = {qh0, qh1};
  us2_t qlv = {f2bf(qs0 - bf2f(qh0)), f2bf(qs1 - bf2f(qh1))};
  *(us2_t*)(qs_h + base + e0) = qhv;
  *(us2_t*)(qs_l + base + e0) = qlv;

  *(float2*)(ksm + base + e0) = make_float2(ks0, ks1);
  *(float2*)(kb + base + e0) = make_float2(ks0 * g0, ks1 * g1);
  *(float2*)(vb + base + e0) = make_float2(v0 * g0, v1 * g1);
}

// -------- ksm -> transposed bf16 hi/lo kT[bh][d][n] ------------------------
__global__ __launch_bounds__(256) void k_transpose(const float* __restrict__ ksm,
                                                   ushort_t* __restrict__ kTh,
                                                   ushort_t* __restrict__ kTl) {
  __shared__ float t[32][33];
  const int tid = threadIdx.x;
  const int n0 = blockIdx.x * 32;
  const int d0 = blockIdx.y * 32;
  const int bh = blockIdx.z;
  const int b = bh >> 4, h = bh & 15;
  const int c = tid & 31, rr = tid >> 5;
#pragma unroll
  for (int p = 0; p < 4; p++) {
    int r = p * 8 + rr;
    t[r][c] = ksm[(size_t)(b * 1024 + n0 + r) * D + h * 128 + d0 + c];
  }
  __syncthreads();
#pragma unroll
  for (int p = 0; p < 4; p++) {
    int r = p * 8 + rr;
    float v = t[c][r];
    ushort_t hb = f2bf(v);
    kTh[(size_t)(bh * 128 + d0 + r) * 1024 + n0 + c] = hb;
    kTl[(size_t)(bh * 128 + d0 + r) * 1024 + n0 + c] = f2bf(v - bf2f(hb));
  }
}

// ------- per-chunk (MFMA): L = kb@k^T, attn = q@k^T, fwd-subst -> u, w -----
// qs consumed pre-split (hi/lo); w emitted pre-split for scan.
__global__ __launch_bounds__(256) void chunk_uw_kernel(const ushort_t* __restrict__ qs_h,
                                                       const ushort_t* __restrict__ qs_l,
                                                       const float* __restrict__ ksm,
                                                       const float* __restrict__ kb,
                                                       const float* __restrict__ vb,
                                                       float* __restrict__ u,
                                                       ushort_t* __restrict__ w_h,
                                                       ushort_t* __restrict__ w_l,
                                                       ushort_t* __restrict__ attn_h,
                                                       ushort_t* __restrict__ attn_l) {
  __shared__ __align__(16) ushort_t kh_s[8192];   // k hi  [64][128] swizzled
  __shared__ __align__(16) ushort_t kl_s[8192];   // k lo
  __shared__ __align__(16) ushort_t xh_s[8192];   // kb hi, then q hi
  __shared__ __align__(16) ushort_t xl_s[8192];   // kb lo, then q lo
  __shared__ float L_s[4096];                     // [64][64]
  const int tid = threadIdx.x, lane = tid & 63, wid = tid >> 6;
  const int lm = lane & 15, lg = lane >> 4;
  const int bh = blockIdx.x >> 4, ci = blockIdx.x & 15;
  const int rowbase = (bh >> 4) * 1024 + ci * 64;
  const int colbase = (bh & 15) * 128;
  const size_t gbase = (size_t)rowbase * D + colbase;
  const int wr = (wid >> 1) * 32, wc = (wid & 1) * 32;

  auto stageM = [&](const float* __restrict__ src, ushort_t* dh, ushort_t* dl) {
#pragma unroll
    for (int it = 0; it < 4; it++) {
      int idx = tid + it * 256;
      int r = idx >> 4, c8 = idx & 15;
      const float* g = src + gbase + (size_t)r * D + c8 * 8;
      float4 v0 = *(const float4*)g;
      float4 v1 = *(const float4*)(g + 4);
      float vv[8] = {v0.x, v0.y, v0.z, v0.w, v1.x, v1.y, v1.z, v1.w};
      s8_t hv, lv;
#pragma unroll
      for (int j = 0; j < 8; j++) {
        ushort_t hb = f2bf(vv[j]);
        hv[j] = (short)hb;
        lv[j] = (short)f2bf(vv[j] - bf2f(hb));
      }
      int byo = r * 256 + ((c8 * 16) ^ ((r & 7) << 4));
      *(s8_t*)((char*)dh + byo) = hv;
      *(s8_t*)((char*)dl + byo) = lv;
    }
  };

  // pre-split source: pure swizzled copy, no conversion
  auto stageHL = [&](const ushort_t* __restrict__ srcH,
                     const ushort_t* __restrict__ srcL,
                     ushort_t* dh, ushort_t* dl) {
#pragma unroll
    for (int it = 0; it < 4; it++) {
      int idx = tid + it * 256;
      int r = idx >> 4, c8 = idx & 15;
      size_t g = gbase + (size_t)r * D + c8 * 8;
      s8_t hv = *(const s8_t*)(srcH + g);
      s8_t lv = *(const s8_t*)(srcL + g);
      int byo = r * 256 + ((c8 * 16) ^ ((r & 7) << 4));
      *(s8_t*)((char*)dh + byo) = hv;
      *(s8_t*)((char*)dl + byo) = lv;
    }
  };

  auto mm3 = [&](const ushort_t* Ah, const ushort_t* Al,
                 const ushort_t* Bh, const ushort_t* Bl, f4_t acc[2][2]) {
#pragma unroll
    for (int m = 0; m < 2; m++)
#pragma unroll
      for (int n = 0; n < 2; n++) acc[m][n] = (f4_t){0.f, 0.f, 0.f, 0.f};
#pragma unroll
    for (int term = 0; term < 3; term++) {
      const ushort_t* A = (term == 2) ? Al : Ah;
      const ushort_t* Bsrc = (term == 1) ? Bl : Bh;
#pragma unroll
      for (int ks = 0; ks < 4; ks++) {
        s8_t af[2], bf_[2];
#pragma unroll
        for (int m = 0; m < 2; m++) {
          int row = wr + m * 16 + lm;
          int byo = row * 256 + ((ks * 64 + lg * 16) ^ ((row & 7) << 4));
          af[m] = *(const s8_t*)((const char*)A + byo);
        }
#pragma unroll
        for (int n = 0; n < 2; n++) {
          int row = wc + n * 16 + lm;
          int byo = row * 256 + ((ks * 64 + lg * 16) ^ ((row & 7) << 4));
          bf_[n] = *(const s8_t*)((const char*)Bsrc + byo);
        }
#pragma unroll
        for (int m = 0; m < 2; m++)
#pragma unroll
          for (int n = 0; n < 2; n++)
            acc[m][n] = MFMA16(af[m], bf_[n], acc[m][n]);
      }
    }
  };

  stageM(ksm, kh_s, kl_s);
  stageM(kb, xh_s, xl_s);
  __syncthreads();

  f4_t accL[2][2];
  mm3(xh_s, xl_s, kh_s, kl_s, accL);
#pragma unroll
  for (int m = 0; m < 2; m++)
#pragma unroll
    for (int n = 0; n < 2; n++)
#pragma unroll
      for (int r = 0; r < 4; r++) {
        int i = wr + m * 16 + lg * 4 + r;
        int j = wc + n * 16 + lm;
        L_s[i * 64 + j] = (j < i) ? accL[m][n][r] : 0.f;
      }
  __syncthreads();

  stageHL(qs_h, qs_l, xh_s, xl_s);
  __syncthreads();

  f4_t accA[2][2];
  mm3(xh_s, xl_s, kh_s, kl_s, accA);
  ushort_t* abh = attn_h + (size_t)blockIdx.x * 4096;
  ushort_t* abl = attn_l + (size_t)blockIdx.x * 4096;
#pragma unroll
  for (int m = 0; m < 2; m++)
#pragma unroll
    for (int n = 0; n < 2; n++)
#pragma unroll
      for (int r = 0; r < 4; r++) {
        int i = wr + m * 16 + lg * 4 + r;
        int j = wc + n * 16 + lm;
        float val = (j <= i) ? accA[m][n][r] : 0.f;
        ushort_t hb = f2bf(val);
        abh[i * 64 + j] = hb;
        abl[i * 64 + j] = f2bf(val - bf2f(hb));
      }

  float x[64];
  const int c = tid & 127;
  const float* rhs = (tid < 128) ? (vb + gbase + c) : (kb + gbase + c);
#pragma unroll
  for (int j = 0; j < 64; j++) x[j] = rhs[(size_t)j * D];
#pragma unroll
  for (int i = 0; i < 64; i++) {
    float xi = x[i];
#pragma unroll
    for (int r2 = i + 1; r2 < 64; r2++) x[r2] -= L_s[r2 * 64 + i] * xi;
  }
  if (tid < 128) {
#pragma unroll
    for (int j = 0; j < 64; j++) u[gbase + (size_t)j * D + c] = x[j];
  } else {
#pragma unroll
    for (int j = 0; j < 64; j++) {
      ushort_t hb = f2bf(x[j]);
      w_h[gbase + (size_t)j * D + c] = hb;
      w_l[gbase + (size_t)j * D + c] = f2bf(x[j] - bf2f(hb));
    }
  }
}

// ------- sequential scan: grid(32 bh, 8 vgroups), 512 thr ------------------
// v9: phase1 inputs pre-split (no per-chunk f2bf); all-MFMA phases; dbuf
// async staging (pre-swizzled global source); register prefetch.
__global__ __launch_bounds__(512, 2) void scan_kernel(const ushort_t* __restrict__ qs_h,
                                                      const ushort_t* __restrict__ qs_l,
                                                      const float* __restrict__ u,
                                                      const ushort_t* __restrict__ w_h,
                                                      const ushort_t* __restrict__ w_l,
                                                      const ushort_t* __restrict__ kTh_g,
                                                      const ushort_t* __restrict__ kTl_g,
                                                      const ushort_t* __restrict__ ath_g,
                                                      const ushort_t* __restrict__ atl_g,
                                                      float* __restrict__ o_lin) {
  __shared__ __align__(16) ushort_t kT_h[2][8192];   // [k][i] swizzled, dbuf
  __shared__ __align__(16) ushort_t kT_l[2][8192];
  __shared__ __align__(16) ushort_t at_h[2][4096];   // [i][j] swizzled, dbuf
  __shared__ __align__(16) ushort_t at_l[2][4096];
  __shared__ __align__(16) ushort_t Sh_s[16 * 128];  // S^T [c][k] swizzled
  __shared__ __align__(16) ushort_t Sl_s[16 * 128];
  __shared__ __align__(16) ushort_t uh_s[16 * 80];   // u'^T [c][i]
  __shared__ __align__(16) ushort_t ul_s[16 * 80];
  __shared__ __align__(16) float oT[16 * 68];        // q@S partial [c][i]
  const int tid = threadIdx.x;
  const int bh = blockIdx.x;
  const int b = bh >> 4, h = bh & 15;
  const int g = blockIdx.y;            // 0..7 (16 dv cols each)
  const int colbase = h * 128;
  const int vcol = h * 128 + g * 16;
  const int lane = tid & 63, wid = tid >> 6;
  const int lm = lane & 15, lg = lane >> 4;
  const int dsub = lane >> 3;          // 0..7
  const int i8x = (lane & 7) ^ dsub;   // pre-swizzled col group

  for (int i = tid; i < 16 * 128; i += 512) { Sh_s[i] = 0; Sl_s[i] = 0; }

  f4_t acc3[2];                        // persistent S tiles (waves 4-7)
  acc3[0] = (f4_t){0.f, 0.f, 0.f, 0.f};
  acc3[1] = (f4_t){0.f, 0.f, 0.f, 0.f};

  const ushort_t* kThb = kTh_g + (size_t)bh * 128 * 1024;
  const ushort_t* kTlb = kTl_g + (size_t)bh * 128 * 1024;

  auto issue_stage = [&](int buf, int chunk) {
#pragma unroll
    for (int it = 0; it < 2; it++) {
      int seg = it * 8 + wid;               // 0..15 (8 kT rows each)
      int d = seg * 8 + dsub;               // row 0..127
      size_t goff = (size_t)d * 1024 + chunk * 64 + i8x * 8;
      GLOAD16(kThb + goff, (char*)&kT_h[buf][0] + seg * 1024);
      GLOAD16(kTlb + goff, (char*)&kT_l[buf][0] + seg * 1024);
    }
    {
      int i = wid * 8 + dsub;               // attn row 0..63
      size_t asrc = (size_t)(bh * 16 + chunk) * 4096 + i * 64 + i8x * 8;
      GLOAD16(ath_g + asrc, (char*)&at_h[buf][0] + wid * 1024);
      GLOAD16(atl_g + asrc, (char*)&at_l[buf][0] + wid * 1024);
    }
  };

  const bool isU = (wid < 4);
  const int m0 = (isU ? wid : (wid - 4)) * 16;
  const ushort_t* AsrcH = isU ? w_h : qs_h;
  const ushort_t* AsrcL = isU ? w_l : qs_l;

  s8_t pAh[4], pAl[4];                  // prefetched hi/lo fragments
  float pu[4];
  auto prefetchA = [&](int chunk) {
    const size_t gb = (size_t)(b * 1024 + chunk * 64) * D;
#pragma unroll
    for (int ks = 0; ks < 4; ks++) {
      size_t off = gb + (size_t)(m0 + lm) * D + colbase + ks * 32 + lg * 8;
      pAh[ks] = *(const s8_t*)(AsrcH + off);
      pAl[ks] = *(const s8_t*)(AsrcL + off);
    }
    if (isU) {
#pragma unroll
      for (int r = 0; r < 4; r++)
        pu[r] = u[gb + (size_t)(m0 + lg * 4 + r) * D + vcol + lm];
    }
  };

  issue_stage(0, 0);
  prefetchA(0);
  __syncthreads();                      // S mirror init visible

  for (int chunk = 0; chunk < 16; chunk++) {
    const int cur = chunk & 1;
    const size_t gbase = (size_t)(b * 1024 + chunk * 64) * D;
    if (chunk + 1 < 16) issue_stage(cur ^ 1, chunk + 1);
    // ---- phase1 MFMA from prefetched pre-split regs: u' / q@S ----
    {
      f4_t acc = (f4_t){0.f, 0.f, 0.f, 0.f};
#pragma unroll
      for (int ks = 0; ks < 4; ks++) {
        int byo = (lm * 256 + ks * 64 + lg * 16) ^ ((lm & 7) << 4);
        s8_t sh = *(const s8_t*)((const char*)Sh_s + byo);
        s8_t sl = *(const s8_t*)((const char*)Sl_s + byo);
        acc = MFMA16(pAh[ks], sh, acc);
        acc = MFMA16(pAh[ks], sl, acc);
        acc = MFMA16(pAl[ks], sh, acc);
      }
      if (isU) {
        float res[4];
#pragma unroll
        for (int r = 0; r < 4; r++) res[r] = pu[r] - acc[r];
        us4_t rh, rl;
#pragma unroll
        for (int r = 0; r < 4; r++) {
          ushort_t hb = f2bf(res[r]);
          rh[r] = hb;
          rl[r] = f2bf(res[r] - bf2f(hb));
        }
        *(us4_t*)&uh_s[lm * 80 + m0 + lg * 4] = rh;
        *(us4_t*)&ul_s[lm * 80 + m0 + lg * 4] = rl;
      } else {
        float4 res = {acc[0], acc[1], acc[2], acc[3]};
        *(float4*)&oT[lm * 68 + m0 + lg * 4] = res;
      }
    }
    __syncthreads();                     // B: u', oT visible; staging drained
    if (chunk + 1 < 16) prefetchA(chunk + 1);
    if (isU) {
      // ---- phase2 MFMA: o = oT + attn @ u' ; store to global ----
      float4 o0 = *(const float4*)&oT[lm * 68 + m0 + lg * 4];
      f4_t acc2 = (f4_t){o0.x, o0.y, o0.z, o0.w};
#pragma unroll
      for (int ks = 0; ks < 2; ks++) {
        int arow = m0 + lm;
        int abyo = arow * 128 + ((ks * 64 + lg * 16) ^ ((arow & 7) << 4));
        s8_t afh = *(const s8_t*)((const char*)&at_h[cur][0] + abyo);
        s8_t afl = *(const s8_t*)((const char*)&at_l[cur][0] + abyo);
        s8_t ufh = *(const s8_t*)&uh_s[lm * 80 + ks * 32 + lg * 8];
        s8_t ufl = *(const s8_t*)&ul_s[lm * 80 + ks * 32 + lg * 8];
        acc2 = MFMA16(afh, ufh, acc2);
        acc2 = MFMA16(afh, ufl, acc2);
        acc2 = MFMA16(afl, ufh, acc2);
      }
#pragma unroll
      for (int r = 0; r < 4; r++)
        o_lin[gbase + (size_t)(m0 + lg * 4 + r) * D + vcol + lm] = acc2[r];
    } else {
      // ---- phase3 MFMA: S += u'^T @ kT (persistent acc) + mirror refresh --
      const int w3 = wid - 4;
      s8_t ufh0 = *(const s8_t*)&uh_s[lm * 80 + 0 * 32 + lg * 8];
      s8_t ufl0 = *(const s8_t*)&ul_s[lm * 80 + 0 * 32 + lg * 8];
      s8_t ufh1 = *(const s8_t*)&uh_s[lm * 80 + 1 * 32 + lg * 8];
      s8_t ufl1 = *(const s8_t*)&ul_s[lm * 80 + 1 * 32 + lg * 8];
#pragma unroll
      for (int t = 0; t < 2; t++) {
        const int krow = (w3 * 2 + t) * 16 + lm;
        int b0 = krow * 128 + ((0 * 64 + lg * 16) ^ ((krow & 7) << 4));
        int b1 = krow * 128 + ((1 * 64 + lg * 16) ^ ((krow & 7) << 4));
        s8_t kh0 = *(const s8_t*)((const char*)&kT_h[cur][0] + b0);
        s8_t kl0 = *(const s8_t*)((const char*)&kT_l[cur][0] + b0);
        s8_t kh1 = *(const s8_t*)((const char*)&kT_h[cur][0] + b1);
        s8_t kl1 = *(const s8_t*)((const char*)&kT_l[cur][0] + b1);
        acc3[t] = MFMA16(ufh0, kh0, acc3[t]);
        acc3[t] = MFMA16(ufh0, kl0, acc3[t]);
        acc3[t] = MFMA16(ufl0, kh0, acc3[t]);
        acc3[t] = MFMA16(ufh1, kh1, acc3[t]);
        acc3[t] = MFMA16(ufh1, kl1, acc3[t]);
        acc3[t] = MFMA16(ufl1, kh1, acc3[t]);
      }
#pragma unroll
      for (int t = 0; t < 2; t++)
#pragma unroll
        for (int r = 0; r < 4; r++) {
          int c = lg * 4 + r;
          int k = (w3 * 2 + t) * 16 + lm;
          float sval = acc3[t][r];
          ushort_t hb = f2bf(sval);
          int sbyo = (c * 256 + k * 2) ^ ((c & 7) << 4);
          *(ushort_t*)((char*)Sh_s + sbyo) = hb;
          *(ushort_t*)((char*)Sl_s + sbyo) = f2bf(sval - bf2f(hb));
        }
    }
    __syncthreads();                     // C: reads done; mirror ordered
  }
}

// -------- v (from fp16 qkv) -> transposed bf16 vt[b][h][d][n] -------------
__global__ __launch_bounds__(256) void v_transpose(const _Float16* __restrict__ qkv,
                                                   ushort_t* __restrict__ vt) {
  __shared__ float t[32][33];
  const int tid = threadIdx.x;
  const int n0 = blockIdx.x * 32;
  const int d0 = blockIdx.y * 32;
  const int bh = blockIdx.z;
  const int b = bh >> 4, h = bh & 15;
  const int c = tid & 31, rr = tid >> 5;
#pragma unroll
  for (int p = 0; p < 4; p++) {
    int r = p * 8 + rr;
    t[r][c] = (float)qkv[(size_t)(b * 1024 + n0 + r) * NQKV + 4096 + h * 128 + d0 + c];
  }
  __syncthreads();
#pragma unroll
  for (int p = 0; p < 4; p++) {
    int r = p * 8 + rr;
    vt[(size_t)(bh * 128 + d0 + r) * 1024 + n0 + c] = f2bf(t[c][r]);
  }
}

// -------- MFMA bf16 flash attention + 0.5/0.5 mix + fp16 out --------------
__global__ __launch_bounds__(256) void attn_mfma(const ushort_t* __restrict__ qb,
                                                 const ushort_t* __restrict__ kb,
                                                 const ushort_t* __restrict__ vt,
                                                 const float* __restrict__ o_lin,
                                                 _Float16* __restrict__ mixh) {
  __shared__ __align__(16) ushort_t K_s[8192];
  __shared__ __align__(16) ushort_t V_s[8192];
  __shared__ __align__(16) ushort_t P_s[4][1152];
  const int tid = threadIdx.x;
  const int lane = tid & 63, wid = tid >> 6;
  const int bh = blockIdx.x;
  const int b = bh >> 4, h = bh & 15;
  const int qt = blockIdx.y;
  const int lm = lane & 15, lg = lane >> 4;

  s8_t qf[4];
  const size_t qrowG = (size_t)(b * 1024 + qt * 64 + wid * 16 + lm);
#pragma unroll
  for (int kb4 = 0; kb4 < 4; kb4++)
    qf[kb4] = *(const s8_t*)(qb + qrowG * D + h * 128 + kb4 * 32 + lg * 8);

  f4_t o[8];
#pragma unroll
  for (int n = 0; n < 8; n++) o[n] = (f4_t){0.f, 0.f, 0.f, 0.f};
  float mrow[4] = {-INFINITY, -INFINITY, -INFINITY, -INFINITY};
  float lrow[4] = {0.f, 0.f, 0.f, 0.f};
  const int myq = qt * 64 + wid * 16 + lg * 4;

  for (int kt = 0; kt <= qt; kt++) {
    __syncthreads();
#pragma unroll
    for (int p = 0; p < 4; p++) {
      int c = tid + p * 256;
      int key = c >> 4, dc = c & 15;
      s8_t v = *(const s8_t*)(kb + (size_t)(b * 1024 + kt * 64 + key) * D + h * 128 + dc * 8);
      int byo = key * 256 + ((dc * 16) ^ ((key & 7) << 4));
      *(s8_t*)((char*)K_s + byo) = v;
    }
#pragma unroll
    for (int p = 0; p < 4; p++) {
      int c = tid + p * 256;
      int d = c >> 3, nc = c & 7;
      s8_t v = *(const s8_t*)(vt + (size_t)(bh * 128 + d) * 1024 + kt * 64 + nc * 8);
      int byo = d * 128 + ((nc * 16) ^ ((d & 7) << 4));
      *(s8_t*)((char*)V_s + byo) = v;
    }
    __syncthreads();

    f4_t s[4];
#pragma unroll
    for (int ks = 0; ks < 4; ks++) {
      f4_t a = (f4_t){0.f, 0.f, 0.f, 0.f};
      int key = ks * 16 + lm;
#pragma unroll
      for (int kb4 = 0; kb4 < 4; kb4++) {
        int byo = key * 256 + ((kb4 * 64 + lg * 16) ^ ((key & 7) << 4));
        s8_t kf = *(const s8_t*)((char*)K_s + byo);
        a = MFMA16(qf[kb4], kf, a);
      }
      s[ks] = a;
    }
    if (kt == qt) {
#pragma unroll
      for (int ks = 0; ks < 4; ks++) {
        int key = kt * 64 + ks * 16 + lm;
#pragma unroll
        for (int r = 0; r < 4; r++)
          if (key > myq + r) s[ks][r] = -INFINITY;
      }
    }
    float mloc[4];
#pragma unroll
    for (int r = 0; r < 4; r++) {
      mloc[r] = fmaxf(fmaxf(s[0][r], s[1][r]), fmaxf(s[2][r], s[3][r]));
      mloc[r] = fmaxf(mloc[r], __shfl_xor(mloc[r], 1));
      mloc[r] = fmaxf(mloc[r], __shfl_xor(mloc[r], 2));
      mloc[r] = fmaxf(mloc[r], __shfl_xor(mloc[r], 4));
      mloc[r] = fmaxf(mloc[r], __shfl_xor(mloc[r], 8));
    }
    float scale[4];
#pragma unroll
    for (int r = 0; r < 4; r++) {
      float mn = fmaxf(mrow[r], mloc[r]);
      scale[r] = __expf(mrow[r] - mn);
      mrow[r] = mn;
    }
    float lad[4] = {0.f, 0.f, 0.f, 0.f};
#pragma unroll
    for (int ks = 0; ks < 4; ks++)
#pragma unroll
      for (int r = 0; r < 4; r++) {
        float p = __expf(s[ks][r] - mrow[r]);
        lad[r] += p;
        P_s[wid][(lg * 4 + r) * 72 + ks * 16 + lm] = f2bf(p);
      }
#pragma unroll
    for (int r = 0; r < 4; r++) {
      lad[r] += __shfl_xor(lad[r], 1);
      lad[r] += __shfl_xor(lad[r], 2);
      lad[r] += __shfl_xor(lad[r], 4);
      lad[r] += __shfl_xor(lad[r], 8);
      lrow[r] = lrow[r] * scale[r] + lad[r];
    }
#pragma unroll
    for (int n = 0; n < 8; n++)
#pragma unroll
      for (int r = 0; r < 4; r++) o[n][r] *= scale[r];

    s8_t pf[2];
#pragma unroll
    for (int ksl = 0; ksl < 2; ksl++)
      pf[ksl] = *(const s8_t*)&P_s[wid][lm * 72 + ksl * 32 + lg * 8];
#pragma unroll
    for (int n = 0; n < 8; n++) {
      int d = n * 16 + lm;
#pragma unroll
      for (int ksl = 0; ksl < 2; ksl++) {
        int byo = d * 128 + ((ksl * 64 + lg * 16) ^ ((d & 7) << 4));
        s8_t vf = *(const s8_t*)((char*)V_s + byo);
        o[n] = MFMA16(pf[ksl], vf, o[n]);
      }
    }
  }

  float invl[4];
#pragma unroll
  for (int r = 0; r < 4; r++) invl[r] = 1.f / lrow[r];
#pragma unroll
  for (int n = 0; n < 8; n++)
#pragma unroll
    for (int r = 0; r < 4; r++) {
      size_t G = (size_t)(b * 1024 + qt * 64 + wid * 16 + lg * 4 + r);
      int dcol = h * 128 + n * 16 + lm;
      float mix = 0.5f * (o[n][r] * invl[r]) + 0.5f * o_lin[G * D + dcol];
      mixh[G * D + dcol] = (_Float16)mix;
    }
}

// ---------------------------------------------------------------------------
extern "C" void kernel_launch(void* const* d_in, const int* in_sizes, int n_in,
                              void* d_out, int out_size, void* d_ws, size_t ws_size,
                              hipStream_t stream) {
  const float* x  = (const float*)d_in[0];
  const float* Wq = (const float*)d_in[1];
  const float* Wk = (const float*)d_in[2];
  const float* Wv = (const float*)d_in[3];
  const float* Wo = (const float*)d_in[4];
  float* out = (float*)d_out;
  float* ws = (float*)d_ws;

  const size_t B = (size_t)NROWS * D;   // 4,194,304 floats per slot
  _Float16* qkv = (_Float16*)(ws + 0 * B);   // [2048][6144] fp16 (slots 0-1)
  float* q_s  = ws + 3 * B;                  // holds qs_h/qs_l (bf16 pair)
  float* k_sm = ws + 4 * B;
  float* kbuf = ws + 5 * B;
  float* vbuf = ws + 6 * B;
  float* u    = ws + 7 * B;
  float* w    = ws + 8 * B;                  // holds w_h/w_l (bf16 pair)
  float* o_lin = kbuf;

  _Float16* x_hi = (_Float16*)u;                    // dead before chunk_uw writes u
  _Float16* Wt   = (_Float16*)(ws + 9 * B);         // QKV weights, dead after gemm1h
  ushort_t* attn_h = (ushort_t*)(ws + 9 * B);                 // after gemm1h
  ushort_t* attn_l = attn_h + (size_t)2097152;
  ushort_t* kTh_g  = (ushort_t*)(ws + 9 * B + 2097152);       // 4M u16
  ushort_t* kTl_g  = (ushort_t*)(ws + 10 * B);                // 4M u16
  _Float16* Wo_t   = (_Float16*)(ws + 10 * B + 2097152);      // own region
  ushort_t* qs_h = (ushort_t*)q_s;
  ushort_t* qs_l = qs_h + B;
  ushort_t* w_h  = (ushort_t*)w;
  ushort_t* w_l  = w_h + B;
  ushort_t* qb16 = (ushort_t*)(ws + 2 * B);
  ushort_t* kb16 = qb16 + B;
  ushort_t* vt16 = (ushort_t*)vbuf;
  _Float16* mixh = (_Float16*)qkv;

  split_h<<<4096, 256, 0, stream>>>(x, x_hi);
  wsplit4<<<dim3(64, 64, 4), 256, 0, stream>>>(Wq, Wk, Wv, Wo, Wt, Wo_t);
  gemm1h<<<16 * 48, 256, 0, stream>>>(x_hi, Wt, qkv, NROWS, NQKV, D);

  act_kernel<<<8192, 256, 0, stream>>>(qkv, qs_h, qs_l, k_sm, kbuf, vbuf, qb16, kb16);
  k_transpose<<<dim3(32, 4, 32), 256, 0, stream>>>(k_sm, kTh_g, kTl_g);
  chunk_uw_kernel<<<512, 256, 0, stream>>>(qs_h, qs_l, k_sm, kbuf, vbuf, u, w_h, w_l, attn_h, attn_l);
  scan_kernel<<<dim3(32, 8), 512, 0, stream>>>(qs_h, qs_l, u, w_h, w_l, kTh_g, kTl_g, attn_h, attn_l, o_lin);

  v_transpose<<<dim3(32, 4, 32), 256, 0, stream>>>(qkv, vt16);
  attn_mfma<<<dim3(32, 16), 256, 0, stream>>>(qb16, kb16, vt16, o_lin, mixh);

  gemm1<<<16 * 16, 256, 0, stream>>>(mixh, Wo_t, out, NROWS, D, D);
}

// Round 20
// 277.688 us; speedup vs baseline: 1.1627x; 1.0280x over previous
//
#include <hip/hip_runtime.h>
#include <hip/hip_bf16.h>
#include <math.h>

#define D 2048
#define NROWS 2048      // b*n
#define NQKV 6144       // fused QKV width
#define H 16
#define DH 128
#define CHK 64
#define NC 16
#define EPSC 1e-6f
#define RSQDH 0.08838834764831845f   // 128^-0.5

typedef unsigned short ushort_t;
typedef __attribute__((ext_vector_type(4))) float f4_t;
typedef __attribute__((ext_vector_type(8))) short s8_t;
typedef __attribute__((ext_vector_type(8))) _Float16 h8_t;
typedef __attribute__((ext_vector_type(4))) _Float16 h4_t;
typedef __attribute__((ext_vector_type(2))) _Float16 h2_t;
typedef __attribute__((ext_vector_type(4))) unsigned short us4_t;
typedef __attribute__((ext_vector_type(2))) unsigned short us2_t;

#define MFMA16(a, b, c) __builtin_amdgcn_mfma_f32_16x16x32_bf16((a), (b), (c), 0, 0, 0)
#define MFMAH(a, b, c)  __builtin_amdgcn_mfma_f32_16x16x32_f16((a), (b), (c), 0, 0, 0)
#define GLOAD16(g, l) __builtin_amdgcn_global_load_lds((const __attribute__((address_space(1))) unsigned int*)(g), (__attribute__((address_space(3))) unsigned int*)(l), 16, 0, 0)

__device__ __forceinline__ ushort_t f2bf(float f) {
  union { float f; unsigned u; } v; v.f = f;
  unsigned r = (v.u + 0x7fffu + ((v.u >> 16) & 1u)) >> 16;
  return (ushort_t)r;
}
__device__ __forceinline__ float bf2f(ushort_t h) {
  union { unsigned u; float f; } v; v.u = ((unsigned)h) << 16;
  return v.f;
}

// ---------------- fp32 -> fp16 (1-term, for QKV GEMM A) --------------------
__global__ __launch_bounds__(256) void split_h(const float* __restrict__ in,
                                               _Float16* __restrict__ hi) {
  int i = (blockIdx.x * 256 + threadIdx.x) * 4;
  float4 v = *(const float4*)(in + i);
  float vv[4] = {v.x, v.y, v.z, v.w};
  h4_t h;
#pragma unroll
  for (int j = 0; j < 4; j++) h[j] = (_Float16)vv[j];
  *(h4_t*)(hi + i) = h;
}

// ------------- all 4 weights: transpose + fp16 round, one launch -----------
__global__ __launch_bounds__(256) void wsplit4(const float* __restrict__ Wq,
                                               const float* __restrict__ Wk,
                                               const float* __restrict__ Wv,
                                               const float* __restrict__ Wo,
                                               _Float16* __restrict__ Tqkv,
                                               _Float16* __restrict__ To) {
  __shared__ float t[32][33];
  const int tid = threadIdx.x;
  const int k0 = blockIdx.y * 32, n0 = blockIdx.x * 32;
  const int z = blockIdx.z;
  const float* W = (z == 0) ? Wq : (z == 1) ? Wk : (z == 2) ? Wv : Wo;
  _Float16* T = (z < 3) ? (Tqkv + (size_t)z * D * D) : To;
  const int c = tid & 31, rr = tid >> 5;
#pragma unroll
  for (int p = 0; p < 4; p++) {
    int r = p * 8 + rr;
    t[r][c] = W[(size_t)(k0 + r) * D + n0 + c];
  }
  __syncthreads();
#pragma unroll
  for (int p = 0; p < 4; p++) {
    int r = p * 8 + rr;
    T[(size_t)(n0 + r) * D + k0 + c] = (_Float16)t[c][r];
  }
}

// ------ fp16 1-term MFMA GEMM (fp32 out, final Wo GEMM) --------------------
__global__ __launch_bounds__(256) void gemm1(const _Float16* __restrict__ Ah,
                                             const _Float16* __restrict__ Bt,
                                             float* __restrict__ C,
                                             int M, int N, int K) {
  __shared__ __align__(16) ushort_t A_s[2][4096];    // [128][32]
  __shared__ __align__(16) ushort_t B_s[2][4096];    // [128 cols][32 k]
  const int tid = threadIdx.x, lane = tid & 63, wid = tid >> 6;
  const int nwg = gridDim.x;
  int bid = blockIdx.x;
  int swz = (bid & 7) * (nwg >> 3) + (bid >> 3);     // XCD swizzle (nwg%8==0)
  const int nbn = N >> 7;
  const int bm = swz / nbn, bn = swz % nbn;
  const int row0 = bm << 7, col0 = bn << 7;
  const int lm = lane & 15, lg = lane >> 4;
  const int wrow = (wid >> 1) * 64, wcol = (wid & 1) * 64;
  const int NT = K >> 5;

  f4_t acc[4][4];
#pragma unroll
  for (int m = 0; m < 4; m++)
#pragma unroll
    for (int n = 0; n < 4; n++) acc[m][n] = (f4_t){0.f, 0.f, 0.f, 0.f};

  auto stage = [&](int buf, int ks) {
    int k0 = ks << 5;
#pragma unroll
    for (int p = 0; p < 2; p++) {
      int c = p * 256 + wid * 64 + lane;             // 16B chunk 0..511
      int r = c >> 2, q = (c & 3) * 8;
      char* la = (char*)&A_s[buf][0] + p * 4096 + wid * 1024;
      GLOAD16(Ah + (size_t)(row0 + r) * K + k0 + q, la);
      char* lb = (char*)&B_s[buf][0] + p * 4096 + wid * 1024;
      GLOAD16(Bt + (size_t)(col0 + r) * K + k0 + q, lb);
    }
  };

  stage(0, 0);
  __syncthreads();
  for (int t = 0; t < NT; t++) {
    int cur = t & 1;
    if (t + 1 < NT) stage(cur ^ 1, t + 1);
    h8_t af[4], bfr[4];
#pragma unroll
    for (int m = 0; m < 4; m++)
      af[m] = *(const h8_t*)&A_s[cur][(wrow + m * 16 + lm) * 32 + lg * 8];
#pragma unroll
    for (int n = 0; n < 4; n++)
      bfr[n] = *(const h8_t*)&B_s[cur][(wcol + n * 16 + lm) * 32 + lg * 8];
#pragma unroll
    for (int m = 0; m < 4; m++)
#pragma unroll
      for (int n = 0; n < 4; n++)
        acc[m][n] = MFMAH(af[m], bfr[n], acc[m][n]);
    __syncthreads();
  }
#pragma unroll
  for (int m = 0; m < 4; m++)
#pragma unroll
    for (int n = 0; n < 4; n++)
#pragma unroll
      for (int r = 0; r < 4; r++)
        C[(size_t)(row0 + wrow + m * 16 + lg * 4 + r) * N + col0 + wcol + n * 16 + lm] = acc[m][n][r];
}

// ------ fp16 1-term MFMA GEMM (fp16 out, QKV projection) -------------------
__global__ __launch_bounds__(256) void gemm1h(const _Float16* __restrict__ Ah,
                                              const _Float16* __restrict__ Bt,
                                              _Float16* __restrict__ C,
                                              int M, int N, int K) {
  __shared__ __align__(16) ushort_t A_s[2][4096];    // [128][32]
  __shared__ __align__(16) ushort_t B_s[2][4096];    // [128 cols][32 k]
  const int tid = threadIdx.x, lane = tid & 63, wid = tid >> 6;
  const int nwg = gridDim.x;
  int bid = blockIdx.x;
  int swz = (bid & 7) * (nwg >> 3) + (bid >> 3);     // XCD swizzle (nwg%8==0)
  const int nbn = N >> 7;
  const int bm = swz / nbn, bn = swz % nbn;
  const int lm = lane & 15, lg = lane >> 4;
  const int row0 = bm << 7, col0 = bn << 7;
  const int wrow = (wid >> 1) * 64, wcol = (wid & 1) * 64;
  const int NT = K >> 5;

  f4_t acc[4][4];
#pragma unroll
  for (int m = 0; m < 4; m++)
#pragma unroll
    for (int n = 0; n < 4; n++) acc[m][n] = (f4_t){0.f, 0.f, 0.f, 0.f};

  auto stage = [&](int buf, int ks) {
    int k0 = ks << 5;
#pragma unroll
    for (int p = 0; p < 2; p++) {
      int c = p * 256 + wid * 64 + lane;             // 16B chunk 0..511
      int r = c >> 2, q = (c & 3) * 8;
      char* la = (char*)&A_s[buf][0] + p * 4096 + wid * 1024;
      GLOAD16(Ah + (size_t)(row0 + r) * K + k0 + q, la);
      char* lb = (char*)&B_s[buf][0] + p * 4096 + wid * 1024;
      GLOAD16(Bt + (size_t)(col0 + r) * K + k0 + q, lb);
    }
  };

  stage(0, 0);
  __syncthreads();
  for (int t = 0; t < NT; t++) {
    int cur = t & 1;
    if (t + 1 < NT) stage(cur ^ 1, t + 1);
    h8_t af[4], bfr[4];
#pragma unroll
    for (int m = 0; m < 4; m++)
      af[m] = *(const h8_t*)&A_s[cur][(wrow + m * 16 + lm) * 32 + lg * 8];
#pragma unroll
    for (int n = 0; n < 4; n++)
      bfr[n] = *(const h8_t*)&B_s[cur][(wcol + n * 16 + lm) * 32 + lg * 8];
#pragma unroll
    for (int m = 0; m < 4; m++)
#pragma unroll
      for (int n = 0; n < 4; n++)
        acc[m][n] = MFMAH(af[m], bfr[n], acc[m][n]);
    __syncthreads();
  }
#pragma unroll
  for (int m = 0; m < 4; m++)
#pragma unroll
    for (int n = 0; n < 4; n++)
#pragma unroll
      for (int r = 0; r < 4; r++)
        C[(size_t)(row0 + wrow + m * 16 + lg * 4 + r) * N + col0 + wcol + n * 16 + lm] = (_Float16)acc[m][n][r];
}

// ---- activations: qs emitted as bf16 hi/lo; qk->bf16 fused ----------------
__device__ __forceinline__ float gate_fn(float z) {
  float t = -z;
  float sp = (t > 20.f) ? t : log1pf(expf(t));   // softplus(-z)
  float g = -sp * (1.f / 16.f);                  // log_sigmoid(z)/16
  return fminf(fmaxf(g, -16.f), 16.f);
}

__global__ __launch_bounds__(256) void act_kernel(const _Float16* __restrict__ qkv,
                                                  ushort_t* __restrict__ qs_h,
                                                  ushort_t* __restrict__ qs_l,
                                                  float* __restrict__ ksm,
                                                  float* __restrict__ kb,
                                                  float* __restrict__ vb,
                                                  ushort_t* __restrict__ qb16,
                                                  ushort_t* __restrict__ kb16) {
  int wave = blockIdx.x * 4 + (threadIdx.x >> 6);  // (row*16 + h)
  int lane = threadIdx.x & 63;
  int row = wave >> 4, h = wave & 15;
  size_t inb = (size_t)row * NQKV + h * 128;
  size_t base = (size_t)wave * 128;
  const int e0 = 2 * lane;                         // lane owns elems e0, e0+1

  h2_t qv = *(const h2_t*)(qkv + inb + e0);
  h2_t kv = *(const h2_t*)(qkv + inb + 2048 + e0);
  h2_t vv = *(const h2_t*)(qkv + inb + 4096 + e0);
  float q0 = (float)qv[0], q1 = (float)qv[1];
  float k0 = (float)kv[0], k1 = (float)kv[1];
  float v0 = (float)vv[0], v1 = (float)vv[1];

  // fused raw-logit bf16 outputs for base attention
  us2_t qo = {f2bf(q0 * RSQDH), f2bf(q1 * RSQDH)};
  us2_t ko = {f2bf(k0), f2bf(k1)};
  *(us2_t*)(qb16 + base + e0) = qo;
  *(us2_t*)(kb16 + base + e0) = ko;

  float m = fmaxf(q0, q1);
  for (int o = 1; o < 64; o <<= 1) m = fmaxf(m, __shfl_xor(m, o));
  float e0f = expf(q0 - m), e1f = expf(q1 - m);
  float s = e0f + e1f;
  for (int o = 1; o < 64; o <<= 1) s += __shfl_xor(s, o);
  float inv = 1.f / s;
  float qs0 = fminf(fmaxf(e0f * inv, EPSC), 1.f - EPSC) * RSQDH;
  float qs1 = fminf(fmaxf(e1f * inv, EPSC), 1.f - EPSC) * RSQDH;

  float mk = fmaxf(k0, k1);
  for (int o = 1; o < 64; o <<= 1) mk = fmaxf(mk, __shfl_xor(mk, o));
  float f0 = expf(k0 - mk), f1 = expf(k1 - mk);
  float sk = f0 + f1;
  for (int o = 1; o < 64; o <<= 1) sk += __shfl_xor(sk, o);
  float invk = 1.f / sk;
  float ks0 = fminf(fmaxf(f0 * invk, EPSC), 1.f - EPSC);
  float ks1 = fminf(fmaxf(f1 * invk, EPSC), 1.f - EPSC);

  float g0 = gate_fn(k0), g1 = gate_fn(k1);

  // qs as bf16 hi/lo (split once; consumers use directly)
  ushort_t qh0 = f2bf(qs0), qh1 = f2bf(qs1);
  us2_t qhv = {qh0, qh1};
  us2_t qlv = {f2bf(qs0 - bf2f(qh0)), f2bf(qs1 - bf2f(qh1))};
  *(us2_t*)(qs_h + base + e0) = qhv;
  *(us2_t*)(qs_l + base + e0) = qlv;

  *(float2*)(ksm + base + e0) = make_float2(ks0, ks1);
  *(float2*)(kb + base + e0) = make_float2(ks0 * g0, ks1 * g1);
  *(float2*)(vb + base + e0) = make_float2(v0 * g0, v1 * g1);
}

// ------- per-chunk (MFMA): L = kb@k^T, attn = q@k^T, fwd-subst -> u, w -----
// qs consumed pre-split; w emitted pre-split; kT hi/lo emitted from staged
// LDS k tile (replaces the separate k_transpose kernel).
__global__ __launch_bounds__(256) void chunk_uw_kernel(const ushort_t* __restrict__ qs_h,
                                                       const ushort_t* __restrict__ qs_l,
                                                       const float* __restrict__ ksm,
                                                       const float* __restrict__ kb,
                                                       const float* __restrict__ vb,
                                                       float* __restrict__ u,
                                                       ushort_t* __restrict__ w_h,
                                                       ushort_t* __restrict__ w_l,
                                                       ushort_t* __restrict__ attn_h,
                                                       ushort_t* __restrict__ attn_l,
                                                       ushort_t* __restrict__ kTh_g,
                                                       ushort_t* __restrict__ kTl_g) {
  __shared__ __align__(16) ushort_t kh_s[8192];   // k hi  [64][128] swizzled
  __shared__ __align__(16) ushort_t kl_s[8192];   // k lo
  __shared__ __align__(16) ushort_t xh_s[8192];   // kb hi, then q hi
  __shared__ __align__(16) ushort_t xl_s[8192];   // kb lo, then q lo
  __shared__ float L_s[4096];                     // [64][64]
  const int tid = threadIdx.x, lane = tid & 63, wid = tid >> 6;
  const int lm = lane & 15, lg = lane >> 4;
  const int bh = blockIdx.x >> 4, ci = blockIdx.x & 15;
  const int rowbase = (bh >> 4) * 1024 + ci * 64;
  const int colbase = (bh & 15) * 128;
  const size_t gbase = (size_t)rowbase * D + colbase;
  const int wr = (wid >> 1) * 32, wc = (wid & 1) * 32;

  auto stageM = [&](const float* __restrict__ src, ushort_t* dh, ushort_t* dl) {
#pragma unroll
    for (int it = 0; it < 4; it++) {
      int idx = tid + it * 256;
      int r = idx >> 4, c8 = idx & 15;
      const float* g = src + gbase + (size_t)r * D + c8 * 8;
      float4 v0 = *(const float4*)g;
      float4 v1 = *(const float4*)(g + 4);
      float vv[8] = {v0.x, v0.y, v0.z, v0.w, v1.x, v1.y, v1.z, v1.w};
      s8_t hv, lv;
#pragma unroll
      for (int j = 0; j < 8; j++) {
        ushort_t hb = f2bf(vv[j]);
        hv[j] = (short)hb;
        lv[j] = (short)f2bf(vv[j] - bf2f(hb));
      }
      int byo = r * 256 + ((c8 * 16) ^ ((r & 7) << 4));
      *(s8_t*)((char*)dh + byo) = hv;
      *(s8_t*)((char*)dl + byo) = lv;
    }
  };

  // pre-split source: pure swizzled copy, no conversion
  auto stageHL = [&](const ushort_t* __restrict__ srcH,
                     const ushort_t* __restrict__ srcL,
                     ushort_t* dh, ushort_t* dl) {
#pragma unroll
    for (int it = 0; it < 4; it++) {
      int idx = tid + it * 256;
      int r = idx >> 4, c8 = idx & 15;
      size_t g = gbase + (size_t)r * D + c8 * 8;
      s8_t hv = *(const s8_t*)(srcH + g);
      s8_t lv = *(const s8_t*)(srcL + g);
      int byo = r * 256 + ((c8 * 16) ^ ((r & 7) << 4));
      *(s8_t*)((char*)dh + byo) = hv;
      *(s8_t*)((char*)dl + byo) = lv;
    }
  };

  auto mm3 = [&](const ushort_t* Ah, const ushort_t* Al,
                 const ushort_t* Bh, const ushort_t* Bl, f4_t acc[2][2]) {
#pragma unroll
    for (int m = 0; m < 2; m++)
#pragma unroll
      for (int n = 0; n < 2; n++) acc[m][n] = (f4_t){0.f, 0.f, 0.f, 0.f};
#pragma unroll
    for (int term = 0; term < 3; term++) {
      const ushort_t* A = (term == 2) ? Al : Ah;
      const ushort_t* Bsrc = (term == 1) ? Bl : Bh;
#pragma unroll
      for (int ks = 0; ks < 4; ks++) {
        s8_t af[2], bf_[2];
#pragma unroll
        for (int m = 0; m < 2; m++) {
          int row = wr + m * 16 + lm;
          int byo = row * 256 + ((ks * 64 + lg * 16) ^ ((row & 7) << 4));
          af[m] = *(const s8_t*)((const char*)A + byo);
        }
#pragma unroll
        for (int n = 0; n < 2; n++) {
          int row = wc + n * 16 + lm;
          int byo = row * 256 + ((ks * 64 + lg * 16) ^ ((row & 7) << 4));
          bf_[n] = *(const s8_t*)((const char*)Bsrc + byo);
        }
#pragma unroll
        for (int m = 0; m < 2; m++)
#pragma unroll
          for (int n = 0; n < 2; n++)
            acc[m][n] = MFMA16(af[m], bf_[n], acc[m][n]);
      }
    }
  };

  stageM(ksm, kh_s, kl_s);
  stageM(kb, xh_s, xl_s);
  __syncthreads();

  f4_t accL[2][2];
  mm3(xh_s, xl_s, kh_s, kl_s, accL);

  // ---- emit kT hi/lo (transposed) from staged LDS k tile ----
  {
    const int dw = wid * 32;             // wave covers d = dw..dw+31
    const int r = lane;                  // n index within chunk (0..63)
#pragma unroll
    for (int i = 0; i < 32; i++) {
      int d = dw + i;
      int byo = r * 256 + ((((d >> 3) ^ (r & 7)) << 4)) + (d & 7) * 2;
      ushort_t hv = *(const ushort_t*)((const char*)kh_s + byo);
      ushort_t lv = *(const ushort_t*)((const char*)kl_s + byo);
      size_t go = (size_t)(bh * 128 + d) * 1024 + ci * 64 + r;
      kTh_g[go] = hv;
      kTl_g[go] = lv;
    }
  }

#pragma unroll
  for (int m = 0; m < 2; m++)
#pragma unroll
    for (int n = 0; n < 2; n++)
#pragma unroll
      for (int r = 0; r < 4; r++) {
        int i = wr + m * 16 + lg * 4 + r;
        int j = wc + n * 16 + lm;
        L_s[i * 64 + j] = (j < i) ? accL[m][n][r] : 0.f;
      }
  __syncthreads();

  stageHL(qs_h, qs_l, xh_s, xl_s);
  __syncthreads();

  f4_t accA[2][2];
  mm3(xh_s, xl_s, kh_s, kl_s, accA);
  ushort_t* abh = attn_h + (size_t)blockIdx.x * 4096;
  ushort_t* abl = attn_l + (size_t)blockIdx.x * 4096;
#pragma unroll
  for (int m = 0; m < 2; m++)
#pragma unroll
    for (int n = 0; n < 2; n++)
#pragma unroll
      for (int r = 0; r < 4; r++) {
        int i = wr + m * 16 + lg * 4 + r;
        int j = wc + n * 16 + lm;
        float val = (j <= i) ? accA[m][n][r] : 0.f;
        ushort_t hb = f2bf(val);
        abh[i * 64 + j] = hb;
        abl[i * 64 + j] = f2bf(val - bf2f(hb));
      }

  float x[64];
  const int c = tid & 127;
  const float* rhs = (tid < 128) ? (vb + gbase + c) : (kb + gbase + c);
#pragma unroll
  for (int j = 0; j < 64; j++) x[j] = rhs[(size_t)j * D];
#pragma unroll
  for (int i = 0; i < 64; i++) {
    float xi = x[i];
#pragma unroll
    for (int r2 = i + 1; r2 < 64; r2++) x[r2] -= L_s[r2 * 64 + i] * xi;
  }
  if (tid < 128) {
#pragma unroll
    for (int j = 0; j < 64; j++) u[gbase + (size_t)j * D + c] = x[j];
  } else {
#pragma unroll
    for (int j = 0; j < 64; j++) {
      ushort_t hb = f2bf(x[j]);
      w_h[gbase + (size_t)j * D + c] = hb;
      w_l[gbase + (size_t)j * D + c] = f2bf(x[j] - bf2f(hb));
    }
  }
}

// ------- sequential scan: grid(32 bh, 8 vgroups), 512 thr ------------------
// v9: phase1 inputs pre-split; all-MFMA phases; dbuf async staging
// (pre-swizzled global source); register prefetch.
__global__ __launch_bounds__(512, 2) void scan_kernel(const ushort_t* __restrict__ qs_h,
                                                      const ushort_t* __restrict__ qs_l,
                                                      const float* __restrict__ u,
                                                      const ushort_t* __restrict__ w_h,
                                                      const ushort_t* __restrict__ w_l,
                                                      const ushort_t* __restrict__ kTh_g,
                                                      const ushort_t* __restrict__ kTl_g,
                                                      const ushort_t* __restrict__ ath_g,
                                                      const ushort_t* __restrict__ atl_g,
                                                      float* __restrict__ o_lin) {
  __shared__ __align__(16) ushort_t kT_h[2][8192];   // [k][i] swizzled, dbuf
  __shared__ __align__(16) ushort_t kT_l[2][8192];
  __shared__ __align__(16) ushort_t at_h[2][4096];   // [i][j] swizzled, dbuf
  __shared__ __align__(16) ushort_t at_l[2][4096];
  __shared__ __align__(16) ushort_t Sh_s[16 * 128];  // S^T [c][k] swizzled
  __shared__ __align__(16) ushort_t Sl_s[16 * 128];
  __shared__ __align__(16) ushort_t uh_s[16 * 80];   // u'^T [c][i]
  __shared__ __align__(16) ushort_t ul_s[16 * 80];
  __shared__ __align__(16) float oT[16 * 68];        // q@S partial [c][i]
  const int tid = threadIdx.x;
  const int bh = blockIdx.x;
  const int b = bh >> 4, h = bh & 15;
  const int g = blockIdx.y;            // 0..7 (16 dv cols each)
  const int colbase = h * 128;
  const int vcol = h * 128 + g * 16;
  const int lane = tid & 63, wid = tid >> 6;
  const int lm = lane & 15, lg = lane >> 4;
  const int dsub = lane >> 3;          // 0..7
  const int i8x = (lane & 7) ^ dsub;   // pre-swizzled col group

  for (int i = tid; i < 16 * 128; i += 512) { Sh_s[i] = 0; Sl_s[i] = 0; }

  f4_t acc3[2];                        // persistent S tiles (waves 4-7)
  acc3[0] = (f4_t){0.f, 0.f, 0.f, 0.f};
  acc3[1] = (f4_t){0.f, 0.f, 0.f, 0.f};

  const ushort_t* kThb = kTh_g + (size_t)bh * 128 * 1024;
  const ushort_t* kTlb = kTl_g + (size_t)bh * 128 * 1024;

  auto issue_stage = [&](int buf, int chunk) {
#pragma unroll
    for (int it = 0; it < 2; it++) {
      int seg = it * 8 + wid;               // 0..15 (8 kT rows each)
      int d = seg * 8 + dsub;               // row 0..127
      size_t goff = (size_t)d * 1024 + chunk * 64 + i8x * 8;
      GLOAD16(kThb + goff, (char*)&kT_h[buf][0] + seg * 1024);
      GLOAD16(kTlb + goff, (char*)&kT_l[buf][0] + seg * 1024);
    }
    {
      int i = wid * 8 + dsub;               // attn row 0..63
      size_t asrc = (size_t)(bh * 16 + chunk) * 4096 + i * 64 + i8x * 8;
      GLOAD16(ath_g + asrc, (char*)&at_h[buf][0] + wid * 1024);
      GLOAD16(atl_g + asrc, (char*)&at_l[buf][0] + wid * 1024);
    }
  };

  const bool isU = (wid < 4);
  const int m0 = (isU ? wid : (wid - 4)) * 16;
  const ushort_t* AsrcH = isU ? w_h : qs_h;
  const ushort_t* AsrcL = isU ? w_l : qs_l;

  s8_t pAh[4], pAl[4];                  // prefetched hi/lo fragments
  float pu[4];
  auto prefetchA = [&](int chunk) {
    const size_t gb = (size_t)(b * 1024 + chunk * 64) * D;
#pragma unroll
    for (int ks = 0; ks < 4; ks++) {
      size_t off = gb + (size_t)(m0 + lm) * D + colbase + ks * 32 + lg * 8;
      pAh[ks] = *(const s8_t*)(AsrcH + off);
      pAl[ks] = *(const s8_t*)(AsrcL + off);
    }
    if (isU) {
#pragma unroll
      for (int r = 0; r < 4; r++)
        pu[r] = u[gb + (size_t)(m0 + lg * 4 + r) * D + vcol + lm];
    }
  };

  issue_stage(0, 0);
  prefetchA(0);
  __syncthreads();                      // S mirror init visible

  for (int chunk = 0; chunk < 16; chunk++) {
    const int cur = chunk & 1;
    const size_t gbase = (size_t)(b * 1024 + chunk * 64) * D;
    if (chunk + 1 < 16) issue_stage(cur ^ 1, chunk + 1);
    // ---- phase1 MFMA from prefetched pre-split regs: u' / q@S ----
    {
      f4_t acc = (f4_t){0.f, 0.f, 0.f, 0.f};
#pragma unroll
      for (int ks = 0; ks < 4; ks++) {
        int byo = (lm * 256 + ks * 64 + lg * 16) ^ ((lm & 7) << 4);
        s8_t sh = *(const s8_t*)((const char*)Sh_s + byo);
        s8_t sl = *(const s8_t*)((const char*)Sl_s + byo);
        acc = MFMA16(pAh[ks], sh, acc);
        acc = MFMA16(pAh[ks], sl, acc);
        acc = MFMA16(pAl[ks], sh, acc);
      }
      if (isU) {
        float res[4];
#pragma unroll
        for (int r = 0; r < 4; r++) res[r] = pu[r] - acc[r];
        us4_t rh, rl;
#pragma unroll
        for (int r = 0; r < 4; r++) {
          ushort_t hb = f2bf(res[r]);
          rh[r] = hb;
          rl[r] = f2bf(res[r] - bf2f(hb));
        }
        *(us4_t*)&uh_s[lm * 80 + m0 + lg * 4] = rh;
        *(us4_t*)&ul_s[lm * 80 + m0 + lg * 4] = rl;
      } else {
        float4 res = {acc[0], acc[1], acc[2], acc[3]};
        *(float4*)&oT[lm * 68 + m0 + lg * 4] = res;
      }
    }
    __syncthreads();                     // B: u', oT visible; staging drained
    if (chunk + 1 < 16) prefetchA(chunk + 1);
    if (isU) {
      // ---- phase2 MFMA: o = oT + attn @ u' ; store to global ----
      float4 o0 = *(const float4*)&oT[lm * 68 + m0 + lg * 4];
      f4_t acc2 = (f4_t){o0.x, o0.y, o0.z, o0.w};
#pragma unroll
      for (int ks = 0; ks < 2; ks++) {
        int arow = m0 + lm;
        int abyo = arow * 128 + ((ks * 64 + lg * 16) ^ ((arow & 7) << 4));
        s8_t afh = *(const s8_t*)((const char*)&at_h[cur][0] + abyo);
        s8_t afl = *(const s8_t*)((const char*)&at_l[cur][0] + abyo);
        s8_t ufh = *(const s8_t*)&uh_s[lm * 80 + ks * 32 + lg * 8];
        s8_t ufl = *(const s8_t*)&ul_s[lm * 80 + ks * 32 + lg * 8];
        acc2 = MFMA16(afh, ufh, acc2);
        acc2 = MFMA16(afh, ufl, acc2);
        acc2 = MFMA16(afl, ufh, acc2);
      }
#pragma unroll
      for (int r = 0; r < 4; r++)
        o_lin[gbase + (size_t)(m0 + lg * 4 + r) * D + vcol + lm] = acc2[r];
    } else {
      // ---- phase3 MFMA: S += u'^T @ kT (persistent acc) + mirror refresh --
      const int w3 = wid - 4;
      s8_t ufh0 = *(const s8_t*)&uh_s[lm * 80 + 0 * 32 + lg * 8];
      s8_t ufl0 = *(const s8_t*)&ul_s[lm * 80 + 0 * 32 + lg * 8];
      s8_t ufh1 = *(const s8_t*)&uh_s[lm * 80 + 1 * 32 + lg * 8];
      s8_t ufl1 = *(const s8_t*)&ul_s[lm * 80 + 1 * 32 + lg * 8];
#pragma unroll
      for (int t = 0; t < 2; t++) {
        const int krow = (w3 * 2 + t) * 16 + lm;
        int b0 = krow * 128 + ((0 * 64 + lg * 16) ^ ((krow & 7) << 4));
        int b1 = krow * 128 + ((1 * 64 + lg * 16) ^ ((krow & 7) << 4));
        s8_t kh0 = *(const s8_t*)((const char*)&kT_h[cur][0] + b0);
        s8_t kl0 = *(const s8_t*)((const char*)&kT_l[cur][0] + b0);
        s8_t kh1 = *(const s8_t*)((const char*)&kT_h[cur][0] + b1);
        s8_t kl1 = *(const s8_t*)((const char*)&kT_l[cur][0] + b1);
        acc3[t] = MFMA16(ufh0, kh0, acc3[t]);
        acc3[t] = MFMA16(ufh0, kl0, acc3[t]);
        acc3[t] = MFMA16(ufl0, kh0, acc3[t]);
        acc3[t] = MFMA16(ufh1, kh1, acc3[t]);
        acc3[t] = MFMA16(ufh1, kl1, acc3[t]);
        acc3[t] = MFMA16(ufl1, kh1, acc3[t]);
      }
#pragma unroll
      for (int t = 0; t < 2; t++)
#pragma unroll
        for (int r = 0; r < 4; r++) {
          int c = lg * 4 + r;
          int k = (w3 * 2 + t) * 16 + lm;
          float sval = acc3[t][r];
          ushort_t hb = f2bf(sval);
          int sbyo = (c * 256 + k * 2) ^ ((c & 7) << 4);
          *(ushort_t*)((char*)Sh_s + sbyo) = hb;
          *(ushort_t*)((char*)Sl_s + sbyo) = f2bf(sval - bf2f(hb));
        }
    }
    __syncthreads();                     // C: reads done; mirror ordered
  }
}

// -------- v (from fp16 qkv) -> transposed bf16 vt[b][h][d][n] -------------
__global__ __launch_bounds__(256) void v_transpose(const _Float16* __restrict__ qkv,
                                                   ushort_t* __restrict__ vt) {
  __shared__ float t[32][33];
  const int tid = threadIdx.x;
  const int n0 = blockIdx.x * 32;
  const int d0 = blockIdx.y * 32;
  const int bh = blockIdx.z;
  const int b = bh >> 4, h = bh & 15;
  const int c = tid & 31, rr = tid >> 5;
#pragma unroll
  for (int p = 0; p < 4; p++) {
    int r = p * 8 + rr;
    t[r][c] = (float)qkv[(size_t)(b * 1024 + n0 + r) * NQKV + 4096 + h * 128 + d0 + c];
  }
  __syncthreads();
#pragma unroll
  for (int p = 0; p < 4; p++) {
    int r = p * 8 + rr;
    vt[(size_t)(bh * 128 + d0 + r) * 1024 + n0 + c] = f2bf(t[c][r]);
  }
}

// -------- MFMA bf16 flash attention + 0.5/0.5 mix + fp16 out --------------
// Longest blocks (qt near 15) launch FIRST for load balance.
__global__ __launch_bounds__(256) void attn_mfma(const ushort_t* __restrict__ qb,
                                                 const ushort_t* __restrict__ kb,
                                                 const ushort_t* __restrict__ vt,
                                                 const float* __restrict__ o_lin,
                                                 _Float16* __restrict__ mixh) {
  __shared__ __align__(16) ushort_t K_s[8192];
  __shared__ __align__(16) ushort_t V_s[8192];
  __shared__ __align__(16) ushort_t P_s[4][1152];
  const int tid = threadIdx.x;
  const int lane = tid & 63, wid = tid >> 6;
  const int bh = blockIdx.x;
  const int b = bh >> 4, h = bh & 15;
  const int qt = (int)(gridDim.y - 1) - (int)blockIdx.y;   // longest-first
  const int lm = lane & 15, lg = lane >> 4;

  s8_t qf[4];
  const size_t qrowG = (size_t)(b * 1024 + qt * 64 + wid * 16 + lm);
#pragma unroll
  for (int kb4 = 0; kb4 < 4; kb4++)
    qf[kb4] = *(const s8_t*)(qb + qrowG * D + h * 128 + kb4 * 32 + lg * 8);

  f4_t o[8];
#pragma unroll
  for (int n = 0; n < 8; n++) o[n] = (f4_t){0.f, 0.f, 0.f, 0.f};
  float mrow[4] = {-INFINITY, -INFINITY, -INFINITY, -INFINITY};
  float lrow[4] = {0.f, 0.f, 0.f, 0.f};
  const int myq = qt * 64 + wid * 16 + lg * 4;

  for (int kt = 0; kt <= qt; kt++) {
    __syncthreads();
#pragma unroll
    for (int p = 0; p < 4; p++) {
      int c = tid + p * 256;
      int key = c >> 4, dc = c & 15;
      s8_t v = *(const s8_t*)(kb + (size_t)(b * 1024 + kt * 64 + key) * D + h * 128 + dc * 8);
      int byo = key * 256 + ((dc * 16) ^ ((key & 7) << 4));
      *(s8_t*)((char*)K_s + byo) = v;
    }
#pragma unroll
    for (int p = 0; p < 4; p++) {
      int c = tid + p * 256;
      int d = c >> 3, nc = c & 7;
      s8_t v = *(const s8_t*)(vt + (size_t)(bh * 128 + d) * 1024 + kt * 64 + nc * 8);
      int byo = d * 128 + ((nc * 16) ^ ((d & 7) << 4));
      *(s8_t*)((char*)V_s + byo) = v;
    }
    __syncthreads();

    f4_t s[4];
#pragma unroll
    for (int ks = 0; ks < 4; ks++) {
      f4_t a = (f4_t){0.f, 0.f, 0.f, 0.f};
      int key = ks * 16 + lm;
#pragma unroll
      for (int kb4 = 0; kb4 < 4; kb4++) {
        int byo = key * 256 + ((kb4 * 64 + lg * 16) ^ ((key & 7) << 4));
        s8_t kf = *(const s8_t*)((char*)K_s + byo);
        a = MFMA16(qf[kb4], kf, a);
      }
      s[ks] = a;
    }
    if (kt == qt) {
#pragma unroll
      for (int ks = 0; ks < 4; ks++) {
        int key = kt * 64 + ks * 16 + lm;
#pragma unroll
        for (int r = 0; r < 4; r++)
          if (key > myq + r) s[ks][r] = -INFINITY;
      }
    }
    float mloc[4];
#pragma unroll
    for (int r = 0; r < 4; r++) {
      mloc[r] = fmaxf(fmaxf(s[0][r], s[1][r]), fmaxf(s[2][r], s[3][r]));
      mloc[r] = fmaxf(mloc[r], __shfl_xor(mloc[r], 1));
      mloc[r] = fmaxf(mloc[r], __shfl_xor(mloc[r], 2));
      mloc[r] = fmaxf(mloc[r], __shfl_xor(mloc[r], 4));
      mloc[r] = fmaxf(mloc[r], __shfl_xor(mloc[r], 8));
    }
    float scale[4];
#pragma unroll
    for (int r = 0; r < 4; r++) {
      float mn = fmaxf(mrow[r], mloc[r]);
      scale[r] = __expf(mrow[r] - mn);
      mrow[r] = mn;
    }
    float lad[4] = {0.f, 0.f, 0.f, 0.f};
#pragma unroll
    for (int ks = 0; ks < 4; ks++)
#pragma unroll
      for (int r = 0; r < 4; r++) {
        float p = __expf(s[ks][r] - mrow[r]);
        lad[r] += p;
        P_s[wid][(lg * 4 + r) * 72 + ks * 16 + lm] = f2bf(p);
      }
#pragma unroll
    for (int r = 0; r < 4; r++) {
      lad[r] += __shfl_xor(lad[r], 1);
      lad[r] += __shfl_xor(lad[r], 2);
      lad[r] += __shfl_xor(lad[r], 4);
      lad[r] += __shfl_xor(lad[r], 8);
      lrow[r] = lrow[r] * scale[r] + lad[r];
    }
#pragma unroll
    for (int n = 0; n < 8; n++)
#pragma unroll
      for (int r = 0; r < 4; r++) o[n][r] *= scale[r];

    s8_t pf[2];
#pragma unroll
    for (int ksl = 0; ksl < 2; ksl++)
      pf[ksl] = *(const s8_t*)&P_s[wid][lm * 72 + ksl * 32 + lg * 8];
#pragma unroll
    for (int n = 0; n < 8; n++) {
      int d = n * 16 + lm;
#pragma unroll
      for (int ksl = 0; ksl < 2; ksl++) {
        int byo = d * 128 + ((ksl * 64 + lg * 16) ^ ((d & 7) << 4));
        s8_t vf = *(const s8_t*)((char*)V_s + byo);
        o[n] = MFMA16(pf[ksl], vf, o[n]);
      }
    }
  }

  float invl[4];
#pragma unroll
  for (int r = 0; r < 4; r++) invl[r] = 1.f / lrow[r];
#pragma unroll
  for (int n = 0; n < 8; n++)
#pragma unroll
    for (int r = 0; r < 4; r++) {
      size_t G = (size_t)(b * 1024 + qt * 64 + wid * 16 + lg * 4 + r);
      int dcol = h * 128 + n * 16 + lm;
      float mix = 0.5f * (o[n][r] * invl[r]) + 0.5f * o_lin[G * D + dcol];
      mixh[G * D + dcol] = (_Float16)mix;
    }
}

// ---------------------------------------------------------------------------
extern "C" void kernel_launch(void* const* d_in, const int* in_sizes, int n_in,
                              void* d_out, int out_size, void* d_ws, size_t ws_size,
                              hipStream_t stream) {
  const float* x  = (const float*)d_in[0];
  const float* Wq = (const float*)d_in[1];
  const float* Wk = (const float*)d_in[2];
  const float* Wv = (const float*)d_in[3];
  const float* Wo = (const float*)d_in[4];
  float* out = (float*)d_out;
  float* ws = (float*)d_ws;

  const size_t B = (size_t)NROWS * D;   // 4,194,304 floats per slot
  _Float16* qkv = (_Float16*)(ws + 0 * B);   // [2048][6144] fp16 (slots 0-1)
  float* q_s  = ws + 3 * B;                  // holds qs_h/qs_l (bf16 pair)
  float* k_sm = ws + 4 * B;
  float* kbuf = ws + 5 * B;
  float* vbuf = ws + 6 * B;
  float* u    = ws + 7 * B;
  float* w    = ws + 8 * B;                  // holds w_h/w_l (bf16 pair)
  float* o_lin = kbuf;

  _Float16* x_hi = (_Float16*)u;                    // dead before chunk_uw writes u
  _Float16* Wt   = (_Float16*)(ws + 9 * B);         // QKV weights, dead after gemm1h
  ushort_t* attn_h = (ushort_t*)(ws + 9 * B);                 // after gemm1h
  ushort_t* attn_l = attn_h + (size_t)2097152;
  ushort_t* kTh_g  = (ushort_t*)(ws + 9 * B + 2097152);       // 4M u16
  ushort_t* kTl_g  = (ushort_t*)(ws + 10 * B);                // 4M u16
  _Float16* Wo_t   = (_Float16*)(ws + 10 * B + 2097152);      // own region
  ushort_t* qs_h = (ushort_t*)q_s;
  ushort_t* qs_l = qs_h + B;
  ushort_t* w_h  = (ushort_t*)w;
  ushort_t* w_l  = w_h + B;
  ushort_t* qb16 = (ushort_t*)(ws + 2 * B);
  ushort_t* kb16 = qb16 + B;
  ushort_t* vt16 = (ushort_t*)vbuf;
  _Float16* mixh = (_Float16*)qkv;

  split_h<<<4096, 256, 0, stream>>>(x, x_hi);
  wsplit4<<<dim3(64, 64, 4), 256, 0, stream>>>(Wq, Wk, Wv, Wo, Wt, Wo_t);
  gemm1h<<<16 * 48, 256, 0, stream>>>(x_hi, Wt, qkv, NROWS, NQKV, D);

  act_kernel<<<8192, 256, 0, stream>>>(qkv, qs_h, qs_l, k_sm, kbuf, vbuf, qb16, kb16);
  chunk_uw_kernel<<<512, 256, 0, stream>>>(qs_h, qs_l, k_sm, kbuf, vbuf, u, w_h, w_l,
                                           attn_h, attn_l, kTh_g, kTl_g);
  scan_kernel<<<dim3(32, 8), 512, 0, stream>>>(qs_h, qs_l, u, w_h, w_l, kTh_g, kTl_g, attn_h, attn_l, o_lin);

  v_transpose<<<dim3(32, 4, 32), 256, 0, stream>>>(qkv, vt16);
  attn_mfma<<<dim3(32, 16), 256, 0, stream>>>(qb16, kb16, vt16, o_lin, mixh);

  gemm1<<<16 * 16, 256, 0, stream>>>(mixh, Wo_t, out, NROWS, D, D);
}

// Round 21
// 275.725 us; speedup vs baseline: 1.1710x; 1.0071x over previous
//
#include <hip/hip_runtime.h>
#include <hip/hip_bf16.h>
#include <math.h>

#define D 2048
#define NROWS 2048      // b*n
#define NQKV 6144       // fused QKV width
#define H 16
#define DH 128
#define CHK 64
#define NC 16
#define EPSC 1e-6f
#define RSQDH 0.08838834764831845f   // 128^-0.5

typedef unsigned short ushort_t;
typedef __attribute__((ext_vector_type(4))) float f4_t;
typedef __attribute__((ext_vector_type(8))) short s8_t;
typedef __attribute__((ext_vector_type(8))) _Float16 h8_t;
typedef __attribute__((ext_vector_type(4))) _Float16 h4_t;
typedef __attribute__((ext_vector_type(2))) _Float16 h2_t;
typedef __attribute__((ext_vector_type(4))) unsigned short us4_t;
typedef __attribute__((ext_vector_type(2))) unsigned short us2_t;

#define MFMA16(a, b, c) __builtin_amdgcn_mfma_f32_16x16x32_bf16((a), (b), (c), 0, 0, 0)
#define MFMAH(a, b, c)  __builtin_amdgcn_mfma_f32_16x16x32_f16((a), (b), (c), 0, 0, 0)
#define GLOAD16(g, l) __builtin_amdgcn_global_load_lds((const __attribute__((address_space(1))) unsigned int*)(g), (__attribute__((address_space(3))) unsigned int*)(l), 16, 0, 0)

__device__ __forceinline__ ushort_t f2bf(float f) {
  union { float f; unsigned u; } v; v.f = f;
  unsigned r = (v.u + 0x7fffu + ((v.u >> 16) & 1u)) >> 16;
  return (ushort_t)r;
}
__device__ __forceinline__ float bf2f(ushort_t h) {
  union { unsigned u; float f; } v; v.u = ((unsigned)h) << 16;
  return v.f;
}

// ---------------- fp32 -> fp16 (1-term, for QKV GEMM A) --------------------
__global__ __launch_bounds__(256) void split_h(const float* __restrict__ in,
                                               _Float16* __restrict__ hi) {
  int i = (blockIdx.x * 256 + threadIdx.x) * 4;
  float4 v = *(const float4*)(in + i);
  float vv[4] = {v.x, v.y, v.z, v.w};
  h4_t h;
#pragma unroll
  for (int j = 0; j < 4; j++) h[j] = (_Float16)vv[j];
  *(h4_t*)(hi + i) = h;
}

// ------------- all 4 weights: transpose + fp16 round, one launch -----------
__global__ __launch_bounds__(256) void wsplit4(const float* __restrict__ Wq,
                                               const float* __restrict__ Wk,
                                               const float* __restrict__ Wv,
                                               const float* __restrict__ Wo,
                                               _Float16* __restrict__ Tqkv,
                                               _Float16* __restrict__ To) {
  __shared__ float t[32][33];
  const int tid = threadIdx.x;
  const int k0 = blockIdx.y * 32, n0 = blockIdx.x * 32;
  const int z = blockIdx.z;
  const float* W = (z == 0) ? Wq : (z == 1) ? Wk : (z == 2) ? Wv : Wo;
  _Float16* T = (z < 3) ? (Tqkv + (size_t)z * D * D) : To;
  const int c = tid & 31, rr = tid >> 5;
#pragma unroll
  for (int p = 0; p < 4; p++) {
    int r = p * 8 + rr;
    t[r][c] = W[(size_t)(k0 + r) * D + n0 + c];
  }
  __syncthreads();
#pragma unroll
  for (int p = 0; p < 4; p++) {
    int r = p * 8 + rr;
    T[(size_t)(n0 + r) * D + k0 + c] = (_Float16)t[c][r];
  }
}

// ------ fp16 1-term MFMA GEMM (fp32 out, final Wo GEMM) --------------------
__global__ __launch_bounds__(256) void gemm1(const _Float16* __restrict__ Ah,
                                             const _Float16* __restrict__ Bt,
                                             float* __restrict__ C,
                                             int M, int N, int K) {
  __shared__ __align__(16) ushort_t A_s[2][4096];    // [128][32]
  __shared__ __align__(16) ushort_t B_s[2][4096];    // [128 cols][32 k]
  const int tid = threadIdx.x, lane = tid & 63, wid = tid >> 6;
  const int nwg = gridDim.x;
  int bid = blockIdx.x;
  int swz = (bid & 7) * (nwg >> 3) + (bid >> 3);     // XCD swizzle (nwg%8==0)
  const int nbn = N >> 7;
  const int bm = swz / nbn, bn = swz % nbn;
  const int row0 = bm << 7, col0 = bn << 7;
  const int lm = lane & 15, lg = lane >> 4;
  const int wrow = (wid >> 1) * 64, wcol = (wid & 1) * 64;
  const int NT = K >> 5;

  f4_t acc[4][4];
#pragma unroll
  for (int m = 0; m < 4; m++)
#pragma unroll
    for (int n = 0; n < 4; n++) acc[m][n] = (f4_t){0.f, 0.f, 0.f, 0.f};

  auto stage = [&](int buf, int ks) {
    int k0 = ks << 5;
#pragma unroll
    for (int p = 0; p < 2; p++) {
      int c = p * 256 + wid * 64 + lane;             // 16B chunk 0..511
      int r = c >> 2, q = (c & 3) * 8;
      char* la = (char*)&A_s[buf][0] + p * 4096 + wid * 1024;
      GLOAD16(Ah + (size_t)(row0 + r) * K + k0 + q, la);
      char* lb = (char*)&B_s[buf][0] + p * 4096 + wid * 1024;
      GLOAD16(Bt + (size_t)(col0 + r) * K + k0 + q, lb);
    }
  };

  stage(0, 0);
  __syncthreads();
  for (int t = 0; t < NT; t++) {
    int cur = t & 1;
    if (t + 1 < NT) stage(cur ^ 1, t + 1);
    h8_t af[4], bfr[4];
#pragma unroll
    for (int m = 0; m < 4; m++)
      af[m] = *(const h8_t*)&A_s[cur][(wrow + m * 16 + lm) * 32 + lg * 8];
#pragma unroll
    for (int n = 0; n < 4; n++)
      bfr[n] = *(const h8_t*)&B_s[cur][(wcol + n * 16 + lm) * 32 + lg * 8];
#pragma unroll
    for (int m = 0; m < 4; m++)
#pragma unroll
      for (int n = 0; n < 4; n++)
        acc[m][n] = MFMAH(af[m], bfr[n], acc[m][n]);
    __syncthreads();
  }
#pragma unroll
  for (int m = 0; m < 4; m++)
#pragma unroll
    for (int n = 0; n < 4; n++)
#pragma unroll
      for (int r = 0; r < 4; r++)
        C[(size_t)(row0 + wrow + m * 16 + lg * 4 + r) * N + col0 + wcol + n * 16 + lm] = acc[m][n][r];
}

// ------ fp16 1-term MFMA GEMM (fp16 out, QKV projection) -------------------
__global__ __launch_bounds__(256) void gemm1h(const _Float16* __restrict__ Ah,
                                              const _Float16* __restrict__ Bt,
                                              _Float16* __restrict__ C,
                                              int M, int N, int K) {
  __shared__ __align__(16) ushort_t A_s[2][4096];    // [128][32]
  __shared__ __align__(16) ushort_t B_s[2][4096];    // [128 cols][32 k]
  const int tid = threadIdx.x, lane = tid & 63, wid = tid >> 6;
  const int nwg = gridDim.x;
  int bid = blockIdx.x;
  int swz = (bid & 7) * (nwg >> 3) + (bid >> 3);     // XCD swizzle (nwg%8==0)
  const int nbn = N >> 7;
  const int bm = swz / nbn, bn = swz % nbn;
  const int lm = lane & 15, lg = lane >> 4;
  const int row0 = bm << 7, col0 = bn << 7;
  const int wrow = (wid >> 1) * 64, wcol = (wid & 1) * 64;
  const int NT = K >> 5;

  f4_t acc[4][4];
#pragma unroll
  for (int m = 0; m < 4; m++)
#pragma unroll
    for (int n = 0; n < 4; n++) acc[m][n] = (f4_t){0.f, 0.f, 0.f, 0.f};

  auto stage = [&](int buf, int ks) {
    int k0 = ks << 5;
#pragma unroll
    for (int p = 0; p < 2; p++) {
      int c = p * 256 + wid * 64 + lane;             // 16B chunk 0..511
      int r = c >> 2, q = (c & 3) * 8;
      char* la = (char*)&A_s[buf][0] + p * 4096 + wid * 1024;
      GLOAD16(Ah + (size_t)(row0 + r) * K + k0 + q, la);
      char* lb = (char*)&B_s[buf][0] + p * 4096 + wid * 1024;
      GLOAD16(Bt + (size_t)(col0 + r) * K + k0 + q, lb);
    }
  };

  stage(0, 0);
  __syncthreads();
  for (int t = 0; t < NT; t++) {
    int cur = t & 1;
    if (t + 1 < NT) stage(cur ^ 1, t + 1);
    h8_t af[4], bfr[4];
#pragma unroll
    for (int m = 0; m < 4; m++)
      af[m] = *(const h8_t*)&A_s[cur][(wrow + m * 16 + lm) * 32 + lg * 8];
#pragma unroll
    for (int n = 0; n < 4; n++)
      bfr[n] = *(const h8_t*)&B_s[cur][(wcol + n * 16 + lm) * 32 + lg * 8];
#pragma unroll
    for (int m = 0; m < 4; m++)
#pragma unroll
      for (int n = 0; n < 4; n++)
        acc[m][n] = MFMAH(af[m], bfr[n], acc[m][n]);
    __syncthreads();
  }
#pragma unroll
  for (int m = 0; m < 4; m++)
#pragma unroll
    for (int n = 0; n < 4; n++)
#pragma unroll
      for (int r = 0; r < 4; r++)
        C[(size_t)(row0 + wrow + m * 16 + lg * 4 + r) * N + col0 + wcol + n * 16 + lm] = (_Float16)acc[m][n][r];
}

// ---- activations: qs emitted as bf16 hi/lo; qk->bf16 fused ----------------
__device__ __forceinline__ float gate_fn(float z) {
  float t = -z;
  float sp = (t > 20.f) ? t : log1pf(expf(t));   // softplus(-z)
  float g = -sp * (1.f / 16.f);                  // log_sigmoid(z)/16
  return fminf(fmaxf(g, -16.f), 16.f);
}

__global__ __launch_bounds__(256) void act_kernel(const _Float16* __restrict__ qkv,
                                                  ushort_t* __restrict__ qs_h,
                                                  ushort_t* __restrict__ qs_l,
                                                  float* __restrict__ ksm,
                                                  float* __restrict__ kb,
                                                  float* __restrict__ vb,
                                                  ushort_t* __restrict__ qb16,
                                                  ushort_t* __restrict__ kb16) {
  int wave = blockIdx.x * 4 + (threadIdx.x >> 6);  // (row*16 + h)
  int lane = threadIdx.x & 63;
  int row = wave >> 4, h = wave & 15;
  size_t inb = (size_t)row * NQKV + h * 128;
  size_t base = (size_t)wave * 128;
  const int e0 = 2 * lane;                         // lane owns elems e0, e0+1

  h2_t qv = *(const h2_t*)(qkv + inb + e0);
  h2_t kv = *(const h2_t*)(qkv + inb + 2048 + e0);
  h2_t vv = *(const h2_t*)(qkv + inb + 4096 + e0);
  float q0 = (float)qv[0], q1 = (float)qv[1];
  float k0 = (float)kv[0], k1 = (float)kv[1];
  float v0 = (float)vv[0], v1 = (float)vv[1];

  // fused raw-logit bf16 outputs for base attention
  us2_t qo = {f2bf(q0 * RSQDH), f2bf(q1 * RSQDH)};
  us2_t ko = {f2bf(k0), f2bf(k1)};
  *(us2_t*)(qb16 + base + e0) = qo;
  *(us2_t*)(kb16 + base + e0) = ko;

  float m = fmaxf(q0, q1);
  for (int o = 1; o < 64; o <<= 1) m = fmaxf(m, __shfl_xor(m, o));
  float e0f = expf(q0 - m), e1f = expf(q1 - m);
  float s = e0f + e1f;
  for (int o = 1; o < 64; o <<= 1) s += __shfl_xor(s, o);
  float inv = 1.f / s;
  float qs0 = fminf(fmaxf(e0f * inv, EPSC), 1.f - EPSC) * RSQDH;
  float qs1 = fminf(fmaxf(e1f * inv, EPSC), 1.f - EPSC) * RSQDH;

  float mk = fmaxf(k0, k1);
  for (int o = 1; o < 64; o <<= 1) mk = fmaxf(mk, __shfl_xor(mk, o));
  float f0 = expf(k0 - mk), f1 = expf(k1 - mk);
  float sk = f0 + f1;
  for (int o = 1; o < 64; o <<= 1) sk += __shfl_xor(sk, o);
  float invk = 1.f / sk;
  float ks0 = fminf(fmaxf(f0 * invk, EPSC), 1.f - EPSC);
  float ks1 = fminf(fmaxf(f1 * invk, EPSC), 1.f - EPSC);

  float g0 = gate_fn(k0), g1 = gate_fn(k1);

  // qs as bf16 hi/lo (split once; consumers use directly)
  ushort_t qh0 = f2bf(qs0), qh1 = f2bf(qs1);
  us2_t qhv = {qh0, qh1};
  us2_t qlv = {f2bf(qs0 - bf2f(qh0)), f2bf(qs1 - bf2f(qh1))};
  *(us2_t*)(qs_h + base + e0) = qhv;
  *(us2_t*)(qs_l + base + e0) = qlv;

  *(float2*)(ksm + base + e0) = make_float2(ks0, ks1);
  *(float2*)(kb + base + e0) = make_float2(ks0 * g0, ks1 * g1);
  *(float2*)(vb + base + e0) = make_float2(v0 * g0, v1 * g1);
}

// ------- per-chunk (MFMA): L = kb@k^T, attn = q@k^T, fwd-subst -> u, w -----
// qs consumed pre-split; w emitted pre-split; kT hi/lo emitted from staged
// LDS k tile (replaces the separate k_transpose kernel).
__global__ __launch_bounds__(256) void chunk_uw_kernel(const ushort_t* __restrict__ qs_h,
                                                       const ushort_t* __restrict__ qs_l,
                                                       const float* __restrict__ ksm,
                                                       const float* __restrict__ kb,
                                                       const float* __restrict__ vb,
                                                       float* __restrict__ u,
                                                       ushort_t* __restrict__ w_h,
                                                       ushort_t* __restrict__ w_l,
                                                       ushort_t* __restrict__ attn_h,
                                                       ushort_t* __restrict__ attn_l,
                                                       ushort_t* __restrict__ kTh_g,
                                                       ushort_t* __restrict__ kTl_g) {
  __shared__ __align__(16) ushort_t kh_s[8192];   // k hi  [64][128] swizzled
  __shared__ __align__(16) ushort_t kl_s[8192];   // k lo
  __shared__ __align__(16) ushort_t xh_s[8192];   // kb hi, then q hi
  __shared__ __align__(16) ushort_t xl_s[8192];   // kb lo, then q lo
  __shared__ float L_s[4096];                     // [64][64]
  const int tid = threadIdx.x, lane = tid & 63, wid = tid >> 6;
  const int lm = lane & 15, lg = lane >> 4;
  const int bh = blockIdx.x >> 4, ci = blockIdx.x & 15;
  const int rowbase = (bh >> 4) * 1024 + ci * 64;
  const int colbase = (bh & 15) * 128;
  const size_t gbase = (size_t)rowbase * D + colbase;
  const int wr = (wid >> 1) * 32, wc = (wid & 1) * 32;

  auto stageM = [&](const float* __restrict__ src, ushort_t* dh, ushort_t* dl) {
#pragma unroll
    for (int it = 0; it < 4; it++) {
      int idx = tid + it * 256;
      int r = idx >> 4, c8 = idx & 15;
      const float* g = src + gbase + (size_t)r * D + c8 * 8;
      float4 v0 = *(const float4*)g;
      float4 v1 = *(const float4*)(g + 4);
      float vv[8] = {v0.x, v0.y, v0.z, v0.w, v1.x, v1.y, v1.z, v1.w};
      s8_t hv, lv;
#pragma unroll
      for (int j = 0; j < 8; j++) {
        ushort_t hb = f2bf(vv[j]);
        hv[j] = (short)hb;
        lv[j] = (short)f2bf(vv[j] - bf2f(hb));
      }
      int byo = r * 256 + ((c8 * 16) ^ ((r & 7) << 4));
      *(s8_t*)((char*)dh + byo) = hv;
      *(s8_t*)((char*)dl + byo) = lv;
    }
  };

  // pre-split source: pure swizzled copy, no conversion
  auto stageHL = [&](const ushort_t* __restrict__ srcH,
                     const ushort_t* __restrict__ srcL,
                     ushort_t* dh, ushort_t* dl) {
#pragma unroll
    for (int it = 0; it < 4; it++) {
      int idx = tid + it * 256;
      int r = idx >> 4, c8 = idx & 15;
      size_t g = gbase + (size_t)r * D + c8 * 8;
      s8_t hv = *(const s8_t*)(srcH + g);
      s8_t lv = *(const s8_t*)(srcL + g);
      int byo = r * 256 + ((c8 * 16) ^ ((r & 7) << 4));
      *(s8_t*)((char*)dh + byo) = hv;
      *(s8_t*)((char*)dl + byo) = lv;
    }
  };

  auto mm3 = [&](const ushort_t* Ah, const ushort_t* Al,
                 const ushort_t* Bh, const ushort_t* Bl, f4_t acc[2][2]) {
#pragma unroll
    for (int m = 0; m < 2; m++)
#pragma unroll
      for (int n = 0; n < 2; n++) acc[m][n] = (f4_t){0.f, 0.f, 0.f, 0.f};
#pragma unroll
    for (int term = 0; term < 3; term++) {
      const ushort_t* A = (term == 2) ? Al : Ah;
      const ushort_t* Bsrc = (term == 1) ? Bl : Bh;
#pragma unroll
      for (int ks = 0; ks < 4; ks++) {
        s8_t af[2], bf_[2];
#pragma unroll
        for (int m = 0; m < 2; m++) {
          int row = wr + m * 16 + lm;
          int byo = row * 256 + ((ks * 64 + lg * 16) ^ ((row & 7) << 4));
          af[m] = *(const s8_t*)((const char*)A + byo);
        }
#pragma unroll
        for (int n = 0; n < 2; n++) {
          int row = wc + n * 16 + lm;
          int byo = row * 256 + ((ks * 64 + lg * 16) ^ ((row & 7) << 4));
          bf_[n] = *(const s8_t*)((const char*)Bsrc + byo);
        }
#pragma unroll
        for (int m = 0; m < 2; m++)
#pragma unroll
          for (int n = 0; n < 2; n++)
            acc[m][n] = MFMA16(af[m], bf_[n], acc[m][n]);
      }
    }
  };

  stageM(ksm, kh_s, kl_s);
  stageM(kb, xh_s, xl_s);
  __syncthreads();

  f4_t accL[2][2];
  mm3(xh_s, xl_s, kh_s, kl_s, accL);

  // ---- emit kT hi/lo (transposed) from staged LDS k tile ----
  {
    const int dw = wid * 32;             // wave covers d = dw..dw+31
    const int r = lane;                  // n index within chunk (0..63)
#pragma unroll
    for (int i = 0; i < 32; i++) {
      int d = dw + i;
      int byo = r * 256 + ((((d >> 3) ^ (r & 7)) << 4)) + (d & 7) * 2;
      ushort_t hv = *(const ushort_t*)((const char*)kh_s + byo);
      ushort_t lv = *(const ushort_t*)((const char*)kl_s + byo);
      size_t go = (size_t)(bh * 128 + d) * 1024 + ci * 64 + r;
      kTh_g[go] = hv;
      kTl_g[go] = lv;
    }
  }

#pragma unroll
  for (int m = 0; m < 2; m++)
#pragma unroll
    for (int n = 0; n < 2; n++)
#pragma unroll
      for (int r = 0; r < 4; r++) {
        int i = wr + m * 16 + lg * 4 + r;
        int j = wc + n * 16 + lm;
        L_s[i * 64 + j] = (j < i) ? accL[m][n][r] : 0.f;
      }
  __syncthreads();

  stageHL(qs_h, qs_l, xh_s, xl_s);
  __syncthreads();

  f4_t accA[2][2];
  mm3(xh_s, xl_s, kh_s, kl_s, accA);
  ushort_t* abh = attn_h + (size_t)blockIdx.x * 4096;
  ushort_t* abl = attn_l + (size_t)blockIdx.x * 4096;
#pragma unroll
  for (int m = 0; m < 2; m++)
#pragma unroll
    for (int n = 0; n < 2; n++)
#pragma unroll
      for (int r = 0; r < 4; r++) {
        int i = wr + m * 16 + lg * 4 + r;
        int j = wc + n * 16 + lm;
        float val = (j <= i) ? accA[m][n][r] : 0.f;
        ushort_t hb = f2bf(val);
        abh[i * 64 + j] = hb;
        abl[i * 64 + j] = f2bf(val - bf2f(hb));
      }

  float x[64];
  const int c = tid & 127;
  const float* rhs = (tid < 128) ? (vb + gbase + c) : (kb + gbase + c);
#pragma unroll
  for (int j = 0; j < 64; j++) x[j] = rhs[(size_t)j * D];
#pragma unroll
  for (int i = 0; i < 64; i++) {
    float xi = x[i];
#pragma unroll
    for (int r2 = i + 1; r2 < 64; r2++) x[r2] -= L_s[r2 * 64 + i] * xi;
  }
  if (tid < 128) {
#pragma unroll
    for (int j = 0; j < 64; j++) u[gbase + (size_t)j * D + c] = x[j];
  } else {
#pragma unroll
    for (int j = 0; j < 64; j++) {
      ushort_t hb = f2bf(x[j]);
      w_h[gbase + (size_t)j * D + c] = hb;
      w_l[gbase + (size_t)j * D + c] = f2bf(x[j] - bf2f(hb));
    }
  }
}

// ------- sequential scan: grid(32 bh, 8 vgroups), 512 thr ------------------
// v9: phase1 inputs pre-split; all-MFMA phases; dbuf async staging
// (pre-swizzled global source); register prefetch.
__global__ __launch_bounds__(512, 2) void scan_kernel(const ushort_t* __restrict__ qs_h,
                                                      const ushort_t* __restrict__ qs_l,
                                                      const float* __restrict__ u,
                                                      const ushort_t* __restrict__ w_h,
                                                      const ushort_t* __restrict__ w_l,
                                                      const ushort_t* __restrict__ kTh_g,
                                                      const ushort_t* __restrict__ kTl_g,
                                                      const ushort_t* __restrict__ ath_g,
                                                      const ushort_t* __restrict__ atl_g,
                                                      float* __restrict__ o_lin) {
  __shared__ __align__(16) ushort_t kT_h[2][8192];   // [k][i] swizzled, dbuf
  __shared__ __align__(16) ushort_t kT_l[2][8192];
  __shared__ __align__(16) ushort_t at_h[2][4096];   // [i][j] swizzled, dbuf
  __shared__ __align__(16) ushort_t at_l[2][4096];
  __shared__ __align__(16) ushort_t Sh_s[16 * 128];  // S^T [c][k] swizzled
  __shared__ __align__(16) ushort_t Sl_s[16 * 128];
  __shared__ __align__(16) ushort_t uh_s[16 * 80];   // u'^T [c][i]
  __shared__ __align__(16) ushort_t ul_s[16 * 80];
  __shared__ __align__(16) float oT[16 * 68];        // q@S partial [c][i]
  const int tid = threadIdx.x;
  const int bh = blockIdx.x;
  const int b = bh >> 4, h = bh & 15;
  const int g = blockIdx.y;            // 0..7 (16 dv cols each)
  const int colbase = h * 128;
  const int vcol = h * 128 + g * 16;
  const int lane = tid & 63, wid = tid >> 6;
  const int lm = lane & 15, lg = lane >> 4;
  const int dsub = lane >> 3;          // 0..7
  const int i8x = (lane & 7) ^ dsub;   // pre-swizzled col group

  for (int i = tid; i < 16 * 128; i += 512) { Sh_s[i] = 0; Sl_s[i] = 0; }

  f4_t acc3[2];                        // persistent S tiles (waves 4-7)
  acc3[0] = (f4_t){0.f, 0.f, 0.f, 0.f};
  acc3[1] = (f4_t){0.f, 0.f, 0.f, 0.f};

  const ushort_t* kThb = kTh_g + (size_t)bh * 128 * 1024;
  const ushort_t* kTlb = kTl_g + (size_t)bh * 128 * 1024;

  auto issue_stage = [&](int buf, int chunk) {
#pragma unroll
    for (int it = 0; it < 2; it++) {
      int seg = it * 8 + wid;               // 0..15 (8 kT rows each)
      int d = seg * 8 + dsub;               // row 0..127
      size_t goff = (size_t)d * 1024 + chunk * 64 + i8x * 8;
      GLOAD16(kThb + goff, (char*)&kT_h[buf][0] + seg * 1024);
      GLOAD16(kTlb + goff, (char*)&kT_l[buf][0] + seg * 1024);
    }
    {
      int i = wid * 8 + dsub;               // attn row 0..63
      size_t asrc = (size_t)(bh * 16 + chunk) * 4096 + i * 64 + i8x * 8;
      GLOAD16(ath_g + asrc, (char*)&at_h[buf][0] + wid * 1024);
      GLOAD16(atl_g + asrc, (char*)&at_l[buf][0] + wid * 1024);
    }
  };

  const bool isU = (wid < 4);
  const int m0 = (isU ? wid : (wid - 4)) * 16;
  const ushort_t* AsrcH = isU ? w_h : qs_h;
  const ushort_t* AsrcL = isU ? w_l : qs_l;

  s8_t pAh[4], pAl[4];                  // prefetched hi/lo fragments
  float pu[4];
  auto prefetchA = [&](int chunk) {
    const size_t gb = (size_t)(b * 1024 + chunk * 64) * D;
#pragma unroll
    for (int ks = 0; ks < 4; ks++) {
      size_t off = gb + (size_t)(m0 + lm) * D + colbase + ks * 32 + lg * 8;
      pAh[ks] = *(const s8_t*)(AsrcH + off);
      pAl[ks] = *(const s8_t*)(AsrcL + off);
    }
    if (isU) {
#pragma unroll
      for (int r = 0; r < 4; r++)
        pu[r] = u[gb + (size_t)(m0 + lg * 4 + r) * D + vcol + lm];
    }
  };

  issue_stage(0, 0);
  prefetchA(0);
  __syncthreads();                      // S mirror init visible

  for (int chunk = 0; chunk < 16; chunk++) {
    const int cur = chunk & 1;
    const size_t gbase = (size_t)(b * 1024 + chunk * 64) * D;
    if (chunk + 1 < 16) issue_stage(cur ^ 1, chunk + 1);
    // ---- phase1 MFMA from prefetched pre-split regs: u' / q@S ----
    {
      f4_t acc = (f4_t){0.f, 0.f, 0.f, 0.f};
#pragma unroll
      for (int ks = 0; ks < 4; ks++) {
        int byo = (lm * 256 + ks * 64 + lg * 16) ^ ((lm & 7) << 4);
        s8_t sh = *(const s8_t*)((const char*)Sh_s + byo);
        s8_t sl = *(const s8_t*)((const char*)Sl_s + byo);
        acc = MFMA16(pAh[ks], sh, acc);
        acc = MFMA16(pAh[ks], sl, acc);
        acc = MFMA16(pAl[ks], sh, acc);
      }
      if (isU) {
        float res[4];
#pragma unroll
        for (int r = 0; r < 4; r++) res[r] = pu[r] - acc[r];
        us4_t rh, rl;
#pragma unroll
        for (int r = 0; r < 4; r++) {
          ushort_t hb = f2bf(res[r]);
          rh[r] = hb;
          rl[r] = f2bf(res[r] - bf2f(hb));
        }
        *(us4_t*)&uh_s[lm * 80 + m0 + lg * 4] = rh;
        *(us4_t*)&ul_s[lm * 80 + m0 + lg * 4] = rl;
      } else {
        float4 res = {acc[0], acc[1], acc[2], acc[3]};
        *(float4*)&oT[lm * 68 + m0 + lg * 4] = res;
      }
    }
    __syncthreads();                     // B: u', oT visible; staging drained
    if (chunk + 1 < 16) prefetchA(chunk + 1);
    if (isU) {
      // ---- phase2 MFMA: o = oT + attn @ u' ; store to global ----
      float4 o0 = *(const float4*)&oT[lm * 68 + m0 + lg * 4];
      f4_t acc2 = (f4_t){o0.x, o0.y, o0.z, o0.w};
#pragma unroll
      for (int ks = 0; ks < 2; ks++) {
        int arow = m0 + lm;
        int abyo = arow * 128 + ((ks * 64 + lg * 16) ^ ((arow & 7) << 4));
        s8_t afh = *(const s8_t*)((const char*)&at_h[cur][0] + abyo);
        s8_t afl = *(const s8_t*)((const char*)&at_l[cur][0] + abyo);
        s8_t ufh = *(const s8_t*)&uh_s[lm * 80 + ks * 32 + lg * 8];
        s8_t ufl = *(const s8_t*)&ul_s[lm * 80 + ks * 32 + lg * 8];
        acc2 = MFMA16(afh, ufh, acc2);
        acc2 = MFMA16(afh, ufl, acc2);
        acc2 = MFMA16(afl, ufh, acc2);
      }
#pragma unroll
      for (int r = 0; r < 4; r++)
        o_lin[gbase + (size_t)(m0 + lg * 4 + r) * D + vcol + lm] = acc2[r];
    } else {
      // ---- phase3 MFMA: S += u'^T @ kT (persistent acc) + mirror refresh --
      const int w3 = wid - 4;
      s8_t ufh0 = *(const s8_t*)&uh_s[lm * 80 + 0 * 32 + lg * 8];
      s8_t ufl0 = *(const s8_t*)&ul_s[lm * 80 + 0 * 32 + lg * 8];
      s8_t ufh1 = *(const s8_t*)&uh_s[lm * 80 + 1 * 32 + lg * 8];
      s8_t ufl1 = *(const s8_t*)&ul_s[lm * 80 + 1 * 32 + lg * 8];
#pragma unroll
      for (int t = 0; t < 2; t++) {
        const int krow = (w3 * 2 + t) * 16 + lm;
        int b0 = krow * 128 + ((0 * 64 + lg * 16) ^ ((krow & 7) << 4));
        int b1 = krow * 128 + ((1 * 64 + lg * 16) ^ ((krow & 7) << 4));
        s8_t kh0 = *(const s8_t*)((const char*)&kT_h[cur][0] + b0);
        s8_t kl0 = *(const s8_t*)((const char*)&kT_l[cur][0] + b0);
        s8_t kh1 = *(const s8_t*)((const char*)&kT_h[cur][0] + b1);
        s8_t kl1 = *(const s8_t*)((const char*)&kT_l[cur][0] + b1);
        acc3[t] = MFMA16(ufh0, kh0, acc3[t]);
        acc3[t] = MFMA16(ufh0, kl0, acc3[t]);
        acc3[t] = MFMA16(ufl0, kh0, acc3[t]);
        acc3[t] = MFMA16(ufh1, kh1, acc3[t]);
        acc3[t] = MFMA16(ufh1, kl1, acc3[t]);
        acc3[t] = MFMA16(ufl1, kh1, acc3[t]);
      }
#pragma unroll
      for (int t = 0; t < 2; t++)
#pragma unroll
        for (int r = 0; r < 4; r++) {
          int c = lg * 4 + r;
          int k = (w3 * 2 + t) * 16 + lm;
          float sval = acc3[t][r];
          ushort_t hb = f2bf(sval);
          int sbyo = (c * 256 + k * 2) ^ ((c & 7) << 4);
          *(ushort_t*)((char*)Sh_s + sbyo) = hb;
          *(ushort_t*)((char*)Sl_s + sbyo) = f2bf(sval - bf2f(hb));
        }
    }
    __syncthreads();                     // C: reads done; mirror ordered
  }
}

// -------- v (from fp16 qkv) -> transposed bf16 vt[b][h][d][n] -------------
__global__ __launch_bounds__(256) void v_transpose(const _Float16* __restrict__ qkv,
                                                   ushort_t* __restrict__ vt) {
  __shared__ float t[32][33];
  const int tid = threadIdx.x;
  const int n0 = blockIdx.x * 32;
  const int d0 = blockIdx.y * 32;
  const int bh = blockIdx.z;
  const int b = bh >> 4, h = bh & 15;
  const int c = tid & 31, rr = tid >> 5;
#pragma unroll
  for (int p = 0; p < 4; p++) {
    int r = p * 8 + rr;
    t[r][c] = (float)qkv[(size_t)(b * 1024 + n0 + r) * NQKV + 4096 + h * 128 + d0 + c];
  }
  __syncthreads();
#pragma unroll
  for (int p = 0; p < 4; p++) {
    int r = p * 8 + rr;
    vt[(size_t)(bh * 128 + d0 + r) * 1024 + n0 + c] = f2bf(t[c][r]);
  }
}

// -------- MFMA bf16 flash attention + 0.5/0.5 mix + fp16 out --------------
// Longest blocks first; T14 async-STAGE split (reg prefetch of K/V);
// T13 defer-max (RESCALE_THRESHOLD = 8).
__global__ __launch_bounds__(256) void attn_mfma(const ushort_t* __restrict__ qb,
                                                 const ushort_t* __restrict__ kb,
                                                 const ushort_t* __restrict__ vt,
                                                 const float* __restrict__ o_lin,
                                                 _Float16* __restrict__ mixh) {
  __shared__ __align__(16) ushort_t K_s[8192];
  __shared__ __align__(16) ushort_t V_s[8192];
  __shared__ __align__(16) ushort_t P_s[4][1152];
  const int tid = threadIdx.x;
  const int lane = tid & 63, wid = tid >> 6;
  const int bh = blockIdx.x;
  const int b = bh >> 4, h = bh & 15;
  const int qt = (int)(gridDim.y - 1) - (int)blockIdx.y;   // longest-first
  const int lm = lane & 15, lg = lane >> 4;

  s8_t qf[4];
  const size_t qrowG = (size_t)(b * 1024 + qt * 64 + wid * 16 + lm);
#pragma unroll
  for (int kb4 = 0; kb4 < 4; kb4++)
    qf[kb4] = *(const s8_t*)(qb + qrowG * D + h * 128 + kb4 * 32 + lg * 8);

  f4_t o[8];
#pragma unroll
  for (int n = 0; n < 8; n++) o[n] = (f4_t){0.f, 0.f, 0.f, 0.f};
  float mrow[4] = {-INFINITY, -INFINITY, -INFINITY, -INFINITY};
  float lrow[4] = {0.f, 0.f, 0.f, 0.f};
  const int myq = qt * 64 + wid * 16 + lg * 4;

  // T14: register prefetch of K/V tiles (static indices)
  s8_t sK[4], sV[4];
  auto loadK = [&](int kt) {
#pragma unroll
    for (int p = 0; p < 4; p++) {
      int c = tid + p * 256;
      int key = c >> 4, dc = c & 15;
      sK[p] = *(const s8_t*)(kb + (size_t)(b * 1024 + kt * 64 + key) * D + h * 128 + dc * 8);
    }
  };
  auto loadV = [&](int kt) {
#pragma unroll
    for (int p = 0; p < 4; p++) {
      int c = tid + p * 256;
      int d = c >> 3, nc = c & 7;
      sV[p] = *(const s8_t*)(vt + (size_t)(bh * 128 + d) * 1024 + kt * 64 + nc * 8);
    }
  };
  auto writeKV = [&]() {
#pragma unroll
    for (int p = 0; p < 4; p++) {
      int c = tid + p * 256;
      int key = c >> 4, dc = c & 15;
      int byo = key * 256 + ((dc * 16) ^ ((key & 7) << 4));
      *(s8_t*)((char*)K_s + byo) = sK[p];
      int d = c >> 3, nc = c & 7;
      int byo2 = d * 128 + ((nc * 16) ^ ((d & 7) << 4));
      *(s8_t*)((char*)V_s + byo2) = sV[p];
    }
  };

  loadK(0);
  loadV(0);

  for (int kt = 0; kt <= qt; kt++) {
    writeKV();
    __syncthreads();                       // LDS tile ready
    if (kt < qt) { loadK(kt + 1); loadV(kt + 1); }   // in flight under compute

    f4_t s[4];
#pragma unroll
    for (int ks = 0; ks < 4; ks++) {
      f4_t a = (f4_t){0.f, 0.f, 0.f, 0.f};
      int key = ks * 16 + lm;
#pragma unroll
      for (int kb4 = 0; kb4 < 4; kb4++) {
        int byo = key * 256 + ((kb4 * 64 + lg * 16) ^ ((key & 7) << 4));
        s8_t kf = *(const s8_t*)((char*)K_s + byo);
        a = MFMA16(qf[kb4], kf, a);
      }
      s[ks] = a;
    }
    if (kt == qt) {
#pragma unroll
      for (int ks = 0; ks < 4; ks++) {
        int key = kt * 64 + ks * 16 + lm;
#pragma unroll
        for (int r = 0; r < 4; r++)
          if (key > myq + r) s[ks][r] = -INFINITY;
      }
    }
    float mloc[4];
#pragma unroll
    for (int r = 0; r < 4; r++) {
      mloc[r] = fmaxf(fmaxf(s[0][r], s[1][r]), fmaxf(s[2][r], s[3][r]));
      mloc[r] = fmaxf(mloc[r], __shfl_xor(mloc[r], 1));
      mloc[r] = fmaxf(mloc[r], __shfl_xor(mloc[r], 2));
      mloc[r] = fmaxf(mloc[r], __shfl_xor(mloc[r], 4));
      mloc[r] = fmaxf(mloc[r], __shfl_xor(mloc[r], 8));
    }
    // T13 defer-max: rescale only when max grew past threshold
    int grow = 0;
#pragma unroll
    for (int r = 0; r < 4; r++)
      grow |= (mloc[r] > mrow[r] + 8.f) ? 1 : 0;
    if (__any(grow)) {
      float scale[4];
#pragma unroll
      for (int r = 0; r < 4; r++) {
        float mn = fmaxf(mrow[r], mloc[r]);
        scale[r] = __expf(mrow[r] - mn);
        mrow[r] = mn;
        lrow[r] *= scale[r];
      }
#pragma unroll
      for (int n = 0; n < 8; n++)
#pragma unroll
        for (int r = 0; r < 4; r++) o[n][r] *= scale[r];
    }
    float lad[4] = {0.f, 0.f, 0.f, 0.f};
#pragma unroll
    for (int ks = 0; ks < 4; ks++)
#pragma unroll
      for (int r = 0; r < 4; r++) {
        float p = __expf(s[ks][r] - mrow[r]);
        lad[r] += p;
        P_s[wid][(lg * 4 + r) * 72 + ks * 16 + lm] = f2bf(p);
      }
#pragma unroll
    for (int r = 0; r < 4; r++) {
      lad[r] += __shfl_xor(lad[r], 1);
      lad[r] += __shfl_xor(lad[r], 2);
      lad[r] += __shfl_xor(lad[r], 4);
      lad[r] += __shfl_xor(lad[r], 8);
      lrow[r] += lad[r];
    }

    s8_t pf[2];
#pragma unroll
    for (int ksl = 0; ksl < 2; ksl++)
      pf[ksl] = *(const s8_t*)&P_s[wid][lm * 72 + ksl * 32 + lg * 8];
#pragma unroll
    for (int n = 0; n < 8; n++) {
      int d = n * 16 + lm;
#pragma unroll
      for (int ksl = 0; ksl < 2; ksl++) {
        int byo = d * 128 + ((ksl * 64 + lg * 16) ^ ((d & 7) << 4));
        s8_t vf = *(const s8_t*)((char*)V_s + byo);
        o[n] = MFMA16(pf[ksl], vf, o[n]);
      }
    }
    __syncthreads();                       // all reads done; next writeKV safe
  }

  float invl[4];
#pragma unroll
  for (int r = 0; r < 4; r++) invl[r] = 1.f / lrow[r];
#pragma unroll
  for (int n = 0; n < 8; n++)
#pragma unroll
    for (int r = 0; r < 4; r++) {
      size_t G = (size_t)(b * 1024 + qt * 64 + wid * 16 + lg * 4 + r);
      int dcol = h * 128 + n * 16 + lm;
      float mix = 0.5f * (o[n][r] * invl[r]) + 0.5f * o_lin[G * D + dcol];
      mixh[G * D + dcol] = (_Float16)mix;
    }
}

// ---------------------------------------------------------------------------
extern "C" void kernel_launch(void* const* d_in, const int* in_sizes, int n_in,
                              void* d_out, int out_size, void* d_ws, size_t ws_size,
                              hipStream_t stream) {
  const float* x  = (const float*)d_in[0];
  const float* Wq = (const float*)d_in[1];
  const float* Wk = (const float*)d_in[2];
  const float* Wv = (const float*)d_in[3];
  const float* Wo = (const float*)d_in[4];
  float* out = (float*)d_out;
  float* ws = (float*)d_ws;

  const size_t B = (size_t)NROWS * D;   // 4,194,304 floats per slot
  _Float16* qkv = (_Float16*)(ws + 0 * B);   // [2048][6144] fp16 (slots 0-1)
  float* q_s  = ws + 3 * B;                  // holds qs_h/qs_l (bf16 pair)
  float* k_sm = ws + 4 * B;
  float* kbuf = ws + 5 * B;
  float* vbuf = ws + 6 * B;
  float* u    = ws + 7 * B;
  float* w    = ws + 8 * B;                  // holds w_h/w_l (bf16 pair)
  float* o_lin = kbuf;

  _Float16* x_hi = (_Float16*)u;                    // dead before chunk_uw writes u
  _Float16* Wt   = (_Float16*)(ws + 9 * B);         // QKV weights, dead after gemm1h
  ushort_t* attn_h = (ushort_t*)(ws + 9 * B);                 // after gemm1h
  ushort_t* attn_l = attn_h + (size_t)2097152;
  ushort_t* kTh_g  = (ushort_t*)(ws + 9 * B + 2097152);       // 4M u16
  ushort_t* kTl_g  = (ushort_t*)(ws + 10 * B);                // 4M u16
  _Float16* Wo_t   = (_Float16*)(ws + 10 * B + 2097152);      // own region
  ushort_t* qs_h = (ushort_t*)q_s;
  ushort_t* qs_l = qs_h + B;
  ushort_t* w_h  = (ushort_t*)w;
  ushort_t* w_l  = w_h + B;
  ushort_t* qb16 = (ushort_t*)(ws + 2 * B);
  ushort_t* kb16 = qb16 + B;
  ushort_t* vt16 = (ushort_t*)vbuf;
  _Float16* mixh = (_Float16*)qkv;

  split_h<<<4096, 256, 0, stream>>>(x, x_hi);
  wsplit4<<<dim3(64, 64, 4), 256, 0, stream>>>(Wq, Wk, Wv, Wo, Wt, Wo_t);
  gemm1h<<<16 * 48, 256, 0, stream>>>(x_hi, Wt, qkv, NROWS, NQKV, D);

  act_kernel<<<8192, 256, 0, stream>>>(qkv, qs_h, qs_l, k_sm, kbuf, vbuf, qb16, kb16);
  chunk_uw_kernel<<<512, 256, 0, stream>>>(qs_h, qs_l, k_sm, kbuf, vbuf, u, w_h, w_l,
                                           attn_h, attn_l, kTh_g, kTl_g);
  scan_kernel<<<dim3(32, 8), 512, 0, stream>>>(qs_h, qs_l, u, w_h, w_l, kTh_g, kTl_g, attn_h, attn_l, o_lin);

  v_transpose<<<dim3(32, 4, 32), 256, 0, stream>>>(qkv, vt16);
  attn_mfma<<<dim3(32, 16), 256, 0, stream>>>(qb16, kb16, vt16, o_lin, mixh);

  gemm1<<<16 * 16, 256, 0, stream>>>(mixh, Wo_t, out, NROWS, D, D);
}

// Round 22
// 273.340 us; speedup vs baseline: 1.1812x; 1.0087x over previous
//
#include <hip/hip_runtime.h>
#include <hip/hip_bf16.h>
#include <math.h>

#define D 2048
#define NROWS 2048      // b*n
#define NQKV 6144       // fused QKV width
#define H 16
#define DH 128
#define CHK 64
#define NC 16
#define EPSC 1e-6f
#define RSQDH 0.08838834764831845f   // 128^-0.5

typedef unsigned short ushort_t;
typedef __attribute__((ext_vector_type(4))) float f4_t;
typedef __attribute__((ext_vector_type(8))) short s8_t;
typedef __attribute__((ext_vector_type(8))) _Float16 h8_t;
typedef __attribute__((ext_vector_type(4))) _Float16 h4_t;
typedef __attribute__((ext_vector_type(2))) _Float16 h2_t;
typedef __attribute__((ext_vector_type(4))) unsigned short us4_t;
typedef __attribute__((ext_vector_type(2))) unsigned short us2_t;

#define MFMA16(a, b, c) __builtin_amdgcn_mfma_f32_16x16x32_bf16((a), (b), (c), 0, 0, 0)
#define MFMAH(a, b, c)  __builtin_amdgcn_mfma_f32_16x16x32_f16((a), (b), (c), 0, 0, 0)
#define GLOAD16(g, l) __builtin_amdgcn_global_load_lds((const __attribute__((address_space(1))) unsigned int*)(g), (__attribute__((address_space(3))) unsigned int*)(l), 16, 0, 0)

__device__ __forceinline__ ushort_t f2bf(float f) {
  union { float f; unsigned u; } v; v.f = f;
  unsigned r = (v.u + 0x7fffu + ((v.u >> 16) & 1u)) >> 16;
  return (ushort_t)r;
}
__device__ __forceinline__ float bf2f(ushort_t h) {
  union { unsigned u; float f; } v; v.u = ((unsigned)h) << 16;
  return v.f;
}

// ---- all 4 weights transpose+cast, plus x straight-cast, one launch -------
__global__ __launch_bounds__(256) void wsplit5(const float* __restrict__ Wq,
                                               const float* __restrict__ Wk,
                                               const float* __restrict__ Wv,
                                               const float* __restrict__ Wo,
                                               const float* __restrict__ x,
                                               _Float16* __restrict__ Tqkv,
                                               _Float16* __restrict__ To,
                                               _Float16* __restrict__ x_hi) {
  __shared__ float t[32][33];
  const int tid = threadIdx.x;
  const int k0 = blockIdx.y * 32, n0 = blockIdx.x * 32;
  const int z = blockIdx.z;
  const int c = tid & 31, rr = tid >> 5;
  if (z == 4) {
    // straight fp16 cast of x tile (no transpose)
#pragma unroll
    for (int p = 0; p < 4; p++) {
      int r = p * 8 + rr;
      x_hi[(size_t)(k0 + r) * D + n0 + c] = (_Float16)x[(size_t)(k0 + r) * D + n0 + c];
    }
    return;
  }
  const float* W = (z == 0) ? Wq : (z == 1) ? Wk : (z == 2) ? Wv : Wo;
  _Float16* T = (z < 3) ? (Tqkv + (size_t)z * D * D) : To;
#pragma unroll
  for (int p = 0; p < 4; p++) {
    int r = p * 8 + rr;
    t[r][c] = W[(size_t)(k0 + r) * D + n0 + c];
  }
  __syncthreads();
#pragma unroll
  for (int p = 0; p < 4; p++) {
    int r = p * 8 + rr;
    T[(size_t)(n0 + r) * D + k0 + c] = (_Float16)t[c][r];
  }
}

// ------ fp16 1-term MFMA GEMM (fp32 out, final Wo GEMM) --------------------
__global__ __launch_bounds__(256) void gemm1(const _Float16* __restrict__ Ah,
                                             const _Float16* __restrict__ Bt,
                                             float* __restrict__ C,
                                             int M, int N, int K) {
  __shared__ __align__(16) ushort_t A_s[2][4096];    // [128][32]
  __shared__ __align__(16) ushort_t B_s[2][4096];    // [128 cols][32 k]
  const int tid = threadIdx.x, lane = tid & 63, wid = tid >> 6;
  const int nwg = gridDim.x;
  int bid = blockIdx.x;
  int swz = (bid & 7) * (nwg >> 3) + (bid >> 3);     // XCD swizzle (nwg%8==0)
  const int nbn = N >> 7;
  const int bm = swz / nbn, bn = swz % nbn;
  const int row0 = bm << 7, col0 = bn << 7;
  const int lm = lane & 15, lg = lane >> 4;
  const int wrow = (wid >> 1) * 64, wcol = (wid & 1) * 64;
  const int NT = K >> 5;

  f4_t acc[4][4];
#pragma unroll
  for (int m = 0; m < 4; m++)
#pragma unroll
    for (int n = 0; n < 4; n++) acc[m][n] = (f4_t){0.f, 0.f, 0.f, 0.f};

  auto stage = [&](int buf, int ks) {
    int k0 = ks << 5;
#pragma unroll
    for (int p = 0; p < 2; p++) {
      int c = p * 256 + wid * 64 + lane;             // 16B chunk 0..511
      int r = c >> 2, q = (c & 3) * 8;
      char* la = (char*)&A_s[buf][0] + p * 4096 + wid * 1024;
      GLOAD16(Ah + (size_t)(row0 + r) * K + k0 + q, la);
      char* lb = (char*)&B_s[buf][0] + p * 4096 + wid * 1024;
      GLOAD16(Bt + (size_t)(col0 + r) * K + k0 + q, lb);
    }
  };

  stage(0, 0);
  __syncthreads();
  for (int t = 0; t < NT; t++) {
    int cur = t & 1;
    if (t + 1 < NT) stage(cur ^ 1, t + 1);
    h8_t af[4], bfr[4];
#pragma unroll
    for (int m = 0; m < 4; m++)
      af[m] = *(const h8_t*)&A_s[cur][(wrow + m * 16 + lm) * 32 + lg * 8];
#pragma unroll
    for (int n = 0; n < 4; n++)
      bfr[n] = *(const h8_t*)&B_s[cur][(wcol + n * 16 + lm) * 32 + lg * 8];
#pragma unroll
    for (int m = 0; m < 4; m++)
#pragma unroll
      for (int n = 0; n < 4; n++)
        acc[m][n] = MFMAH(af[m], bfr[n], acc[m][n]);
    __syncthreads();
  }
#pragma unroll
  for (int m = 0; m < 4; m++)
#pragma unroll
    for (int n = 0; n < 4; n++)
#pragma unroll
      for (int r = 0; r < 4; r++)
        C[(size_t)(row0 + wrow + m * 16 + lg * 4 + r) * N + col0 + wcol + n * 16 + lm] = acc[m][n][r];
}

// ------ fp16 1-term MFMA GEMM (fp16 out, QKV projection) -------------------
__global__ __launch_bounds__(256) void gemm1h(const _Float16* __restrict__ Ah,
                                              const _Float16* __restrict__ Bt,
                                              _Float16* __restrict__ C,
                                              int M, int N, int K) {
  __shared__ __align__(16) ushort_t A_s[2][4096];    // [128][32]
  __shared__ __align__(16) ushort_t B_s[2][4096];    // [128 cols][32 k]
  const int tid = threadIdx.x, lane = tid & 63, wid = tid >> 6;
  const int nwg = gridDim.x;
  int bid = blockIdx.x;
  int swz = (bid & 7) * (nwg >> 3) + (bid >> 3);     // XCD swizzle (nwg%8==0)
  const int nbn = N >> 7;
  const int bm = swz / nbn, bn = swz % nbn;
  const int lm = lane & 15, lg = lane >> 4;
  const int row0 = bm << 7, col0 = bn << 7;
  const int wrow = (wid >> 1) * 64, wcol = (wid & 1) * 64;
  const int NT = K >> 5;

  f4_t acc[4][4];
#pragma unroll
  for (int m = 0; m < 4; m++)
#pragma unroll
    for (int n = 0; n < 4; n++) acc[m][n] = (f4_t){0.f, 0.f, 0.f, 0.f};

  auto stage = [&](int buf, int ks) {
    int k0 = ks << 5;
#pragma unroll
    for (int p = 0; p < 2; p++) {
      int c = p * 256 + wid * 64 + lane;             // 16B chunk 0..511
      int r = c >> 2, q = (c & 3) * 8;
      char* la = (char*)&A_s[buf][0] + p * 4096 + wid * 1024;
      GLOAD16(Ah + (size_t)(row0 + r) * K + k0 + q, la);
      char* lb = (char*)&B_s[buf][0] + p * 4096 + wid * 1024;
      GLOAD16(Bt + (size_t)(col0 + r) * K + k0 + q, lb);
    }
  };

  stage(0, 0);
  __syncthreads();
  for (int t = 0; t < NT; t++) {
    int cur = t & 1;
    if (t + 1 < NT) stage(cur ^ 1, t + 1);
    h8_t af[4], bfr[4];
#pragma unroll
    for (int m = 0; m < 4; m++)
      af[m] = *(const h8_t*)&A_s[cur][(wrow + m * 16 + lm) * 32 + lg * 8];
#pragma unroll
    for (int n = 0; n < 4; n++)
      bfr[n] = *(const h8_t*)&B_s[cur][(wcol + n * 16 + lm) * 32 + lg * 8];
#pragma unroll
    for (int m = 0; m < 4; m++)
#pragma unroll
      for (int n = 0; n < 4; n++)
        acc[m][n] = MFMAH(af[m], bfr[n], acc[m][n]);
    __syncthreads();
  }
#pragma unroll
  for (int m = 0; m < 4; m++)
#pragma unroll
    for (int n = 0; n < 4; n++)
#pragma unroll
      for (int r = 0; r < 4; r++)
        C[(size_t)(row0 + wrow + m * 16 + lg * 4 + r) * N + col0 + wcol + n * 16 + lm] = (_Float16)acc[m][n][r];
}

// ---- activations: qs emitted as bf16 hi/lo; qk->bf16 fused ----------------
__device__ __forceinline__ float gate_fn(float z) {
  float t = -z;
  float sp = (t > 20.f) ? t : log1pf(expf(t));   // softplus(-z)
  float g = -sp * (1.f / 16.f);                  // log_sigmoid(z)/16
  return fminf(fmaxf(g, -16.f), 16.f);
}

__global__ __launch_bounds__(256) void act_kernel(const _Float16* __restrict__ qkv,
                                                  ushort_t* __restrict__ qs_h,
                                                  ushort_t* __restrict__ qs_l,
                                                  float* __restrict__ ksm,
                                                  float* __restrict__ kb,
                                                  float* __restrict__ vb,
                                                  ushort_t* __restrict__ qb16,
                                                  ushort_t* __restrict__ kb16) {
  int wave = blockIdx.x * 4 + (threadIdx.x >> 6);  // (row*16 + h)
  int lane = threadIdx.x & 63;
  int row = wave >> 4, h = wave & 15;
  size_t inb = (size_t)row * NQKV + h * 128;
  size_t base = (size_t)wave * 128;
  const int e0 = 2 * lane;                         // lane owns elems e0, e0+1

  h2_t qv = *(const h2_t*)(qkv + inb + e0);
  h2_t kv = *(const h2_t*)(qkv + inb + 2048 + e0);
  h2_t vv = *(const h2_t*)(qkv + inb + 4096 + e0);
  float q0 = (float)qv[0], q1 = (float)qv[1];
  float k0 = (float)kv[0], k1 = (float)kv[1];
  float v0 = (float)vv[0], v1 = (float)vv[1];

  // fused raw-logit bf16 outputs for base attention
  us2_t qo = {f2bf(q0 * RSQDH), f2bf(q1 * RSQDH)};
  us2_t ko = {f2bf(k0), f2bf(k1)};
  *(us2_t*)(qb16 + base + e0) = qo;
  *(us2_t*)(kb16 + base + e0) = ko;

  float m = fmaxf(q0, q1);
  for (int o = 1; o < 64; o <<= 1) m = fmaxf(m, __shfl_xor(m, o));
  float e0f = expf(q0 - m), e1f = expf(q1 - m);
  float s = e0f + e1f;
  for (int o = 1; o < 64; o <<= 1) s += __shfl_xor(s, o);
  float inv = 1.f / s;
  float qs0 = fminf(fmaxf(e0f * inv, EPSC), 1.f - EPSC) * RSQDH;
  float qs1 = fminf(fmaxf(e1f * inv, EPSC), 1.f - EPSC) * RSQDH;

  float mk = fmaxf(k0, k1);
  for (int o = 1; o < 64; o <<= 1) mk = fmaxf(mk, __shfl_xor(mk, o));
  float f0 = expf(k0 - mk), f1 = expf(k1 - mk);
  float sk = f0 + f1;
  for (int o = 1; o < 64; o <<= 1) sk += __shfl_xor(sk, o);
  float invk = 1.f / sk;
  float ks0 = fminf(fmaxf(f0 * invk, EPSC), 1.f - EPSC);
  float ks1 = fminf(fmaxf(f1 * invk, EPSC), 1.f - EPSC);

  float g0 = gate_fn(k0), g1 = gate_fn(k1);

  // qs as bf16 hi/lo (split once; consumers use directly)
  ushort_t qh0 = f2bf(qs0), qh1 = f2bf(qs1);
  us2_t qhv = {qh0, qh1};
  us2_t qlv = {f2bf(qs0 - bf2f(qh0)), f2bf(qs1 - bf2f(qh1))};
  *(us2_t*)(qs_h + base + e0) = qhv;
  *(us2_t*)(qs_l + base + e0) = qlv;

  *(float2*)(ksm + base + e0) = make_float2(ks0, ks1);
  *(float2*)(kb + base + e0) = make_float2(ks0 * g0, ks1 * g1);
  *(float2*)(vb + base + e0) = make_float2(v0 * g0, v1 * g1);
}

// ------- per-chunk (MFMA): L = kb@k^T, attn = q@k^T, fwd-subst -> u, w -----
__global__ __launch_bounds__(256) void chunk_uw_kernel(const ushort_t* __restrict__ qs_h,
                                                       const ushort_t* __restrict__ qs_l,
                                                       const float* __restrict__ ksm,
                                                       const float* __restrict__ kb,
                                                       const float* __restrict__ vb,
                                                       float* __restrict__ u,
                                                       ushort_t* __restrict__ w_h,
                                                       ushort_t* __restrict__ w_l,
                                                       ushort_t* __restrict__ attn_h,
                                                       ushort_t* __restrict__ attn_l,
                                                       ushort_t* __restrict__ kTh_g,
                                                       ushort_t* __restrict__ kTl_g) {
  __shared__ __align__(16) ushort_t kh_s[8192];   // k hi  [64][128] swizzled
  __shared__ __align__(16) ushort_t kl_s[8192];   // k lo
  __shared__ __align__(16) ushort_t xh_s[8192];   // kb hi, then q hi
  __shared__ __align__(16) ushort_t xl_s[8192];   // kb lo, then q lo
  __shared__ float L_s[4096];                     // [64][64]
  const int tid = threadIdx.x, lane = tid & 63, wid = tid >> 6;
  const int lm = lane & 15, lg = lane >> 4;
  const int bh = blockIdx.x >> 4, ci = blockIdx.x & 15;
  const int rowbase = (bh >> 4) * 1024 + ci * 64;
  const int colbase = (bh & 15) * 128;
  const size_t gbase = (size_t)rowbase * D + colbase;
  const int wr = (wid >> 1) * 32, wc = (wid & 1) * 32;

  auto stageM = [&](const float* __restrict__ src, ushort_t* dh, ushort_t* dl) {
#pragma unroll
    for (int it = 0; it < 4; it++) {
      int idx = tid + it * 256;
      int r = idx >> 4, c8 = idx & 15;
      const float* g = src + gbase + (size_t)r * D + c8 * 8;
      float4 v0 = *(const float4*)g;
      float4 v1 = *(const float4*)(g + 4);
      float vv[8] = {v0.x, v0.y, v0.z, v0.w, v1.x, v1.y, v1.z, v1.w};
      s8_t hv, lv;
#pragma unroll
      for (int j = 0; j < 8; j++) {
        ushort_t hb = f2bf(vv[j]);
        hv[j] = (short)hb;
        lv[j] = (short)f2bf(vv[j] - bf2f(hb));
      }
      int byo = r * 256 + ((c8 * 16) ^ ((r & 7) << 4));
      *(s8_t*)((char*)dh + byo) = hv;
      *(s8_t*)((char*)dl + byo) = lv;
    }
  };

  auto stageHL = [&](const ushort_t* __restrict__ srcH,
                     const ushort_t* __restrict__ srcL,
                     ushort_t* dh, ushort_t* dl) {
#pragma unroll
    for (int it = 0; it < 4; it++) {
      int idx = tid + it * 256;
      int r = idx >> 4, c8 = idx & 15;
      size_t g = gbase + (size_t)r * D + c8 * 8;
      s8_t hv = *(const s8_t*)(srcH + g);
      s8_t lv = *(const s8_t*)(srcL + g);
      int byo = r * 256 + ((c8 * 16) ^ ((r & 7) << 4));
      *(s8_t*)((char*)dh + byo) = hv;
      *(s8_t*)((char*)dl + byo) = lv;
    }
  };

  auto mm3 = [&](const ushort_t* Ah, const ushort_t* Al,
                 const ushort_t* Bh, const ushort_t* Bl, f4_t acc[2][2]) {
#pragma unroll
    for (int m = 0; m < 2; m++)
#pragma unroll
      for (int n = 0; n < 2; n++) acc[m][n] = (f4_t){0.f, 0.f, 0.f, 0.f};
#pragma unroll
    for (int term = 0; term < 3; term++) {
      const ushort_t* A = (term == 2) ? Al : Ah;
      const ushort_t* Bsrc = (term == 1) ? Bl : Bh;
#pragma unroll
      for (int ks = 0; ks < 4; ks++) {
        s8_t af[2], bf_[2];
#pragma unroll
        for (int m = 0; m < 2; m++) {
          int row = wr + m * 16 + lm;
          int byo = row * 256 + ((ks * 64 + lg * 16) ^ ((row & 7) << 4));
          af[m] = *(const s8_t*)((const char*)A + byo);
        }
#pragma unroll
        for (int n = 0; n < 2; n++) {
          int row = wc + n * 16 + lm;
          int byo = row * 256 + ((ks * 64 + lg * 16) ^ ((row & 7) << 4));
          bf_[n] = *(const s8_t*)((const char*)Bsrc + byo);
        }
#pragma unroll
        for (int m = 0; m < 2; m++)
#pragma unroll
          for (int n = 0; n < 2; n++)
            acc[m][n] = MFMA16(af[m], bf_[n], acc[m][n]);
      }
    }
  };

  stageM(ksm, kh_s, kl_s);
  stageM(kb, xh_s, xl_s);
  __syncthreads();

  f4_t accL[2][2];
  mm3(xh_s, xl_s, kh_s, kl_s, accL);

  // ---- emit kT hi/lo (transposed) from staged LDS k tile ----
  {
    const int dw = wid * 32;             // wave covers d = dw..dw+31
    const int r = lane;                  // n index within chunk (0..63)
#pragma unroll
    for (int i = 0; i < 32; i++) {
      int d = dw + i;
      int byo = r * 256 + ((((d >> 3) ^ (r & 7)) << 4)) + (d & 7) * 2;
      ushort_t hv = *(const ushort_t*)((const char*)kh_s + byo);
      ushort_t lv = *(const ushort_t*)((const char*)kl_s + byo);
      size_t go = (size_t)(bh * 128 + d) * 1024 + ci * 64 + r;
      kTh_g[go] = hv;
      kTl_g[go] = lv;
    }
  }

#pragma unroll
  for (int m = 0; m < 2; m++)
#pragma unroll
    for (int n = 0; n < 2; n++)
#pragma unroll
      for (int r = 0; r < 4; r++) {
        int i = wr + m * 16 + lg * 4 + r;
        int j = wc + n * 16 + lm;
        L_s[i * 64 + j] = (j < i) ? accL[m][n][r] : 0.f;
      }
  __syncthreads();

  stageHL(qs_h, qs_l, xh_s, xl_s);
  __syncthreads();

  f4_t accA[2][2];
  mm3(xh_s, xl_s, kh_s, kl_s, accA);
  ushort_t* abh = attn_h + (size_t)blockIdx.x * 4096;
  ushort_t* abl = attn_l + (size_t)blockIdx.x * 4096;
#pragma unroll
  for (int m = 0; m < 2; m++)
#pragma unroll
    for (int n = 0; n < 2; n++)
#pragma unroll
      for (int r = 0; r < 4; r++) {
        int i = wr + m * 16 + lg * 4 + r;
        int j = wc + n * 16 + lm;
        float val = (j <= i) ? accA[m][n][r] : 0.f;
        ushort_t hb = f2bf(val);
        abh[i * 64 + j] = hb;
        abl[i * 64 + j] = f2bf(val - bf2f(hb));
      }

  float x[64];
  const int c = tid & 127;
  const float* rhs = (tid < 128) ? (vb + gbase + c) : (kb + gbase + c);
#pragma unroll
  for (int j = 0; j < 64; j++) x[j] = rhs[(size_t)j * D];
#pragma unroll
  for (int i = 0; i < 64; i++) {
    float xi = x[i];
#pragma unroll
    for (int r2 = i + 1; r2 < 64; r2++) x[r2] -= L_s[r2 * 64 + i] * xi;
  }
  if (tid < 128) {
#pragma unroll
    for (int j = 0; j < 64; j++) u[gbase + (size_t)j * D + c] = x[j];
  } else {
#pragma unroll
    for (int j = 0; j < 64; j++) {
      ushort_t hb = f2bf(x[j]);
      w_h[gbase + (size_t)j * D + c] = hb;
      w_l[gbase + (size_t)j * D + c] = f2bf(x[j] - bf2f(hb));
    }
  }
}

// ------- sequential scan: grid(32 bh, 8 vgroups), 512 thr ------------------
// v10: o_lin emitted fp16 (halves o_lin traffic).
__global__ __launch_bounds__(512, 2) void scan_kernel(const ushort_t* __restrict__ qs_h,
                                                      const ushort_t* __restrict__ qs_l,
                                                      const float* __restrict__ u,
                                                      const ushort_t* __restrict__ w_h,
                                                      const ushort_t* __restrict__ w_l,
                                                      const ushort_t* __restrict__ kTh_g,
                                                      const ushort_t* __restrict__ kTl_g,
                                                      const ushort_t* __restrict__ ath_g,
                                                      const ushort_t* __restrict__ atl_g,
                                                      _Float16* __restrict__ o_lin) {
  __shared__ __align__(16) ushort_t kT_h[2][8192];   // [k][i] swizzled, dbuf
  __shared__ __align__(16) ushort_t kT_l[2][8192];
  __shared__ __align__(16) ushort_t at_h[2][4096];   // [i][j] swizzled, dbuf
  __shared__ __align__(16) ushort_t at_l[2][4096];
  __shared__ __align__(16) ushort_t Sh_s[16 * 128];  // S^T [c][k] swizzled
  __shared__ __align__(16) ushort_t Sl_s[16 * 128];
  __shared__ __align__(16) ushort_t uh_s[16 * 80];   // u'^T [c][i]
  __shared__ __align__(16) ushort_t ul_s[16 * 80];
  __shared__ __align__(16) float oT[16 * 68];        // q@S partial [c][i]
  const int tid = threadIdx.x;
  const int bh = blockIdx.x;
  const int b = bh >> 4, h = bh & 15;
  const int g = blockIdx.y;            // 0..7 (16 dv cols each)
  const int colbase = h * 128;
  const int vcol = h * 128 + g * 16;
  const int lane = tid & 63, wid = tid >> 6;
  const int lm = lane & 15, lg = lane >> 4;
  const int dsub = lane >> 3;          // 0..7
  const int i8x = (lane & 7) ^ dsub;   // pre-swizzled col group

  for (int i = tid; i < 16 * 128; i += 512) { Sh_s[i] = 0; Sl_s[i] = 0; }

  f4_t acc3[2];                        // persistent S tiles (waves 4-7)
  acc3[0] = (f4_t){0.f, 0.f, 0.f, 0.f};
  acc3[1] = (f4_t){0.f, 0.f, 0.f, 0.f};

  const ushort_t* kThb = kTh_g + (size_t)bh * 128 * 1024;
  const ushort_t* kTlb = kTl_g + (size_t)bh * 128 * 1024;

  auto issue_stage = [&](int buf, int chunk) {
#pragma unroll
    for (int it = 0; it < 2; it++) {
      int seg = it * 8 + wid;               // 0..15 (8 kT rows each)
      int d = seg * 8 + dsub;               // row 0..127
      size_t goff = (size_t)d * 1024 + chunk * 64 + i8x * 8;
      GLOAD16(kThb + goff, (char*)&kT_h[buf][0] + seg * 1024);
      GLOAD16(kTlb + goff, (char*)&kT_l[buf][0] + seg * 1024);
    }
    {
      int i = wid * 8 + dsub;               // attn row 0..63
      size_t asrc = (size_t)(bh * 16 + chunk) * 4096 + i * 64 + i8x * 8;
      GLOAD16(ath_g + asrc, (char*)&at_h[buf][0] + wid * 1024);
      GLOAD16(atl_g + asrc, (char*)&at_l[buf][0] + wid * 1024);
    }
  };

  const bool isU = (wid < 4);
  const int m0 = (isU ? wid : (wid - 4)) * 16;
  const ushort_t* AsrcH = isU ? w_h : qs_h;
  const ushort_t* AsrcL = isU ? w_l : qs_l;

  s8_t pAh[4], pAl[4];                  // prefetched hi/lo fragments
  float pu[4];
  auto prefetchA = [&](int chunk) {
    const size_t gb = (size_t)(b * 1024 + chunk * 64) * D;
#pragma unroll
    for (int ks = 0; ks < 4; ks++) {
      size_t off = gb + (size_t)(m0 + lm) * D + colbase + ks * 32 + lg * 8;
      pAh[ks] = *(const s8_t*)(AsrcH + off);
      pAl[ks] = *(const s8_t*)(AsrcL + off);
    }
    if (isU) {
#pragma unroll
      for (int r = 0; r < 4; r++)
        pu[r] = u[gb + (size_t)(m0 + lg * 4 + r) * D + vcol + lm];
    }
  };

  issue_stage(0, 0);
  prefetchA(0);
  __syncthreads();                      // S mirror init visible

  for (int chunk = 0; chunk < 16; chunk++) {
    const int cur = chunk & 1;
    const size_t gbase = (size_t)(b * 1024 + chunk * 64) * D;
    if (chunk + 1 < 16) issue_stage(cur ^ 1, chunk + 1);
    // ---- phase1 MFMA from prefetched pre-split regs: u' / q@S ----
    {
      f4_t acc = (f4_t){0.f, 0.f, 0.f, 0.f};
#pragma unroll
      for (int ks = 0; ks < 4; ks++) {
        int byo = (lm * 256 + ks * 64 + lg * 16) ^ ((lm & 7) << 4);
        s8_t sh = *(const s8_t*)((const char*)Sh_s + byo);
        s8_t sl = *(const s8_t*)((const char*)Sl_s + byo);
        acc = MFMA16(pAh[ks], sh, acc);
        acc = MFMA16(pAh[ks], sl, acc);
        acc = MFMA16(pAl[ks], sh, acc);
      }
      if (isU) {
        float res[4];
#pragma unroll
        for (int r = 0; r < 4; r++) res[r] = pu[r] - acc[r];
        us4_t rh, rl;
#pragma unroll
        for (int r = 0; r < 4; r++) {
          ushort_t hb = f2bf(res[r]);
          rh[r] = hb;
          rl[r] = f2bf(res[r] - bf2f(hb));
        }
        *(us4_t*)&uh_s[lm * 80 + m0 + lg * 4] = rh;
        *(us4_t*)&ul_s[lm * 80 + m0 + lg * 4] = rl;
      } else {
        float4 res = {acc[0], acc[1], acc[2], acc[3]};
        *(float4*)&oT[lm * 68 + m0 + lg * 4] = res;
      }
    }
    __syncthreads();                     // B: u', oT visible; staging drained
    if (chunk + 1 < 16) prefetchA(chunk + 1);
    if (isU) {
      // ---- phase2 MFMA: o = oT + attn @ u' ; store to global (fp16) ----
      float4 o0 = *(const float4*)&oT[lm * 68 + m0 + lg * 4];
      f4_t acc2 = (f4_t){o0.x, o0.y, o0.z, o0.w};
#pragma unroll
      for (int ks = 0; ks < 2; ks++) {
        int arow = m0 + lm;
        int abyo = arow * 128 + ((ks * 64 + lg * 16) ^ ((arow & 7) << 4));
        s8_t afh = *(const s8_t*)((const char*)&at_h[cur][0] + abyo);
        s8_t afl = *(const s8_t*)((const char*)&at_l[cur][0] + abyo);
        s8_t ufh = *(const s8_t*)&uh_s[lm * 80 + ks * 32 + lg * 8];
        s8_t ufl = *(const s8_t*)&ul_s[lm * 80 + ks * 32 + lg * 8];
        acc2 = MFMA16(afh, ufh, acc2);
        acc2 = MFMA16(afh, ufl, acc2);
        acc2 = MFMA16(afl, ufh, acc2);
      }
#pragma unroll
      for (int r = 0; r < 4; r++)
        o_lin[gbase + (size_t)(m0 + lg * 4 + r) * D + vcol + lm] = (_Float16)acc2[r];
    } else {
      // ---- phase3 MFMA: S += u'^T @ kT (persistent acc) + mirror refresh --
      const int w3 = wid - 4;
      s8_t ufh0 = *(const s8_t*)&uh_s[lm * 80 + 0 * 32 + lg * 8];
      s8_t ufl0 = *(const s8_t*)&ul_s[lm * 80 + 0 * 32 + lg * 8];
      s8_t ufh1 = *(const s8_t*)&uh_s[lm * 80 + 1 * 32 + lg * 8];
      s8_t ufl1 = *(const s8_t*)&ul_s[lm * 80 + 1 * 32 + lg * 8];
#pragma unroll
      for (int t = 0; t < 2; t++) {
        const int krow = (w3 * 2 + t) * 16 + lm;
        int b0 = krow * 128 + ((0 * 64 + lg * 16) ^ ((krow & 7) << 4));
        int b1 = krow * 128 + ((1 * 64 + lg * 16) ^ ((krow & 7) << 4));
        s8_t kh0 = *(const s8_t*)((const char*)&kT_h[cur][0] + b0);
        s8_t kl0 = *(const s8_t*)((const char*)&kT_l[cur][0] + b0);
        s8_t kh1 = *(const s8_t*)((const char*)&kT_h[cur][0] + b1);
        s8_t kl1 = *(const s8_t*)((const char*)&kT_l[cur][0] + b1);
        acc3[t] = MFMA16(ufh0, kh0, acc3[t]);
        acc3[t] = MFMA16(ufh0, kl0, acc3[t]);
        acc3[t] = MFMA16(ufl0, kh0, acc3[t]);
        acc3[t] = MFMA16(ufh1, kh1, acc3[t]);
        acc3[t] = MFMA16(ufh1, kl1, acc3[t]);
        acc3[t] = MFMA16(ufl1, kh1, acc3[t]);
      }
#pragma unroll
      for (int t = 0; t < 2; t++)
#pragma unroll
        for (int r = 0; r < 4; r++) {
          int c = lg * 4 + r;
          int k = (w3 * 2 + t) * 16 + lm;
          float sval = acc3[t][r];
          ushort_t hb = f2bf(sval);
          int sbyo = (c * 256 + k * 2) ^ ((c & 7) << 4);
          *(ushort_t*)((char*)Sh_s + sbyo) = hb;
          *(ushort_t*)((char*)Sl_s + sbyo) = f2bf(sval - bf2f(hb));
        }
    }
    __syncthreads();                     // C: reads done; mirror ordered
  }
}

// -------- v (from fp16 qkv) -> transposed bf16 vt[b][h][d][n] -------------
__global__ __launch_bounds__(256) void v_transpose(const _Float16* __restrict__ qkv,
                                                   ushort_t* __restrict__ vt) {
  __shared__ float t[32][33];
  const int tid = threadIdx.x;
  const int n0 = blockIdx.x * 32;
  const int d0 = blockIdx.y * 32;
  const int bh = blockIdx.z;
  const int b = bh >> 4, h = bh & 15;
  const int c = tid & 31, rr = tid >> 5;
#pragma unroll
  for (int p = 0; p < 4; p++) {
    int r = p * 8 + rr;
    t[r][c] = (float)qkv[(size_t)(b * 1024 + n0 + r) * NQKV + 4096 + h * 128 + d0 + c];
  }
  __syncthreads();
#pragma unroll
  for (int p = 0; p < 4; p++) {
    int r = p * 8 + rr;
    vt[(size_t)(bh * 128 + d0 + r) * 1024 + n0 + c] = f2bf(t[c][r]);
  }
}

// -------- MFMA bf16 flash attention + 0.5/0.5 mix + fp16 out --------------
__global__ __launch_bounds__(256) void attn_mfma(const ushort_t* __restrict__ qb,
                                                 const ushort_t* __restrict__ kb,
                                                 const ushort_t* __restrict__ vt,
                                                 const _Float16* __restrict__ o_lin,
                                                 _Float16* __restrict__ mixh) {
  __shared__ __align__(16) ushort_t K_s[8192];
  __shared__ __align__(16) ushort_t V_s[8192];
  __shared__ __align__(16) ushort_t P_s[4][1152];
  const int tid = threadIdx.x;
  const int lane = tid & 63, wid = tid >> 6;
  const int bh = blockIdx.x;
  const int b = bh >> 4, h = bh & 15;
  const int qt = (int)(gridDim.y - 1) - (int)blockIdx.y;   // longest-first
  const int lm = lane & 15, lg = lane >> 4;

  s8_t qf[4];
  const size_t qrowG = (size_t)(b * 1024 + qt * 64 + wid * 16 + lm);
#pragma unroll
  for (int kb4 = 0; kb4 < 4; kb4++)
    qf[kb4] = *(const s8_t*)(qb + qrowG * D + h * 128 + kb4 * 32 + lg * 8);

  f4_t o[8];
#pragma unroll
  for (int n = 0; n < 8; n++) o[n] = (f4_t){0.f, 0.f, 0.f, 0.f};
  float mrow[4] = {-INFINITY, -INFINITY, -INFINITY, -INFINITY};
  float lrow[4] = {0.f, 0.f, 0.f, 0.f};
  const int myq = qt * 64 + wid * 16 + lg * 4;

  s8_t sK[4], sV[4];
  auto loadK = [&](int kt) {
#pragma unroll
    for (int p = 0; p < 4; p++) {
      int c = tid + p * 256;
      int key = c >> 4, dc = c & 15;
      sK[p] = *(const s8_t*)(kb + (size_t)(b * 1024 + kt * 64 + key) * D + h * 128 + dc * 8);
    }
  };
  auto loadV = [&](int kt) {
#pragma unroll
    for (int p = 0; p < 4; p++) {
      int c = tid + p * 256;
      int d = c >> 3, nc = c & 7;
      sV[p] = *(const s8_t*)(vt + (size_t)(bh * 128 + d) * 1024 + kt * 64 + nc * 8);
    }
  };
  auto writeKV = [&]() {
#pragma unroll
    for (int p = 0; p < 4; p++) {
      int c = tid + p * 256;
      int key = c >> 4, dc = c & 15;
      int byo = key * 256 + ((dc * 16) ^ ((key & 7) << 4));
      *(s8_t*)((char*)K_s + byo) = sK[p];
      int d = c >> 3, nc = c & 7;
      int byo2 = d * 128 + ((nc * 16) ^ ((d & 7) << 4));
      *(s8_t*)((char*)V_s + byo2) = sV[p];
    }
  };

  loadK(0);
  loadV(0);

  for (int kt = 0; kt <= qt; kt++) {
    writeKV();
    __syncthreads();                       // LDS tile ready
    if (kt < qt) { loadK(kt + 1); loadV(kt + 1); }   // in flight under compute

    f4_t s[4];
#pragma unroll
    for (int ks = 0; ks < 4; ks++) {
      f4_t a = (f4_t){0.f, 0.f, 0.f, 0.f};
      int key = ks * 16 + lm;
#pragma unroll
      for (int kb4 = 0; kb4 < 4; kb4++) {
        int byo = key * 256 + ((kb4 * 64 + lg * 16) ^ ((key & 7) << 4));
        s8_t kf = *(const s8_t*)((char*)K_s + byo);
        a = MFMA16(qf[kb4], kf, a);
      }
      s[ks] = a;
    }
    if (kt == qt) {
#pragma unroll
      for (int ks = 0; ks < 4; ks++) {
        int key = kt * 64 + ks * 16 + lm;
#pragma unroll
        for (int r = 0; r < 4; r++)
          if (key > myq + r) s[ks][r] = -INFINITY;
      }
    }
    float mloc[4];
#pragma unroll
    for (int r = 0; r < 4; r++) {
      mloc[r] = fmaxf(fmaxf(s[0][r], s[1][r]), fmaxf(s[2][r], s[3][r]));
      mloc[r] = fmaxf(mloc[r], __shfl_xor(mloc[r], 1));
      mloc[r] = fmaxf(mloc[r], __shfl_xor(mloc[r], 2));
      mloc[r] = fmaxf(mloc[r], __shfl_xor(mloc[r], 4));
      mloc[r] = fmaxf(mloc[r], __shfl_xor(mloc[r], 8));
    }
    int grow = 0;
#pragma unroll
    for (int r = 0; r < 4; r++)
      grow |= (mloc[r] > mrow[r] + 8.f) ? 1 : 0;
    if (__any(grow)) {
      float scale[4];
#pragma unroll
      for (int r = 0; r < 4; r++) {
        float mn = fmaxf(mrow[r], mloc[r]);
        scale[r] = __expf(mrow[r] - mn);
        mrow[r] = mn;
        lrow[r] *= scale[r];
      }
#pragma unroll
      for (int n = 0; n < 8; n++)
#pragma unroll
        for (int r = 0; r < 4; r++) o[n][r] *= scale[r];
    }
    float lad[4] = {0.f, 0.f, 0.f, 0.f};
#pragma unroll
    for (int ks = 0; ks < 4; ks++)
#pragma unroll
      for (int r = 0; r < 4; r++) {
        float p = __expf(s[ks][r] - mrow[r]);
        lad[r] += p;
        P_s[wid][(lg * 4 + r) * 72 + ks * 16 + lm] = f2bf(p);
      }
#pragma unroll
    for (int r = 0; r < 4; r++) {
      lad[r] += __shfl_xor(lad[r], 1);
      lad[r] += __shfl_xor(lad[r], 2);
      lad[r] += __shfl_xor(lad[r], 4);
      lad[r] += __shfl_xor(lad[r], 8);
      lrow[r] += lad[r];
    }

    s8_t pf[2];
#pragma unroll
    for (int ksl = 0; ksl < 2; ksl++)
      pf[ksl] = *(const s8_t*)&P_s[wid][lm * 72 + ksl * 32 + lg * 8];
#pragma unroll
    for (int n = 0; n < 8; n++) {
      int d = n * 16 + lm;
#pragma unroll
      for (int ksl = 0; ksl < 2; ksl++) {
        int byo = d * 128 + ((ksl * 64 + lg * 16) ^ ((d & 7) << 4));
        s8_t vf = *(const s8_t*)((char*)V_s + byo);
        o[n] = MFMA16(pf[ksl], vf, o[n]);
      }
    }
    __syncthreads();                       // all reads done; next writeKV safe
  }

  float invl[4];
#pragma unroll
  for (int r = 0; r < 4; r++) invl[r] = 1.f / lrow[r];
#pragma unroll
  for (int n = 0; n < 8; n++)
#pragma unroll
    for (int r = 0; r < 4; r++) {
      size_t G = (size_t)(b * 1024 + qt * 64 + wid * 16 + lg * 4 + r);
      int dcol = h * 128 + n * 16 + lm;
      float mix = 0.5f * (o[n][r] * invl[r]) + 0.5f * (float)o_lin[G * D + dcol];
      mixh[G * D + dcol] = (_Float16)mix;
    }
}

// ---------------------------------------------------------------------------
extern "C" void kernel_launch(void* const* d_in, const int* in_sizes, int n_in,
                              void* d_out, int out_size, void* d_ws, size_t ws_size,
                              hipStream_t stream) {
  const float* x  = (const float*)d_in[0];
  const float* Wq = (const float*)d_in[1];
  const float* Wk = (const float*)d_in[2];
  const float* Wv = (const float*)d_in[3];
  const float* Wo = (const float*)d_in[4];
  float* out = (float*)d_out;
  float* ws = (float*)d_ws;

  const size_t B = (size_t)NROWS * D;   // 4,194,304 floats per slot
  _Float16* qkv = (_Float16*)(ws + 0 * B);   // [2048][6144] fp16 (slots 0-1)
  float* q_s  = ws + 3 * B;                  // holds qs_h/qs_l (bf16 pair)
  float* k_sm = ws + 4 * B;
  float* kbuf = ws + 5 * B;
  float* vbuf = ws + 6 * B;
  float* u    = ws + 7 * B;
  float* w    = ws + 8 * B;                  // holds w_h/w_l (bf16 pair)
  _Float16* o_lin = (_Float16*)kbuf;

  _Float16* x_hi = (_Float16*)u;                    // dead before chunk_uw writes u
  _Float16* Wt   = (_Float16*)(ws + 9 * B);         // QKV weights, dead after gemm1h
  ushort_t* attn_h = (ushort_t*)(ws + 9 * B);                 // after gemm1h
  ushort_t* attn_l = attn_h + (size_t)2097152;
  ushort_t* kTh_g  = (ushort_t*)(ws + 9 * B + 2097152);       // 4M u16
  ushort_t* kTl_g  = (ushort_t*)(ws + 10 * B);                // 4M u16
  _Float16* Wo_t   = (_Float16*)(ws + 10 * B + 2097152);      // own region
  ushort_t* qs_h = (ushort_t*)q_s;
  ushort_t* qs_l = qs_h + B;
  ushort_t* w_h  = (ushort_t*)w;
  ushort_t* w_l  = w_h + B;
  ushort_t* qb16 = (ushort_t*)(ws + 2 * B);
  ushort_t* kb16 = qb16 + B;
  ushort_t* vt16 = (ushort_t*)vbuf;
  _Float16* mixh = (_Float16*)qkv;

  wsplit5<<<dim3(64, 64, 5), 256, 0, stream>>>(Wq, Wk, Wv, Wo, x, Wt, Wo_t, x_hi);
  gemm1h<<<16 * 48, 256, 0, stream>>>(x_hi, Wt, qkv, NROWS, NQKV, D);

  act_kernel<<<8192, 256, 0, stream>>>(qkv, qs_h, qs_l, k_sm, kbuf, vbuf, qb16, kb16);
  chunk_uw_kernel<<<512, 256, 0, stream>>>(qs_h, qs_l, k_sm, kbuf, vbuf, u, w_h, w_l,
                                           attn_h, attn_l, kTh_g, kTl_g);
  scan_kernel<<<dim3(32, 8), 512, 0, stream>>>(qs_h, qs_l, u, w_h, w_l, kTh_g, kTl_g, attn_h, attn_l, o_lin);

  v_transpose<<<dim3(32, 4, 32), 256, 0, stream>>>(qkv, vt16);
  attn_mfma<<<dim3(32, 16), 256, 0, stream>>>(qb16, kb16, vt16, o_lin, mixh);

  gemm1<<<16 * 16, 256, 0, stream>>>(mixh, Wo_t, out, NROWS, D, D);
}